// Round 1
// baseline (1080.218 us; speedup 1.0000x reference)
//
#include <hip/hip_runtime.h>
#include <cmath>

// Problem constants (fixed by setup_inputs)
#define TOK   8192   // B*S = 4*2048
#define RNK   256
#define NEXP  16
#define NREF  64
#define DM    1024
#define KTOT  4096   // NEXP * RNK

// Output layout (fp32 elements, concatenated in return order)
#define Y_OFF  0
#define IR_OFF (TOK*DM)                 // 8388608
#define W_OFF  (IR_OFF + TOK*2)         // 8404992
#define ID_OFF (W_OFF + TOK*NEXP)       // 8536064

// ---------- top-2 across a 64-lane wave, lax.top_k tie semantics ----------
__device__ inline void top2_64(double v, int idx, int& i0, int& i1) {
    double bv = v; int bi = idx;
    #pragma unroll
    for (int m = 1; m < 64; m <<= 1) {
        double ov = __shfl_xor(bv, m, 64);
        int    oi = __shfl_xor(bi, m, 64);
        if (ov > bv || (ov == bv && oi < bi)) { bv = ov; bi = oi; }
    }
    i0 = bi;
    double v2 = (idx == i0) ? -INFINITY : v;
    double bv2 = v2; int bi2 = idx;
    #pragma unroll
    for (int m = 1; m < 64; m <<= 1) {
        double ov = __shfl_xor(bv2, m, 64);
        int    oi = __shfl_xor(bi2, m, 64);
        if (ov > bv2 || (ov == bv2 && oi < bi2)) { bv2 = ov; bi2 = oi; }
    }
    i1 = bi2;
}

// ---------- K1: scores_r -> top2 -> 2 reflections -> scores_e -> softmax ----
__global__ __launch_bounds__(256) void k1_tokens(
    const float* __restrict__ x, const float* __restrict__ Wr,
    const float* __restrict__ We, const float* __restrict__ reflect_r,
    float* __restrict__ xprime, float* __restrict__ out_ir,
    float* __restrict__ out_w)
{
    __shared__ float xs[4][RNK];
    const int tid = threadIdx.x;
    const int w = tid >> 6, lane = tid & 63;
    const int t = blockIdx.x * 4 + w;

    float4 xv = *(const float4*)(x + (size_t)t * RNK + lane * 4);
    *(float4*)(&xs[w][lane * 4]) = xv;
    __syncthreads();

    // scores_r: lane n owns row n of Wr (double accumulate for stable top-k)
    double s = 0.0;
    {
        const float* wrow = Wr + (size_t)lane * RNK;
        for (int r4 = 0; r4 < RNK / 4; ++r4) {
            float4 xr = *(const float4*)(&xs[w][r4 * 4]);
            float4 wr = *(const float4*)(wrow + r4 * 4);
            s += (double)xr.x * wr.x + (double)xr.y * wr.y
               + (double)xr.z * wr.z + (double)xr.w * wr.w;
        }
    }
    int i0, i1;
    top2_64(s, lane, i0, i1);

    // two Householder-style reflections: x -= 2 v (v.x) / (|v|^2 + 1e-8)
    #pragma unroll
    for (int rr = 0; rr < 2; ++rr) {
        int idx = rr ? i1 : i0;
        float4 vv = *(const float4*)(reflect_r + (size_t)idx * RNK + lane * 4);
        float sv = vv.x * xv.x + vv.y * xv.y + vv.z * xv.z + vv.w * xv.w;
        float vn = vv.x * vv.x + vv.y * vv.y + vv.z * vv.z + vv.w * vv.w;
        #pragma unroll
        for (int m = 1; m < 64; m <<= 1) {
            sv += __shfl_xor(sv, m, 64);
            vn += __shfl_xor(vn, m, 64);
        }
        float coef = 2.0f * sv / (vn + 1e-8f);
        xv.x -= coef * vv.x; xv.y -= coef * vv.y;
        xv.z -= coef * vv.z; xv.w -= coef * vv.w;
    }
    __syncthreads();
    *(float4*)(&xs[w][lane * 4]) = xv;
    *(float4*)(xprime + (size_t)t * RNK + lane * 4) = xv;
    __syncthreads();

    // scores_e on updated x; lanes replicate per 16-group (n = lane & 15)
    const int n = lane & 15;
    double se = 0.0;
    {
        const float* werow = We + (size_t)n * RNK;
        for (int r4 = 0; r4 < RNK / 4; ++r4) {
            float4 xr = *(const float4*)(&xs[w][r4 * 4]);
            float4 wf = *(const float4*)(werow + r4 * 4);
            se += (double)xr.x * wf.x + (double)xr.y * wf.y
                + (double)xr.z * wf.z + (double)xr.w * wf.w;
        }
    }
    float sef = (float)se;
    float mx = sef;
    #pragma unroll
    for (int m = 1; m < 16; m <<= 1) mx = fmaxf(mx, __shfl_xor(mx, m, 64));
    float ex = expf(sef - mx);
    float sm = ex;
    #pragma unroll
    for (int m = 1; m < 16; m <<= 1) sm += __shfl_xor(sm, m, 64);
    float wgt = ex / sm;

    if (lane < NEXP) out_w[(size_t)t * NEXP + lane] = wgt;
    if (lane == 0) {
        out_ir[(size_t)t * 2 + 0] = (float)i0;
        out_ir[(size_t)t * 2 + 1] = (float)i1;
    }
}

// ---------- K2: y[t,d] = sum_k (w[t,k>>8] * x'[t,k&255]) * E[k,d] ----------
// M=8192, N=1024, K=4096. BM=BN=128, BK=16, 256 threads, 8x8 per thread.
__global__ __launch_bounds__(256) void k2_gemm(
    const float* __restrict__ xp, const float* __restrict__ wts,
    const float* __restrict__ E, float* __restrict__ y)
{
    __shared__ float As[16][132];   // transposed A tile, +4 pad
    __shared__ float Bs[16][132];
    const int tid = threadIdx.x;
    const int bn = blockIdx.x;      // 8 column blocks
    const int bm = blockIdx.y;      // 64 row blocks
    const int tm0 = bm * 128, tn0 = bn * 128;
    const int ty = tid >> 4, tx = tid & 15;

    float acc[8][8] = {};

    for (int kb = 0; kb < KTOT / 16; ++kb) {
        const int e = kb >> 4;                 // expert index (K-block of 256)
        const int rbase = (kb & 15) << 4;      // r offset within expert
        const int kglob = kb << 4;
        __syncthreads();
        // stage A (scale x' rows by expert weight)
        #pragma unroll
        for (int h = 0; h < 2; ++h) {
            int f = tid + h * 256;
            int m = f >> 2, k4 = (f & 3) << 2;
            int t = tm0 + m;
            float4 a = *(const float4*)(xp + (size_t)t * RNK + rbase + k4);
            float wv = wts[(size_t)t * NEXP + e];
            As[k4 + 0][m] = a.x * wv;
            As[k4 + 1][m] = a.y * wv;
            As[k4 + 2][m] = a.z * wv;
            As[k4 + 3][m] = a.w * wv;
        }
        // stage B (expand_neurons is exactly [K][D] row-major)
        #pragma unroll
        for (int h = 0; h < 2; ++h) {
            int f = tid + h * 256;
            int kk = f >> 5, d4 = (f & 31) << 2;
            float4 b = *(const float4*)(E + (size_t)(kglob + kk) * DM + tn0 + d4);
            *(float4*)(&Bs[kk][d4]) = b;
        }
        __syncthreads();
        #pragma unroll
        for (int kk = 0; kk < 16; ++kk) {
            float4 a0 = *(const float4*)(&As[kk][ty * 8]);
            float4 a1 = *(const float4*)(&As[kk][ty * 8 + 4]);
            float4 b0 = *(const float4*)(&Bs[kk][tx * 8]);
            float4 b1 = *(const float4*)(&Bs[kk][tx * 8 + 4]);
            float av[8] = {a0.x, a0.y, a0.z, a0.w, a1.x, a1.y, a1.z, a1.w};
            float bv[8] = {b0.x, b0.y, b0.z, b0.w, b1.x, b1.y, b1.z, b1.w};
            #pragma unroll
            for (int i = 0; i < 8; ++i)
                #pragma unroll
                for (int j = 0; j < 8; ++j)
                    acc[i][j] = fmaf(av[i], bv[j], acc[i][j]);
        }
    }
    #pragma unroll
    for (int i = 0; i < 8; ++i) {
        int t = tm0 + ty * 8 + i;
        float* yrow = y + (size_t)t * DM + tn0 + tx * 8;
        *(float4*)yrow       = make_float4(acc[i][0], acc[i][1], acc[i][2], acc[i][3]);
        *(float4*)(yrow + 4) = make_float4(acc[i][4], acc[i][5], acc[i][6], acc[i][7]);
    }
}

// ---------- K3: scores_d -> top2 -> 2 reflections on y (in place) ----------
__global__ __launch_bounds__(256) void k3_post(
    const float* __restrict__ Wd, const float* __restrict__ reflect_d,
    float* __restrict__ y, float* __restrict__ out_id)
{
    __shared__ float ys[4][DM];
    __shared__ float wds[64][17];   // 17 = conflict-free stride
    const int tid = threadIdx.x;
    const int w = tid >> 6, lane = tid & 63;
    const int t = blockIdx.x * 4 + w;

    float4 yv[4];
    #pragma unroll
    for (int c = 0; c < 4; ++c) {
        yv[c] = *(const float4*)(y + (size_t)t * DM + lane * 16 + c * 4);
        *(float4*)(&ys[w][lane * 16 + c * 4]) = yv[c];
    }

    // scores_d: lane n owns Wd row n; Wd staged chunk-wise in LDS (shared by 4 waves)
    double s = 0.0;
    for (int kb = 0; kb < DM / 16; ++kb) {
        __syncthreads();
        {
            int row = tid >> 2, c4 = (tid & 3) << 2;
            float4 wv = *(const float4*)(Wd + (size_t)row * DM + kb * 16 + c4);
            wds[row][c4 + 0] = wv.x; wds[row][c4 + 1] = wv.y;
            wds[row][c4 + 2] = wv.z; wds[row][c4 + 3] = wv.w;
        }
        __syncthreads();
        #pragma unroll
        for (int i = 0; i < 16; ++i)
            s += (double)ys[w][kb * 16 + i] * (double)wds[lane][i];
    }
    int i0, i1;
    top2_64(s, lane, i0, i1);

    #pragma unroll
    for (int rr = 0; rr < 2; ++rr) {
        int idx = rr ? i1 : i0;
        const float* vrow = reflect_d + (size_t)idx * DM + lane * 16;
        float sv = 0.f, vn = 0.f;
        float4 vv[4];
        #pragma unroll
        for (int c = 0; c < 4; ++c) {
            vv[c] = *(const float4*)(vrow + c * 4);
            sv += vv[c].x * yv[c].x + vv[c].y * yv[c].y
                + vv[c].z * yv[c].z + vv[c].w * yv[c].w;
            vn += vv[c].x * vv[c].x + vv[c].y * vv[c].y
                + vv[c].z * vv[c].z + vv[c].w * vv[c].w;
        }
        #pragma unroll
        for (int m = 1; m < 64; m <<= 1) {
            sv += __shfl_xor(sv, m, 64);
            vn += __shfl_xor(vn, m, 64);
        }
        float coef = 2.0f * sv / (vn + 1e-8f);
        #pragma unroll
        for (int c = 0; c < 4; ++c) {
            yv[c].x -= coef * vv[c].x; yv[c].y -= coef * vv[c].y;
            yv[c].z -= coef * vv[c].z; yv[c].w -= coef * vv[c].w;
        }
    }
    #pragma unroll
    for (int c = 0; c < 4; ++c)
        *(float4*)(y + (size_t)t * DM + lane * 16 + c * 4) = yv[c];
    if (lane == 0) {
        out_id[(size_t)t * 2 + 0] = (float)i0;
        out_id[(size_t)t * 2 + 1] = (float)i1;
    }
}

extern "C" void kernel_launch(void* const* d_in, const int* in_sizes, int n_in,
                              void* d_out, int out_size, void* d_ws, size_t ws_size,
                              hipStream_t stream) {
    const float* x  = (const float*)d_in[0];
    const float* Wr = (const float*)d_in[1];
    const float* We = (const float*)d_in[2];
    const float* Wd = (const float*)d_in[3];
    const float* E  = (const float*)d_in[4];
    const float* rr = (const float*)d_in[5];
    const float* rd = (const float*)d_in[6];
    // reflect_k (d_in[7]) is fixed = 2

    float* out    = (float*)d_out;
    float* y      = out + Y_OFF;
    float* out_ir = out + IR_OFF;
    float* out_w  = out + W_OFF;
    float* out_id = out + ID_OFF;
    float* xprime = (float*)d_ws;   // TOK*RNK floats = 8 MB

    k1_tokens<<<TOK / 4, 256, 0, stream>>>(x, Wr, We, rr, xprime, out_ir, out_w);
    dim3 g2(DM / 128, TOK / 128);
    k2_gemm<<<g2, 256, 0, stream>>>(xprime, out_w, E, y);
    k3_post<<<TOK / 4, 256, 0, stream>>>(Wd, rd, y, out_id);
}

// Round 4
// 537.150 us; speedup vs baseline: 2.0110x; 2.0110x over previous
//
#include <hip/hip_runtime.h>
#include <cmath>

#define TOK   8192
#define RNK   256
#define NEXP  16
#define NREF  64
#define DM    1024
#define KTOT  4096

#define Y_OFF  0
#define IR_OFF (TOK*DM)
#define W_OFF  (IR_OFF + TOK*2)
#define ID_OFF (W_OFF + TOK*NEXP)

#define AB_BYTES  ((size_t)TOK * KTOT * 2)        // 64 MB
#define EBT_BYTES ((size_t)DM * KTOT * 2)         // 8 MB
#define XF_BYTES  ((size_t)TOK * RNK * 4)         // 8 MB
#define XH_BYTES  ((size_t)TOK * RNK * 2)         // 4 MB
#define GT_BYTES  ((size_t)NEXP * NREF * RNK * 2) // 512 KB
#define S_BYTES   ((size_t)TOK * NREF * 4)        // 2 MB
#define G64_BYTES ((size_t)NREF * KTOT * 8)       // 2 MB
#define WS_FULL   (AB_BYTES + EBT_BYTES + XF_BYTES + 2*XH_BYTES + 2*GT_BYTES + S_BYTES + G64_BYTES)

typedef __attribute__((ext_vector_type(8))) short short8;
typedef __attribute__((ext_vector_type(4))) float f32x4;
typedef const __attribute__((address_space(1))) void* gptr_t;
typedef __attribute__((address_space(3))) void* lptr_t;

__device__ inline unsigned short f2bf(float f) {    // RNE float->bf16
    unsigned int u = __float_as_uint(f);
    return (unsigned short)((u + 0x7fffu + ((u >> 16) & 1u)) >> 16);
}
__device__ inline float bf2f(unsigned short h) {
    return __uint_as_float(((unsigned int)h) << 16);
}
__device__ inline void split2(float v, unsigned short& h, unsigned short& l) {
    h = f2bf(v);
    l = f2bf(v - bf2f(h));
}
__device__ inline unsigned long long pack4(unsigned short a, unsigned short b,
                                           unsigned short c, unsigned short d) {
    return (unsigned long long)a | ((unsigned long long)b << 16)
         | ((unsigned long long)c << 32) | ((unsigned long long)d << 48);
}

// ---------- top-2 across a 64-lane wave, lax.top_k tie semantics ----------
__device__ inline void top2_64(double v, int idx, int& i0, int& i1) {
    double bv = v; int bi = idx;
    #pragma unroll
    for (int m = 1; m < 64; m <<= 1) {
        double ov = __shfl_xor(bv, m, 64);
        int    oi = __shfl_xor(bi, m, 64);
        if (ov > bv || (ov == bv && oi < bi)) { bv = ov; bi = oi; }
    }
    i0 = bi;
    double v2 = (idx == i0) ? -INFINITY : v;
    double bv2 = v2; int bi2 = idx;
    #pragma unroll
    for (int m = 1; m < 64; m <<= 1) {
        double ov = __shfl_xor(bv2, m, 64);
        int    oi = __shfl_xor(bi2, m, 64);
        if (ov > bv2 || (ov == bv2 && oi < bi2)) { bv2 = ov; bi2 = oi; }
    }
    i1 = bi2;
}

// ---------- K1: scores_r -> top2 -> reflections -> scores_e -> softmax ----
__global__ __launch_bounds__(256) void k1_tokens(
    const float* __restrict__ x, const float* __restrict__ Wr,
    const float* __restrict__ We, const float* __restrict__ reflect_r,
    float* __restrict__ xprime, unsigned short* __restrict__ Ab,
    unsigned short* __restrict__ Xh, unsigned short* __restrict__ Xl,
    float* __restrict__ out_ir, float* __restrict__ out_w, int mode)
{
    __shared__ float xs[4][RNK];
    const int tid = threadIdx.x;
    const int w = tid >> 6, lane = tid & 63;
    const int t = blockIdx.x * 4 + w;

    float4 xv = *(const float4*)(x + (size_t)t * RNK + lane * 4);
    *(float4*)(&xs[w][lane * 4]) = xv;
    __syncthreads();

    double s = 0.0;
    {
        const float* wrow = Wr + (size_t)lane * RNK;
        for (int r4 = 0; r4 < RNK / 4; ++r4) {
            float4 xr = *(const float4*)(&xs[w][r4 * 4]);
            float4 wr = *(const float4*)(wrow + r4 * 4);
            s += (double)xr.x * wr.x + (double)xr.y * wr.y
               + (double)xr.z * wr.z + (double)xr.w * wr.w;
        }
    }
    int i0, i1;
    top2_64(s, lane, i0, i1);

    #pragma unroll
    for (int rr = 0; rr < 2; ++rr) {
        int idx = rr ? i1 : i0;
        float4 vv = *(const float4*)(reflect_r + (size_t)idx * RNK + lane * 4);
        float sv = vv.x * xv.x + vv.y * xv.y + vv.z * xv.z + vv.w * xv.w;
        float vn = vv.x * vv.x + vv.y * vv.y + vv.z * vv.z + vv.w * vv.w;
        #pragma unroll
        for (int m = 1; m < 64; m <<= 1) {
            sv += __shfl_xor(sv, m, 64);
            vn += __shfl_xor(vn, m, 64);
        }
        float coef = 2.0f * sv / (vn + 1e-8f);
        xv.x -= coef * vv.x; xv.y -= coef * vv.y;
        xv.z -= coef * vv.z; xv.w -= coef * vv.w;
    }
    __syncthreads();
    *(float4*)(&xs[w][lane * 4]) = xv;
    __syncthreads();

    // exact fp32 x' (needed by refine + fallback GEMM)
    *(float4*)(xprime + (size_t)t * RNK + lane * 4) = xv;

    const int n = lane & 15;
    double se = 0.0;
    {
        const float* werow = We + (size_t)n * RNK;
        for (int r4 = 0; r4 < RNK / 4; ++r4) {
            float4 xr = *(const float4*)(&xs[w][r4 * 4]);
            float4 wf = *(const float4*)(werow + r4 * 4);
            se += (double)xr.x * wf.x + (double)xr.y * wf.y
                + (double)xr.z * wf.z + (double)xr.w * wf.w;
        }
    }
    float sef = (float)se;
    float mx = sef;
    #pragma unroll
    for (int m = 1; m < 16; m <<= 1) mx = fmaxf(mx, __shfl_xor(mx, m, 64));
    float ex = expf(sef - mx);
    float sm = ex;
    #pragma unroll
    for (int m = 1; m < 16; m <<= 1) sm += __shfl_xor(sm, m, 64);
    float wgt = ex / sm;

    if (lane < NEXP) out_w[(size_t)t * NEXP + lane] = wgt;
    if (lane == 0) {
        out_ir[(size_t)t * 2 + 0] = (float)i0;
        out_ir[(size_t)t * 2 + 1] = (float)i1;
    }

    if (mode) {
        unsigned short hx, lx, hy, ly, hz, lz, hw, lw;
        split2(xv.x, hx, lx); split2(xv.y, hy, ly);
        split2(xv.z, hz, lz); split2(xv.w, hw, lw);
        *(unsigned long long*)&Xh[(size_t)t * RNK + lane * 4] = pack4(hx, hy, hz, hw);
        *(unsigned long long*)&Xl[(size_t)t * RNK + lane * 4] = pack4(lx, ly, lz, lw);
        #pragma unroll
        for (int e = 0; e < NEXP; ++e) {
            float we = __shfl(wgt, e, 64);
            *(unsigned long long*)&Ab[(size_t)t * KTOT + e * RNK + lane * 4] =
                pack4(f2bf(we * xv.x), f2bf(we * xv.y),
                      f2bf(we * xv.z), f2bf(we * xv.w));
        }
    }
}

// ---------- E transpose+convert: Ebt[d][k] = bf16(E[k][d]) ----------
__global__ __launch_bounds__(256) void e_transpose(
    const float* __restrict__ E, unsigned short* __restrict__ Ebt)
{
    __shared__ float lds[64][68];
    const int tid = threadIdx.x;
    const int k0 = blockIdx.x * 64, d0 = blockIdx.y * 64;
    #pragma unroll
    for (int rep = 0; rep < 4; ++rep) {
        int idx = rep * 256 + tid;
        int r = idx >> 4, c4 = (idx & 15) << 2;
        float4 v = *(const float4*)(E + (size_t)(k0 + r) * DM + d0 + c4);
        lds[r][c4 + 0] = v.x; lds[r][c4 + 1] = v.y;
        lds[r][c4 + 2] = v.z; lds[r][c4 + 3] = v.w;
    }
    __syncthreads();
    #pragma unroll
    for (int rep = 0; rep < 4; ++rep) {
        int idx = rep * 256 + tid;
        int dr = idx >> 4, kc4 = (idx & 15) << 2;
        *(unsigned long long*)&Ebt[(size_t)(d0 + dr) * KTOT + k0 + kc4] =
            pack4(f2bf(lds[kc4 + 0][dr]), f2bf(lds[kc4 + 1][dr]),
                  f2bf(lds[kc4 + 2][dr]), f2bf(lds[kc4 + 3][dr]));
    }
}

// ---------- G (fp64): G64t[n][k] = sum_d E[k,d]*Wd[n,d]; also bf16 hi/lo ----
__global__ __launch_bounds__(256) void g_fp64(
    const float* __restrict__ E, const float* __restrict__ Wd,
    double* __restrict__ G64t,
    unsigned short* __restrict__ Gth, unsigned short* __restrict__ Gtl)
{
    const int tid = threadIdx.x;
    const int kk = tid >> 6;            // wave id 0..3 -> k row
    const int n  = tid & 63;
    const int k  = blockIdx.x * 4 + kk;
    const float* erow = E  + (size_t)k * DM;   // broadcast within wave
    const float* wrow = Wd + (size_t)n * DM;
    double acc = 0.0;
    for (int d4 = 0; d4 < DM; d4 += 4) {
        float4 e4 = *(const float4*)(erow + d4);
        float4 w4 = *(const float4*)(wrow + d4);
        acc = fma((double)e4.x, (double)w4.x, acc);
        acc = fma((double)e4.y, (double)w4.y, acc);
        acc = fma((double)e4.z, (double)w4.z, acc);
        acc = fma((double)e4.w, (double)w4.w, acc);
    }
    G64t[(size_t)n * KTOT + k] = acc;
    float gf = (float)acc;
    unsigned short h, lo;
    split2(gf, h, lo);
    const int e = k >> 8, r = k & 255;
    Gth[((size_t)(e * NREF + n)) * RNK + r] = h;
    Gtl[((size_t)(e * NREF + n)) * RNK + r] = lo;
}

// ---------- S approx: S[t][n] = sum_e w[t,e]*(x'[t,:].G_e[:,n]) ----------
__global__ __launch_bounds__(256) void s_mfma(
    const unsigned short* __restrict__ Xh, const unsigned short* __restrict__ Xl,
    const unsigned short* __restrict__ Gth, const unsigned short* __restrict__ Gtl,
    const float* __restrict__ wts, float* __restrict__ S)
{
    __shared__ float red[4][16][64];
    const int tid = threadIdx.x, l = tid & 63, w = tid >> 6;
    const int t0 = blockIdx.x * 16;

    short8 ah[8], al[8];
    {
        const size_t abase = (size_t)(t0 + (l & 15)) * RNK + (l >> 4) * 8;
        #pragma unroll
        for (int ks = 0; ks < 8; ++ks) {
            ah[ks] = *(const short8*)&Xh[abase + ks * 32];
            al[ks] = *(const short8*)&Xl[abase + ks * 32];
        }
    }

    f32x4 Sacc[4] = {};
    #pragma unroll
    for (int ei = 0; ei < 4; ++ei) {
        const int e = w * 4 + ei;
        f32x4 acc[4] = {};
        #pragma unroll
        for (int ks = 0; ks < 8; ++ks) {
            #pragma unroll
            for (int nn = 0; nn < 4; ++nn) {
                size_t gbase = ((size_t)(e * NREF + nn * 16 + (l & 15))) * RNK
                             + ks * 32 + (l >> 4) * 8;
                short8 bh = *(const short8*)&Gth[gbase];
                short8 bl = *(const short8*)&Gtl[gbase];
                acc[nn] = __builtin_amdgcn_mfma_f32_16x16x32_bf16(al[ks], bh, acc[nn], 0, 0, 0);
                acc[nn] = __builtin_amdgcn_mfma_f32_16x16x32_bf16(ah[ks], bl, acc[nn], 0, 0, 0);
                acc[nn] = __builtin_amdgcn_mfma_f32_16x16x32_bf16(ah[ks], bh, acc[nn], 0, 0, 0);
            }
        }
        #pragma unroll
        for (int j = 0; j < 4; ++j) {
            float wv = wts[(size_t)(t0 + (l >> 4) * 4 + j) * NEXP + e];
            #pragma unroll
            for (int nn = 0; nn < 4; ++nn) Sacc[nn][j] += wv * acc[nn][j];
        }
    }
    #pragma unroll
    for (int nn = 0; nn < 4; ++nn)
        #pragma unroll
        for (int j = 0; j < 4; ++j)
            red[w][(l >> 4) * 4 + j][nn * 16 + (l & 15)] = Sacc[nn][j];
    __syncthreads();
    for (int i = tid; i < 16 * 64; i += 256) {
        int tt = i >> 6, nn = i & 63;
        float sv = red[0][tt][nn] + red[1][tt][nn] + red[2][tt][nn] + red[3][tt][nn];
        S[(size_t)(t0 + tt) * NREF + nn] = sv;
    }
}

// ---------- refine: approx top-4 -> exact fp64 scores -> top-2 ----------
__global__ __launch_bounds__(256) void refine_top2(
    const float* __restrict__ S, const double* __restrict__ G64t,
    const float* __restrict__ xf, const float* __restrict__ wts,
    float* __restrict__ out_id)
{
    __shared__ float xs[4][RNK];
    __shared__ float wsh[4][NEXP];
    const int tid = threadIdx.x, w = tid >> 6, lane = tid & 63;
    const int t = blockIdx.x * 4 + w;

    *(float4*)&xs[w][lane * 4] = *(const float4*)(xf + (size_t)t * RNK + lane * 4);
    if (lane < NEXP) wsh[w][lane] = wts[(size_t)t * NEXP + lane];
    __syncthreads();

    // approx top-4 (tie -> lower index)
    float cur = S[(size_t)t * NREF + lane];
    int cand[4];
    #pragma unroll
    for (int c = 0; c < 4; ++c) {
        float bv = cur; int bi = lane;
        #pragma unroll
        for (int m = 1; m < 64; m <<= 1) {
            float ov = __shfl_xor(bv, m, 64);
            int   oi = __shfl_xor(bi, m, 64);
            if (ov > bv || (ov == bv && oi < bi)) { bv = ov; bi = oi; }
        }
        cand[c] = bi;
        if (lane == bi) cur = -INFINITY;
    }

    // exact fp64 re-score of the 4 candidates
    double rs[4];
    #pragma unroll
    for (int c = 0; c < 4; ++c) {
        const double* grow = G64t + (size_t)cand[c] * KTOT;
        double acc = 0.0;
        #pragma unroll 4
        for (int i = 0; i < 64; ++i) {
            int k = i * 64 + lane;                       // coalesced G read
            double a = (double)wsh[w][k >> 8] * (double)xs[w][k & 255];
            acc = fma(a, grow[k], acc);
        }
        #pragma unroll
        for (int m = 1; m < 64; m <<= 1) acc += __shfl_xor(acc, m, 64);
        rs[c] = acc;
    }

    // top-2 among candidates, lax tie semantics on the ORIGINAL index
    int b0 = 0;
    #pragma unroll
    for (int c = 1; c < 4; ++c)
        if (rs[c] > rs[b0] || (rs[c] == rs[b0] && cand[c] < cand[b0])) b0 = c;
    int b1 = (b0 == 0) ? 1 : 0;
    #pragma unroll
    for (int c = 0; c < 4; ++c) {
        if (c == b0) continue;
        if (rs[c] > rs[b1] || (rs[c] == rs[b1] && cand[c] < cand[b1])) b1 = c;
    }
    if (lane == 0) {
        out_id[(size_t)t * 2 + 0] = (float)cand[b0];
        out_id[(size_t)t * 2 + 1] = (float)cand[b1];
    }
}

// ---------- K2 (MFMA): y = Ab @ Ebt^T.  M=8192 N=1024 K=4096 bf16 ----------
__global__ __launch_bounds__(256) void k2_mfma(
    const unsigned short* __restrict__ Ab,
    const unsigned short* __restrict__ Ebt,
    float* __restrict__ y)
{
    __shared__ unsigned short As[128 * 32];
    __shared__ unsigned short Bs[128 * 32];
    const int tid = threadIdx.x;
    const int l = tid & 63, w = tid >> 6;
    const int wr = w >> 1, wc = w & 1;
    const int tm0 = blockIdx.y * 128, n0 = blockIdx.x * 128;
    const int lrow = l >> 2, s = l & 3, g = l >> 4;

    f32x4 acc[4][4] = {};

    for (int kb = 0; kb < KTOT / 32; ++kb) {
        __syncthreads();
        #pragma unroll
        for (int i = 0; i < 2; ++i) {
            int row = w * 32 + i * 16 + lrow;
            int sw = ((s ^ (row & 3)) << 4);
            const char* ga = (const char*)Ab
                + ((size_t)(tm0 + row) * KTOT + kb * 32) * 2 + sw;
            __builtin_amdgcn_global_load_lds((gptr_t)ga,
                (lptr_t)&As[(w * 32 + i * 16) * 32], 16, 0, 0);
            const char* gb = (const char*)Ebt
                + ((size_t)(n0 + row) * KTOT + kb * 32) * 2 + sw;
            __builtin_amdgcn_global_load_lds((gptr_t)gb,
                (lptr_t)&Bs[(w * 32 + i * 16) * 32], 16, 0, 0);
        }
        __syncthreads();

        short8 af[4], bv[4];
        #pragma unroll
        for (int m = 0; m < 4; ++m) {
            int row = wr * 64 + m * 16 + (l & 15);
            af[m] = *(const short8*)&As[row * 32 + ((g ^ (row & 3)) << 3)];
        }
        #pragma unroll
        for (int nn = 0; nn < 4; ++nn) {
            int row = wc * 64 + nn * 16 + (l & 15);
            bv[nn] = *(const short8*)&Bs[row * 32 + ((g ^ (row & 3)) << 3)];
        }
        #pragma unroll
        for (int m = 0; m < 4; ++m)
            #pragma unroll
            for (int nn = 0; nn < 4; ++nn)
                acc[m][nn] = __builtin_amdgcn_mfma_f32_16x16x32_bf16(
                    af[m], bv[nn], acc[m][nn], 0, 0, 0);
    }

    #pragma unroll
    for (int m = 0; m < 4; ++m) {
        int rbase = tm0 + wr * 64 + m * 16 + (l >> 4) * 4;
        #pragma unroll
        for (int nn = 0; nn < 4; ++nn) {
            int c = n0 + wc * 64 + nn * 16 + (l & 15);
            #pragma unroll
            for (int j = 0; j < 4; ++j)
                y[(size_t)(rbase + j) * DM + c] = acc[m][nn][j];
        }
    }
}

// ---------- K2 fp32 fallback ----------
__global__ __launch_bounds__(256) void k2_gemm(
    const float* __restrict__ xp, const float* __restrict__ wts,
    const float* __restrict__ E, float* __restrict__ y)
{
    __shared__ float As[16][132];
    __shared__ float Bs[16][132];
    const int tid = threadIdx.x;
    const int bn = blockIdx.x, bm = blockIdx.y;
    const int tm0 = bm * 128, tn0 = bn * 128;
    const int ty = tid >> 4, tx = tid & 15;
    float acc[8][8] = {};
    for (int kb = 0; kb < KTOT / 16; ++kb) {
        const int e = kb >> 4;
        const int rbase = (kb & 15) << 4;
        const int kglob = kb << 4;
        __syncthreads();
        #pragma unroll
        for (int h = 0; h < 2; ++h) {
            int f = tid + h * 256;
            int m = f >> 2, k4 = (f & 3) << 2;
            int t = tm0 + m;
            float4 a = *(const float4*)(xp + (size_t)t * RNK + rbase + k4);
            float wv = wts[(size_t)t * NEXP + e];
            As[k4 + 0][m] = a.x * wv; As[k4 + 1][m] = a.y * wv;
            As[k4 + 2][m] = a.z * wv; As[k4 + 3][m] = a.w * wv;
        }
        #pragma unroll
        for (int h = 0; h < 2; ++h) {
            int f = tid + h * 256;
            int kk = f >> 5, d4 = (f & 31) << 2;
            float4 b = *(const float4*)(E + (size_t)(kglob + kk) * DM + tn0 + d4);
            *(float4*)(&Bs[kk][d4]) = b;
        }
        __syncthreads();
        #pragma unroll
        for (int kk = 0; kk < 16; ++kk) {
            float4 a0 = *(const float4*)(&As[kk][ty * 8]);
            float4 a1 = *(const float4*)(&As[kk][ty * 8 + 4]);
            float4 b0 = *(const float4*)(&Bs[kk][tx * 8]);
            float4 b1 = *(const float4*)(&Bs[kk][tx * 8 + 4]);
            float av[8] = {a0.x, a0.y, a0.z, a0.w, a1.x, a1.y, a1.z, a1.w};
            float bw[8] = {b0.x, b0.y, b0.z, b0.w, b1.x, b1.y, b1.z, b1.w};
            #pragma unroll
            for (int i = 0; i < 8; ++i)
                #pragma unroll
                for (int j = 0; j < 8; ++j)
                    acc[i][j] = fmaf(av[i], bw[j], acc[i][j]);
        }
    }
    #pragma unroll
    for (int i = 0; i < 8; ++i) {
        int t = tm0 + ty * 8 + i;
        float* yrow = y + (size_t)t * DM + tn0 + tx * 8;
        *(float4*)yrow       = make_float4(acc[i][0], acc[i][1], acc[i][2], acc[i][3]);
        *(float4*)(yrow + 4) = make_float4(acc[i][4], acc[i][5], acc[i][6], acc[i][7]);
    }
}

// ---------- K3: read refined indices -> 2 reflections on y (in place) -----
__global__ __launch_bounds__(256) void k3_post(
    const float* __restrict__ out_id, const float* __restrict__ reflect_d,
    float* __restrict__ y)
{
    const int tid = threadIdx.x;
    const int w = tid >> 6, lane = tid & 63;
    const int t = blockIdx.x * 4 + w;

    float4 yv[4];
    #pragma unroll
    for (int c = 0; c < 4; ++c)
        yv[c] = *(const float4*)(y + (size_t)t * DM + lane * 16 + c * 4);

    const int i0 = (int)out_id[(size_t)t * 2 + 0];
    const int i1 = (int)out_id[(size_t)t * 2 + 1];

    #pragma unroll
    for (int rr = 0; rr < 2; ++rr) {
        int idx = rr ? i1 : i0;
        const float* vrow = reflect_d + (size_t)idx * DM + lane * 16;
        float sv = 0.f, vn = 0.f;
        float4 vv[4];
        #pragma unroll
        for (int c = 0; c < 4; ++c) {
            vv[c] = *(const float4*)(vrow + c * 4);
            sv += vv[c].x * yv[c].x + vv[c].y * yv[c].y
                + vv[c].z * yv[c].z + vv[c].w * yv[c].w;
            vn += vv[c].x * vv[c].x + vv[c].y * vv[c].y
                + vv[c].z * vv[c].z + vv[c].w * vv[c].w;
        }
        #pragma unroll
        for (int m = 1; m < 64; m <<= 1) {
            sv += __shfl_xor(sv, m, 64);
            vn += __shfl_xor(vn, m, 64);
        }
        float coef = 2.0f * sv / (vn + 1e-8f);
        #pragma unroll
        for (int c = 0; c < 4; ++c) {
            yv[c].x -= coef * vv[c].x; yv[c].y -= coef * vv[c].y;
            yv[c].z -= coef * vv[c].z; yv[c].w -= coef * vv[c].w;
        }
    }
    #pragma unroll
    for (int c = 0; c < 4; ++c)
        *(float4*)(y + (size_t)t * DM + lane * 16 + c * 4) = yv[c];
}

// ---------- K3 fallback (scores_d from fp32 y, top2, reflect) ----------
__global__ __launch_bounds__(256) void k3_full(
    const float* __restrict__ Wd, const float* __restrict__ reflect_d,
    float* __restrict__ y, float* __restrict__ out_id)
{
    __shared__ float ys[4][DM];
    __shared__ float wds[64][17];
    const int tid = threadIdx.x;
    const int w = tid >> 6, lane = tid & 63;
    const int t = blockIdx.x * 4 + w;

    float4 yv[4];
    #pragma unroll
    for (int c = 0; c < 4; ++c) {
        yv[c] = *(const float4*)(y + (size_t)t * DM + lane * 16 + c * 4);
        *(float4*)(&ys[w][lane * 16 + c * 4]) = yv[c];
    }
    double s = 0.0;
    for (int kb = 0; kb < DM / 16; ++kb) {
        __syncthreads();
        {
            int row = tid >> 2, c4 = (tid & 3) << 2;
            float4 wv = *(const float4*)(Wd + (size_t)row * DM + kb * 16 + c4);
            wds[row][c4 + 0] = wv.x; wds[row][c4 + 1] = wv.y;
            wds[row][c4 + 2] = wv.z; wds[row][c4 + 3] = wv.w;
        }
        __syncthreads();
        #pragma unroll
        for (int i = 0; i < 16; ++i)
            s += (double)ys[w][kb * 16 + i] * (double)wds[lane][i];
    }
    int i0, i1;
    top2_64(s, lane, i0, i1);
    #pragma unroll
    for (int rr = 0; rr < 2; ++rr) {
        int idx = rr ? i1 : i0;
        const float* vrow = reflect_d + (size_t)idx * DM + lane * 16;
        float sv = 0.f, vn = 0.f;
        float4 vv[4];
        #pragma unroll
        for (int c = 0; c < 4; ++c) {
            vv[c] = *(const float4*)(vrow + c * 4);
            sv += vv[c].x * yv[c].x + vv[c].y * yv[c].y
                + vv[c].z * yv[c].z + vv[c].w * yv[c].w;
            vn += vv[c].x * vv[c].x + vv[c].y * vv[c].y
                + vv[c].z * vv[c].z + vv[c].w * vv[c].w;
        }
        #pragma unroll
        for (int m = 1; m < 64; m <<= 1) {
            sv += __shfl_xor(sv, m, 64);
            vn += __shfl_xor(vn, m, 64);
        }
        float coef = 2.0f * sv / (vn + 1e-8f);
        #pragma unroll
        for (int c = 0; c < 4; ++c) {
            yv[c].x -= coef * vv[c].x; yv[c].y -= coef * vv[c].y;
            yv[c].z -= coef * vv[c].z; yv[c].w -= coef * vv[c].w;
        }
    }
    #pragma unroll
    for (int c = 0; c < 4; ++c)
        *(float4*)(y + (size_t)t * DM + lane * 16 + c * 4) = yv[c];
    if (lane == 0) {
        out_id[(size_t)t * 2 + 0] = (float)i0;
        out_id[(size_t)t * 2 + 1] = (float)i1;
    }
}

extern "C" void kernel_launch(void* const* d_in, const int* in_sizes, int n_in,
                              void* d_out, int out_size, void* d_ws, size_t ws_size,
                              hipStream_t stream) {
    const float* x  = (const float*)d_in[0];
    const float* Wr = (const float*)d_in[1];
    const float* We = (const float*)d_in[2];
    const float* Wd = (const float*)d_in[3];
    const float* E  = (const float*)d_in[4];
    const float* rr = (const float*)d_in[5];
    const float* rd = (const float*)d_in[6];

    float* out    = (float*)d_out;
    float* y      = out + Y_OFF;
    float* out_ir = out + IR_OFF;
    float* out_w  = out + W_OFF;
    float* out_id = out + ID_OFF;

    if (ws_size >= WS_FULL) {
        char* p = (char*)d_ws;
        unsigned short* Ab  = (unsigned short*)p;  p += AB_BYTES;
        unsigned short* Ebt = (unsigned short*)p;  p += EBT_BYTES;
        float*          Xf  = (float*)p;           p += XF_BYTES;
        unsigned short* Xh  = (unsigned short*)p;  p += XH_BYTES;
        unsigned short* Xl  = (unsigned short*)p;  p += XH_BYTES;
        unsigned short* Gth = (unsigned short*)p;  p += GT_BYTES;
        unsigned short* Gtl = (unsigned short*)p;  p += GT_BYTES;
        float*          Sb  = (float*)p;           p += S_BYTES;
        double*         G64 = (double*)p;

        e_transpose<<<dim3(KTOT / 64, DM / 64), 256, 0, stream>>>(E, Ebt);
        g_fp64<<<KTOT / 4, 256, 0, stream>>>(E, Wd, G64, Gth, Gtl);
        k1_tokens<<<TOK / 4, 256, 0, stream>>>(x, Wr, We, rr, Xf, Ab,
                                               Xh, Xl, out_ir, out_w, 1);
        k2_mfma<<<dim3(DM / 128, TOK / 128), 256, 0, stream>>>(Ab, Ebt, y);
        s_mfma<<<TOK / 16, 256, 0, stream>>>(Xh, Xl, Gth, Gtl, out_w, Sb);
        refine_top2<<<TOK / 4, 256, 0, stream>>>(Sb, G64, Xf, out_w, out_id);
        k3_post<<<TOK / 4, 256, 0, stream>>>(out_id, rd, y);
    } else {
        float* xprime = (float*)d_ws;
        k1_tokens<<<TOK / 4, 256, 0, stream>>>(x, Wr, We, rr, xprime, nullptr,
                                               nullptr, nullptr, out_ir, out_w, 0);
        k2_gemm<<<dim3(DM / 128, TOK / 128), 256, 0, stream>>>(xprime, out_w, E, y);
        k3_full<<<TOK / 4, 256, 0, stream>>>(Wd, rd, y, out_id);
    }
}

// Round 5
// 502.467 us; speedup vs baseline: 2.1498x; 1.0690x over previous
//
#include <hip/hip_runtime.h>
#include <cmath>

#define TOK   8192
#define RNK   256
#define NEXP  16
#define NREF  64
#define DM    1024
#define KTOT  4096

#define Y_OFF  0
#define IR_OFF (TOK*DM)
#define W_OFF  (IR_OFF + TOK*2)
#define ID_OFF (W_OFF + TOK*NEXP)

#define AB_BYTES  ((size_t)TOK * KTOT * 2)        // 64 MB
#define EBT_BYTES ((size_t)DM * KTOT * 2)         // 8 MB
#define XF_BYTES  ((size_t)TOK * RNK * 4)         // 8 MB
#define XH_BYTES  ((size_t)TOK * RNK * 2)         // 4 MB
#define GT_BYTES  ((size_t)NEXP * NREF * RNK * 2) // 512 KB
#define S_BYTES   ((size_t)TOK * NREF * 4)        // 2 MB
#define G64_BYTES ((size_t)NREF * KTOT * 8)       // 2 MB
#define WS_FULL   (AB_BYTES + EBT_BYTES + XF_BYTES + 2*XH_BYTES + 2*GT_BYTES + S_BYTES + G64_BYTES)

typedef __attribute__((ext_vector_type(8))) short short8;
typedef __attribute__((ext_vector_type(4))) float f32x4;
typedef const __attribute__((address_space(1))) void* gptr_t;
typedef __attribute__((address_space(3))) void* lptr_t;

__device__ inline unsigned short f2bf(float f) {    // RNE float->bf16
    unsigned int u = __float_as_uint(f);
    return (unsigned short)((u + 0x7fffu + ((u >> 16) & 1u)) >> 16);
}
__device__ inline float bf2f(unsigned short h) {
    return __uint_as_float(((unsigned int)h) << 16);
}
__device__ inline void split2(float v, unsigned short& h, unsigned short& l) {
    h = f2bf(v);
    l = f2bf(v - bf2f(h));
}
__device__ inline unsigned long long pack4(unsigned short a, unsigned short b,
                                           unsigned short c, unsigned short d) {
    return (unsigned long long)a | ((unsigned long long)b << 16)
         | ((unsigned long long)c << 32) | ((unsigned long long)d << 48);
}

// ---------- top-2 across a 64-lane wave, lax.top_k tie semantics ----------
__device__ inline void top2_64(double v, int idx, int& i0, int& i1) {
    double bv = v; int bi = idx;
    #pragma unroll
    for (int m = 1; m < 64; m <<= 1) {
        double ov = __shfl_xor(bv, m, 64);
        int    oi = __shfl_xor(bi, m, 64);
        if (ov > bv || (ov == bv && oi < bi)) { bv = ov; bi = oi; }
    }
    i0 = bi;
    double v2 = (idx == i0) ? -INFINITY : v;
    double bv2 = v2; int bi2 = idx;
    #pragma unroll
    for (int m = 1; m < 64; m <<= 1) {
        double ov = __shfl_xor(bv2, m, 64);
        int    oi = __shfl_xor(bi2, m, 64);
        if (ov > bv2 || (ov == bv2 && oi < bi2)) { bv2 = ov; bi2 = oi; }
    }
    i1 = bi2;
}

// ---------- K1: scores_r -> top2 -> reflections -> scores_e -> softmax ----
__global__ __launch_bounds__(256) void k1_tokens(
    const float* __restrict__ x, const float* __restrict__ Wr,
    const float* __restrict__ We, const float* __restrict__ reflect_r,
    float* __restrict__ xprime, unsigned short* __restrict__ Ab,
    unsigned short* __restrict__ Xh, unsigned short* __restrict__ Xl,
    float* __restrict__ out_ir, float* __restrict__ out_w, int mode)
{
    __shared__ float xs[4][RNK];
    const int tid = threadIdx.x;
    const int w = tid >> 6, lane = tid & 63;
    const int t = blockIdx.x * 4 + w;

    float4 xv = *(const float4*)(x + (size_t)t * RNK + lane * 4);
    *(float4*)(&xs[w][lane * 4]) = xv;
    __syncthreads();

    double s = 0.0;
    {
        const float* wrow = Wr + (size_t)lane * RNK;
        for (int r4 = 0; r4 < RNK / 4; ++r4) {
            float4 xr = *(const float4*)(&xs[w][r4 * 4]);
            float4 wr = *(const float4*)(wrow + r4 * 4);
            s += (double)xr.x * wr.x + (double)xr.y * wr.y
               + (double)xr.z * wr.z + (double)xr.w * wr.w;
        }
    }
    int i0, i1;
    top2_64(s, lane, i0, i1);

    #pragma unroll
    for (int rr = 0; rr < 2; ++rr) {
        int idx = rr ? i1 : i0;
        float4 vv = *(const float4*)(reflect_r + (size_t)idx * RNK + lane * 4);
        float sv = vv.x * xv.x + vv.y * xv.y + vv.z * xv.z + vv.w * xv.w;
        float vn = vv.x * vv.x + vv.y * vv.y + vv.z * vv.z + vv.w * vv.w;
        #pragma unroll
        for (int m = 1; m < 64; m <<= 1) {
            sv += __shfl_xor(sv, m, 64);
            vn += __shfl_xor(vn, m, 64);
        }
        float coef = 2.0f * sv / (vn + 1e-8f);
        xv.x -= coef * vv.x; xv.y -= coef * vv.y;
        xv.z -= coef * vv.z; xv.w -= coef * vv.w;
    }
    __syncthreads();
    *(float4*)(&xs[w][lane * 4]) = xv;
    __syncthreads();

    *(float4*)(xprime + (size_t)t * RNK + lane * 4) = xv;

    const int n = lane & 15;
    double se = 0.0;
    {
        const float* werow = We + (size_t)n * RNK;
        for (int r4 = 0; r4 < RNK / 4; ++r4) {
            float4 xr = *(const float4*)(&xs[w][r4 * 4]);
            float4 wf = *(const float4*)(werow + r4 * 4);
            se += (double)xr.x * wf.x + (double)xr.y * wf.y
                + (double)xr.z * wf.z + (double)xr.w * wf.w;
        }
    }
    float sef = (float)se;
    float mx = sef;
    #pragma unroll
    for (int m = 1; m < 16; m <<= 1) mx = fmaxf(mx, __shfl_xor(mx, m, 64));
    float ex = expf(sef - mx);
    float sm = ex;
    #pragma unroll
    for (int m = 1; m < 16; m <<= 1) sm += __shfl_xor(sm, m, 64);
    float wgt = ex / sm;

    if (lane < NEXP) out_w[(size_t)t * NEXP + lane] = wgt;
    if (lane == 0) {
        out_ir[(size_t)t * 2 + 0] = (float)i0;
        out_ir[(size_t)t * 2 + 1] = (float)i1;
    }

    if (mode) {
        unsigned short hx, lx, hy, ly, hz, lz, hw, lw;
        split2(xv.x, hx, lx); split2(xv.y, hy, ly);
        split2(xv.z, hz, lz); split2(xv.w, hw, lw);
        *(unsigned long long*)&Xh[(size_t)t * RNK + lane * 4] = pack4(hx, hy, hz, hw);
        *(unsigned long long*)&Xl[(size_t)t * RNK + lane * 4] = pack4(lx, ly, lz, lw);
        #pragma unroll
        for (int e = 0; e < NEXP; ++e) {
            float we = __shfl(wgt, e, 64);
            *(unsigned long long*)&Ab[(size_t)t * KTOT + e * RNK + lane * 4] =
                pack4(f2bf(we * xv.x), f2bf(we * xv.y),
                      f2bf(we * xv.z), f2bf(we * xv.w));
        }
    }
}

// ---------- E transpose+convert: Ebt[d][k] = bf16(E[k][d]) ----------
__global__ __launch_bounds__(256) void e_transpose(
    const float* __restrict__ E, unsigned short* __restrict__ Ebt)
{
    __shared__ float lds[64][68];
    const int tid = threadIdx.x;
    const int k0 = blockIdx.x * 64, d0 = blockIdx.y * 64;
    #pragma unroll
    for (int rep = 0; rep < 4; ++rep) {
        int idx = rep * 256 + tid;
        int r = idx >> 4, c4 = (idx & 15) << 2;
        float4 v = *(const float4*)(E + (size_t)(k0 + r) * DM + d0 + c4);
        lds[r][c4 + 0] = v.x; lds[r][c4 + 1] = v.y;
        lds[r][c4 + 2] = v.z; lds[r][c4 + 3] = v.w;
    }
    __syncthreads();
    #pragma unroll
    for (int rep = 0; rep < 4; ++rep) {
        int idx = rep * 256 + tid;
        int dr = idx >> 4, kc4 = (idx & 15) << 2;
        *(unsigned long long*)&Ebt[(size_t)(d0 + dr) * KTOT + k0 + kc4] =
            pack4(f2bf(lds[kc4 + 0][dr]), f2bf(lds[kc4 + 1][dr]),
                  f2bf(lds[kc4 + 2][dr]), f2bf(lds[kc4 + 3][dr]));
    }
}

// ---------- G (fp64, LDS-tiled): G64t[n][k] = sum_d E[k,d]*Wd[n,d] ---------
// Block = 16 k-rows x 64 n; Wd staged transposed in LDS (coalesced global
// reads over d, <=2-way bank aliasing on both write and read). E rows are
// wave-uniform -> scalar loads. Accumulation order over d identical to the
// previous version (sequential) -> bit-identical G64.
__global__ __launch_bounds__(256) void g_fp64(
    const float* __restrict__ E, const float* __restrict__ Wd,
    double* __restrict__ G64t,
    unsigned short* __restrict__ Gth, unsigned short* __restrict__ Gtl)
{
    __shared__ float wt[64 * 65];            // [d-local][n], +1 pad
    const int tid = threadIdx.x;
    const int w = tid >> 6, n = tid & 63;
    const int k0 = blockIdx.x * 16;

    double acc[4] = {0.0, 0.0, 0.0, 0.0};
    const float* erow0 = E + (size_t)(k0 + w * 4 + 0) * DM;
    const float* erow1 = E + (size_t)(k0 + w * 4 + 1) * DM;
    const float* erow2 = E + (size_t)(k0 + w * 4 + 2) * DM;
    const float* erow3 = E + (size_t)(k0 + w * 4 + 3) * DM;

    for (int d0 = 0; d0 < DM; d0 += 64) {
        __syncthreads();
        // stage Wd[0:64][d0:d0+64] transposed -> wt[d][n]
        #pragma unroll
        for (int rep = 0; rep < 4; ++rep) {
            int f = rep * 256 + tid;
            int nn = f >> 4, dg = (f & 15) << 2;
            float4 v = *(const float4*)(Wd + (size_t)nn * DM + d0 + dg);
            wt[(dg + 0) * 65 + nn] = v.x;
            wt[(dg + 1) * 65 + nn] = v.y;
            wt[(dg + 2) * 65 + nn] = v.z;
            wt[(dg + 3) * 65 + nn] = v.w;
        }
        __syncthreads();
        #pragma unroll
        for (int dg = 0; dg < 16; ++dg) {
            float4 e0 = *(const float4*)(erow0 + d0 + dg * 4);
            float4 e1 = *(const float4*)(erow1 + d0 + dg * 4);
            float4 e2 = *(const float4*)(erow2 + d0 + dg * 4);
            float4 e3 = *(const float4*)(erow3 + d0 + dg * 4);
            #pragma unroll
            for (int j = 0; j < 4; ++j) {
                double wv = (double)wt[(dg * 4 + j) * 65 + n];
                float ej0 = (&e0.x)[j], ej1 = (&e1.x)[j];
                float ej2 = (&e2.x)[j], ej3 = (&e3.x)[j];
                acc[0] = fma((double)ej0, wv, acc[0]);
                acc[1] = fma((double)ej1, wv, acc[1]);
                acc[2] = fma((double)ej2, wv, acc[2]);
                acc[3] = fma((double)ej3, wv, acc[3]);
            }
        }
    }

    #pragma unroll
    for (int i = 0; i < 4; ++i) {
        int k = k0 + w * 4 + i;
        G64t[(size_t)n * KTOT + k] = acc[i];
        float gf = (float)acc[i];
        unsigned short h, lo;
        split2(gf, h, lo);
        const int e = k >> 8, r = k & 255;
        Gth[((size_t)(e * NREF + n)) * RNK + r] = h;
        Gtl[((size_t)(e * NREF + n)) * RNK + r] = lo;
    }
}

// ---------- S approx: S[t][n] = sum_e w[t,e]*(x'[t,:].G_e[:,n]) ----------
__global__ __launch_bounds__(256) void s_mfma(
    const unsigned short* __restrict__ Xh, const unsigned short* __restrict__ Xl,
    const unsigned short* __restrict__ Gth, const unsigned short* __restrict__ Gtl,
    const float* __restrict__ wts, float* __restrict__ S)
{
    __shared__ float red[4][16][64];
    const int tid = threadIdx.x, l = tid & 63, w = tid >> 6;
    const int t0 = blockIdx.x * 16;

    short8 ah[8], al[8];
    {
        const size_t abase = (size_t)(t0 + (l & 15)) * RNK + (l >> 4) * 8;
        #pragma unroll
        for (int ks = 0; ks < 8; ++ks) {
            ah[ks] = *(const short8*)&Xh[abase + ks * 32];
            al[ks] = *(const short8*)&Xl[abase + ks * 32];
        }
    }

    f32x4 Sacc[4] = {};
    #pragma unroll
    for (int ei = 0; ei < 4; ++ei) {
        const int e = w * 4 + ei;
        f32x4 acc[4] = {};
        #pragma unroll
        for (int ks = 0; ks < 8; ++ks) {
            #pragma unroll
            for (int nn = 0; nn < 4; ++nn) {
                size_t gbase = ((size_t)(e * NREF + nn * 16 + (l & 15))) * RNK
                             + ks * 32 + (l >> 4) * 8;
                short8 bh = *(const short8*)&Gth[gbase];
                short8 bl = *(const short8*)&Gtl[gbase];
                acc[nn] = __builtin_amdgcn_mfma_f32_16x16x32_bf16(al[ks], bh, acc[nn], 0, 0, 0);
                acc[nn] = __builtin_amdgcn_mfma_f32_16x16x32_bf16(ah[ks], bl, acc[nn], 0, 0, 0);
                acc[nn] = __builtin_amdgcn_mfma_f32_16x16x32_bf16(ah[ks], bh, acc[nn], 0, 0, 0);
            }
        }
        #pragma unroll
        for (int j = 0; j < 4; ++j) {
            float wv = wts[(size_t)(t0 + (l >> 4) * 4 + j) * NEXP + e];
            #pragma unroll
            for (int nn = 0; nn < 4; ++nn) Sacc[nn][j] += wv * acc[nn][j];
        }
    }
    #pragma unroll
    for (int nn = 0; nn < 4; ++nn)
        #pragma unroll
        for (int j = 0; j < 4; ++j)
            red[w][(l >> 4) * 4 + j][nn * 16 + (l & 15)] = Sacc[nn][j];
    __syncthreads();
    for (int i = tid; i < 16 * 64; i += 256) {
        int tt = i >> 6, nn = i & 63;
        float sv = red[0][tt][nn] + red[1][tt][nn] + red[2][tt][nn] + red[3][tt][nn];
        S[(size_t)(t0 + tt) * NREF + nn] = sv;
    }
}

// ---------- refine: approx top-4 -> exact fp64 scores -> top-2 ----------
__global__ __launch_bounds__(256) void refine_top2(
    const float* __restrict__ S, const double* __restrict__ G64t,
    const float* __restrict__ xf, const float* __restrict__ wts,
    float* __restrict__ out_id)
{
    __shared__ float xs[4][RNK];
    __shared__ float wsh[4][NEXP];
    const int tid = threadIdx.x, w = tid >> 6, lane = tid & 63;
    const int t = blockIdx.x * 4 + w;

    *(float4*)&xs[w][lane * 4] = *(const float4*)(xf + (size_t)t * RNK + lane * 4);
    if (lane < NEXP) wsh[w][lane] = wts[(size_t)t * NEXP + lane];
    __syncthreads();

    float cur = S[(size_t)t * NREF + lane];
    int cand[4];
    #pragma unroll
    for (int c = 0; c < 4; ++c) {
        float bv = cur; int bi = lane;
        #pragma unroll
        for (int m = 1; m < 64; m <<= 1) {
            float ov = __shfl_xor(bv, m, 64);
            int   oi = __shfl_xor(bi, m, 64);
            if (ov > bv || (ov == bv && oi < bi)) { bv = ov; bi = oi; }
        }
        cand[c] = bi;
        if (lane == bi) cur = -INFINITY;
    }

    double rs[4];
    #pragma unroll
    for (int c = 0; c < 4; ++c) {
        const double* grow = G64t + (size_t)cand[c] * KTOT;
        double acc = 0.0;
        #pragma unroll 4
        for (int i = 0; i < 64; ++i) {
            int k = i * 64 + lane;
            double a = (double)wsh[w][k >> 8] * (double)xs[w][k & 255];
            acc = fma(a, grow[k], acc);
        }
        #pragma unroll
        for (int m = 1; m < 64; m <<= 1) acc += __shfl_xor(acc, m, 64);
        rs[c] = acc;
    }

    int b0 = 0;
    #pragma unroll
    for (int c = 1; c < 4; ++c)
        if (rs[c] > rs[b0] || (rs[c] == rs[b0] && cand[c] < cand[b0])) b0 = c;
    int b1 = (b0 == 0) ? 1 : 0;
    #pragma unroll
    for (int c = 0; c < 4; ++c) {
        if (c == b0) continue;
        if (rs[c] > rs[b1] || (rs[c] == rs[b1] && cand[c] < cand[b1])) b1 = c;
    }
    if (lane == 0) {
        out_id[(size_t)t * 2 + 0] = (float)cand[b0];
        out_id[(size_t)t * 2 + 1] = (float)cand[b1];
    }
}

// ---------- K2 (MFMA): y = Ab @ Ebt^T.  M=8192 N=1024 K=4096 bf16 ----------
__global__ __launch_bounds__(256) void k2_mfma(
    const unsigned short* __restrict__ Ab,
    const unsigned short* __restrict__ Ebt,
    float* __restrict__ y)
{
    __shared__ unsigned short As[128 * 32];
    __shared__ unsigned short Bs[128 * 32];
    const int tid = threadIdx.x;
    const int l = tid & 63, w = tid >> 6;
    const int wr = w >> 1, wc = w & 1;
    const int tm0 = blockIdx.y * 128, n0 = blockIdx.x * 128;
    const int lrow = l >> 2, s = l & 3, g = l >> 4;

    f32x4 acc[4][4] = {};

    for (int kb = 0; kb < KTOT / 32; ++kb) {
        __syncthreads();
        #pragma unroll
        for (int i = 0; i < 2; ++i) {
            int row = w * 32 + i * 16 + lrow;
            int sw = ((s ^ (row & 3)) << 4);
            const char* ga = (const char*)Ab
                + ((size_t)(tm0 + row) * KTOT + kb * 32) * 2 + sw;
            __builtin_amdgcn_global_load_lds((gptr_t)ga,
                (lptr_t)&As[(w * 32 + i * 16) * 32], 16, 0, 0);
            const char* gb = (const char*)Ebt
                + ((size_t)(n0 + row) * KTOT + kb * 32) * 2 + sw;
            __builtin_amdgcn_global_load_lds((gptr_t)gb,
                (lptr_t)&Bs[(w * 32 + i * 16) * 32], 16, 0, 0);
        }
        __syncthreads();

        short8 af[4], bv[4];
        #pragma unroll
        for (int m = 0; m < 4; ++m) {
            int row = wr * 64 + m * 16 + (l & 15);
            af[m] = *(const short8*)&As[row * 32 + ((g ^ (row & 3)) << 3)];
        }
        #pragma unroll
        for (int nn = 0; nn < 4; ++nn) {
            int row = wc * 64 + nn * 16 + (l & 15);
            bv[nn] = *(const short8*)&Bs[row * 32 + ((g ^ (row & 3)) << 3)];
        }
        #pragma unroll
        for (int m = 0; m < 4; ++m)
            #pragma unroll
            for (int nn = 0; nn < 4; ++nn)
                acc[m][nn] = __builtin_amdgcn_mfma_f32_16x16x32_bf16(
                    af[m], bv[nn], acc[m][nn], 0, 0, 0);
    }

    #pragma unroll
    for (int m = 0; m < 4; ++m) {
        int rbase = tm0 + wr * 64 + m * 16 + (l >> 4) * 4;
        #pragma unroll
        for (int nn = 0; nn < 4; ++nn) {
            int c = n0 + wc * 64 + nn * 16 + (l & 15);
            #pragma unroll
            for (int j = 0; j < 4; ++j)
                y[(size_t)(rbase + j) * DM + c] = acc[m][nn][j];
        }
    }
}

// ---------- K2 fp32 fallback ----------
__global__ __launch_bounds__(256) void k2_gemm(
    const float* __restrict__ xp, const float* __restrict__ wts,
    const float* __restrict__ E, float* __restrict__ y)
{
    __shared__ float As[16][132];
    __shared__ float Bs[16][132];
    const int tid = threadIdx.x;
    const int bn = blockIdx.x, bm = blockIdx.y;
    const int tm0 = bm * 128, tn0 = bn * 128;
    const int ty = tid >> 4, tx = tid & 15;
    float acc[8][8] = {};
    for (int kb = 0; kb < KTOT / 16; ++kb) {
        const int e = kb >> 4;
        const int rbase = (kb & 15) << 4;
        const int kglob = kb << 4;
        __syncthreads();
        #pragma unroll
        for (int h = 0; h < 2; ++h) {
            int f = tid + h * 256;
            int m = f >> 2, k4 = (f & 3) << 2;
            int t = tm0 + m;
            float4 a = *(const float4*)(xp + (size_t)t * RNK + rbase + k4);
            float wv = wts[(size_t)t * NEXP + e];
            As[k4 + 0][m] = a.x * wv; As[k4 + 1][m] = a.y * wv;
            As[k4 + 2][m] = a.z * wv; As[k4 + 3][m] = a.w * wv;
        }
        #pragma unroll
        for (int h = 0; h < 2; ++h) {
            int f = tid + h * 256;
            int kk = f >> 5, d4 = (f & 31) << 2;
            float4 b = *(const float4*)(E + (size_t)(kglob + kk) * DM + tn0 + d4);
            *(float4*)(&Bs[kk][d4]) = b;
        }
        __syncthreads();
        #pragma unroll
        for (int kk = 0; kk < 16; ++kk) {
            float4 a0 = *(const float4*)(&As[kk][ty * 8]);
            float4 a1 = *(const float4*)(&As[kk][ty * 8 + 4]);
            float4 b0 = *(const float4*)(&Bs[kk][tx * 8]);
            float4 b1 = *(const float4*)(&Bs[kk][tx * 8 + 4]);
            float av[8] = {a0.x, a0.y, a0.z, a0.w, a1.x, a1.y, a1.z, a1.w};
            float bw[8] = {b0.x, b0.y, b0.z, b0.w, b1.x, b1.y, b1.z, b1.w};
            #pragma unroll
            for (int i = 0; i < 8; ++i)
                #pragma unroll
                for (int j = 0; j < 8; ++j)
                    acc[i][j] = fmaf(av[i], bw[j], acc[i][j]);
        }
    }
    #pragma unroll
    for (int i = 0; i < 8; ++i) {
        int t = tm0 + ty * 8 + i;
        float* yrow = y + (size_t)t * DM + tn0 + tx * 8;
        *(float4*)yrow       = make_float4(acc[i][0], acc[i][1], acc[i][2], acc[i][3]);
        *(float4*)(yrow + 4) = make_float4(acc[i][4], acc[i][5], acc[i][6], acc[i][7]);
    }
}

// ---------- K3: read refined indices -> 2 reflections on y (in place) -----
__global__ __launch_bounds__(256) void k3_post(
    const float* __restrict__ out_id, const float* __restrict__ reflect_d,
    float* __restrict__ y)
{
    const int tid = threadIdx.x;
    const int w = tid >> 6, lane = tid & 63;
    const int t = blockIdx.x * 4 + w;

    float4 yv[4];
    #pragma unroll
    for (int c = 0; c < 4; ++c)
        yv[c] = *(const float4*)(y + (size_t)t * DM + lane * 16 + c * 4);

    const int i0 = (int)out_id[(size_t)t * 2 + 0];
    const int i1 = (int)out_id[(size_t)t * 2 + 1];

    #pragma unroll
    for (int rr = 0; rr < 2; ++rr) {
        int idx = rr ? i1 : i0;
        const float* vrow = reflect_d + (size_t)idx * DM + lane * 16;
        float sv = 0.f, vn = 0.f;
        float4 vv[4];
        #pragma unroll
        for (int c = 0; c < 4; ++c) {
            vv[c] = *(const float4*)(vrow + c * 4);
            sv += vv[c].x * yv[c].x + vv[c].y * yv[c].y
                + vv[c].z * yv[c].z + vv[c].w * yv[c].w;
            vn += vv[c].x * vv[c].x + vv[c].y * vv[c].y
                + vv[c].z * vv[c].z + vv[c].w * vv[c].w;
        }
        #pragma unroll
        for (int m = 1; m < 64; m <<= 1) {
            sv += __shfl_xor(sv, m, 64);
            vn += __shfl_xor(vn, m, 64);
        }
        float coef = 2.0f * sv / (vn + 1e-8f);
        #pragma unroll
        for (int c = 0; c < 4; ++c) {
            yv[c].x -= coef * vv[c].x; yv[c].y -= coef * vv[c].y;
            yv[c].z -= coef * vv[c].z; yv[c].w -= coef * vv[c].w;
        }
    }
    #pragma unroll
    for (int c = 0; c < 4; ++c)
        *(float4*)(y + (size_t)t * DM + lane * 16 + c * 4) = yv[c];
}

// ---------- K3 fallback (scores_d from fp32 y, top2, reflect) ----------
__global__ __launch_bounds__(256) void k3_full(
    const float* __restrict__ Wd, const float* __restrict__ reflect_d,
    float* __restrict__ y, float* __restrict__ out_id)
{
    __shared__ float ys[4][DM];
    __shared__ float wds[64][17];
    const int tid = threadIdx.x;
    const int w = tid >> 6, lane = tid & 63;
    const int t = blockIdx.x * 4 + w;

    float4 yv[4];
    #pragma unroll
    for (int c = 0; c < 4; ++c) {
        yv[c] = *(const float4*)(y + (size_t)t * DM + lane * 16 + c * 4);
        *(float4*)(&ys[w][lane * 16 + c * 4]) = yv[c];
    }
    double s = 0.0;
    for (int kb = 0; kb < DM / 16; ++kb) {
        __syncthreads();
        {
            int row = tid >> 2, c4 = (tid & 3) << 2;
            float4 wv = *(const float4*)(Wd + (size_t)row * DM + kb * 16 + c4);
            wds[row][c4 + 0] = wv.x; wds[row][c4 + 1] = wv.y;
            wds[row][c4 + 2] = wv.z; wds[row][c4 + 3] = wv.w;
        }
        __syncthreads();
        #pragma unroll
        for (int i = 0; i < 16; ++i)
            s += (double)ys[w][kb * 16 + i] * (double)wds[lane][i];
    }
    int i0, i1;
    top2_64(s, lane, i0, i1);
    #pragma unroll
    for (int rr = 0; rr < 2; ++rr) {
        int idx = rr ? i1 : i0;
        const float* vrow = reflect_d + (size_t)idx * DM + lane * 16;
        float sv = 0.f, vn = 0.f;
        float4 vv[4];
        #pragma unroll
        for (int c = 0; c < 4; ++c) {
            vv[c] = *(const float4*)(vrow + c * 4);
            sv += vv[c].x * yv[c].x + vv[c].y * yv[c].y
                + vv[c].z * yv[c].z + vv[c].w * yv[c].w;
            vn += vv[c].x * vv[c].x + vv[c].y * vv[c].y
                + vv[c].z * vv[c].z + vv[c].w * vv[c].w;
        }
        #pragma unroll
        for (int m = 1; m < 64; m <<= 1) {
            sv += __shfl_xor(sv, m, 64);
            vn += __shfl_xor(vn, m, 64);
        }
        float coef = 2.0f * sv / (vn + 1e-8f);
        #pragma unroll
        for (int c = 0; c < 4; ++c) {
            yv[c].x -= coef * vv[c].x; yv[c].y -= coef * vv[c].y;
            yv[c].z -= coef * vv[c].z; yv[c].w -= coef * vv[c].w;
        }
    }
    #pragma unroll
    for (int c = 0; c < 4; ++c)
        *(float4*)(y + (size_t)t * DM + lane * 16 + c * 4) = yv[c];
    if (lane == 0) {
        out_id[(size_t)t * 2 + 0] = (float)i0;
        out_id[(size_t)t * 2 + 1] = (float)i1;
    }
}

extern "C" void kernel_launch(void* const* d_in, const int* in_sizes, int n_in,
                              void* d_out, int out_size, void* d_ws, size_t ws_size,
                              hipStream_t stream) {
    const float* x  = (const float*)d_in[0];
    const float* Wr = (const float*)d_in[1];
    const float* We = (const float*)d_in[2];
    const float* Wd = (const float*)d_in[3];
    const float* E  = (const float*)d_in[4];
    const float* rr = (const float*)d_in[5];
    const float* rd = (const float*)d_in[6];

    float* out    = (float*)d_out;
    float* y      = out + Y_OFF;
    float* out_ir = out + IR_OFF;
    float* out_w  = out + W_OFF;
    float* out_id = out + ID_OFF;

    if (ws_size >= WS_FULL) {
        char* p = (char*)d_ws;
        unsigned short* Ab  = (unsigned short*)p;  p += AB_BYTES;
        unsigned short* Ebt = (unsigned short*)p;  p += EBT_BYTES;
        float*          Xf  = (float*)p;           p += XF_BYTES;
        unsigned short* Xh  = (unsigned short*)p;  p += XH_BYTES;
        unsigned short* Xl  = (unsigned short*)p;  p += XH_BYTES;
        unsigned short* Gth = (unsigned short*)p;  p += GT_BYTES;
        unsigned short* Gtl = (unsigned short*)p;  p += GT_BYTES;
        float*          Sb  = (float*)p;           p += S_BYTES;
        double*         G64 = (double*)p;

        e_transpose<<<dim3(KTOT / 64, DM / 64), 256, 0, stream>>>(E, Ebt);
        g_fp64<<<KTOT / 16, 256, 0, stream>>>(E, Wd, G64, Gth, Gtl);
        k1_tokens<<<TOK / 4, 256, 0, stream>>>(x, Wr, We, rr, Xf, Ab,
                                               Xh, Xl, out_ir, out_w, 1);
        k2_mfma<<<dim3(DM / 128, TOK / 128), 256, 0, stream>>>(Ab, Ebt, y);
        s_mfma<<<TOK / 16, 256, 0, stream>>>(Xh, Xl, Gth, Gtl, out_w, Sb);
        refine_top2<<<TOK / 4, 256, 0, stream>>>(Sb, G64, Xf, out_w, out_id);
        k3_post<<<TOK / 4, 256, 0, stream>>>(out_id, rd, y);
    } else {
        float* xprime = (float*)d_ws;
        k1_tokens<<<TOK / 4, 256, 0, stream>>>(x, Wr, We, rr, xprime, nullptr,
                                               nullptr, nullptr, out_ir, out_w, 0);
        k2_gemm<<<dim3(DM / 128, TOK / 128), 256, 0, stream>>>(xprime, out_w, E, y);
        k3_full<<<TOK / 4, 256, 0, stream>>>(Wd, rd, y, out_id);
    }
}

// Round 6
// 424.347 us; speedup vs baseline: 2.5456x; 1.1841x over previous
//
#include <hip/hip_runtime.h>
#include <cmath>

#define TOK   8192
#define RNK   256
#define NEXP  16
#define NREF  64
#define DM    1024
#define KTOT  4096

#define Y_OFF  0
#define IR_OFF (TOK*DM)
#define W_OFF  (IR_OFF + TOK*2)
#define ID_OFF (W_OFF + TOK*NEXP)

#define AB_BYTES  ((size_t)TOK * KTOT * 2)        // 64 MB
#define EBT_BYTES ((size_t)DM * KTOT * 2)         // 8 MB
#define XF_BYTES  ((size_t)TOK * RNK * 4)         // 8 MB
#define XH_BYTES  ((size_t)TOK * RNK * 2)         // 4 MB
#define GT_BYTES  ((size_t)NEXP * NREF * RNK * 2) // 512 KB
#define S_BYTES   ((size_t)TOK * NREF * 4)        // 2 MB
#define G64_BYTES ((size_t)NREF * KTOT * 8)       // 2 MB
#define SR_BYTES  ((size_t)TOK * NREF * 8)        // 4 MB
#define WS_FULL   (AB_BYTES + EBT_BYTES + XF_BYTES + 2*XH_BYTES + 2*GT_BYTES + S_BYTES + G64_BYTES + SR_BYTES)

typedef __attribute__((ext_vector_type(8))) short short8;
typedef __attribute__((ext_vector_type(4))) float f32x4;
typedef const __attribute__((address_space(1))) void* gptr_t;
typedef __attribute__((address_space(3))) void* lptr_t;

__device__ inline unsigned short f2bf(float f) {    // RNE float->bf16
    unsigned int u = __float_as_uint(f);
    return (unsigned short)((u + 0x7fffu + ((u >> 16) & 1u)) >> 16);
}
__device__ inline float bf2f(unsigned short h) {
    return __uint_as_float(((unsigned int)h) << 16);
}
__device__ inline void split2(float v, unsigned short& h, unsigned short& l) {
    h = f2bf(v);
    l = f2bf(v - bf2f(h));
}
__device__ inline unsigned long long pack4(unsigned short a, unsigned short b,
                                           unsigned short c, unsigned short d) {
    return (unsigned long long)a | ((unsigned long long)b << 16)
         | ((unsigned long long)c << 32) | ((unsigned long long)d << 48);
}

// ---------- top-2 across a 64-lane wave, lax.top_k tie semantics ----------
__device__ inline void top2_64(double v, int idx, int& i0, int& i1) {
    double bv = v; int bi = idx;
    #pragma unroll
    for (int m = 1; m < 64; m <<= 1) {
        double ov = __shfl_xor(bv, m, 64);
        int    oi = __shfl_xor(bi, m, 64);
        if (ov > bv || (ov == bv && oi < bi)) { bv = ov; bi = oi; }
    }
    i0 = bi;
    double v2 = (idx == i0) ? -INFINITY : v;
    double bv2 = v2; int bi2 = idx;
    #pragma unroll
    for (int m = 1; m < 64; m <<= 1) {
        double ov = __shfl_xor(bv2, m, 64);
        int    oi = __shfl_xor(bi2, m, 64);
        if (ov > bv2 || (ov == bv2 && oi < bi2)) { bv2 = ov; bi2 = oi; }
    }
    i1 = bi2;
}

// ---------- Sr (fp64, LDS-tiled): Sr[t][n] = sum_r x[t,r]*Wr[n,r] ----------
// Block = 16 tokens x 64 n. Wr chunk staged transposed in LDS (+1 pad);
// x rows are wave-uniform -> scalar loads. Coalesced Sr writes.
__global__ __launch_bounds__(256) void sr_fp64(
    const float* __restrict__ x, const float* __restrict__ Wr,
    double* __restrict__ Sr)
{
    __shared__ float wt[64 * 65];
    const int tid = threadIdx.x;
    const int w = tid >> 6, n = tid & 63;
    const int t0 = blockIdx.x * 16;

    double acc[4] = {0.0, 0.0, 0.0, 0.0};
    const float* xr0 = x + (size_t)(t0 + w * 4 + 0) * RNK;
    const float* xr1 = x + (size_t)(t0 + w * 4 + 1) * RNK;
    const float* xr2 = x + (size_t)(t0 + w * 4 + 2) * RNK;
    const float* xr3 = x + (size_t)(t0 + w * 4 + 3) * RNK;

    for (int d0 = 0; d0 < RNK; d0 += 64) {
        __syncthreads();
        #pragma unroll
        for (int rep = 0; rep < 4; ++rep) {
            int f = rep * 256 + tid;
            int nn = f >> 4, dg = (f & 15) << 2;
            float4 v = *(const float4*)(Wr + (size_t)nn * RNK + d0 + dg);
            wt[(dg + 0) * 65 + nn] = v.x;
            wt[(dg + 1) * 65 + nn] = v.y;
            wt[(dg + 2) * 65 + nn] = v.z;
            wt[(dg + 3) * 65 + nn] = v.w;
        }
        __syncthreads();
        #pragma unroll
        for (int dg = 0; dg < 16; ++dg) {
            float4 e0 = *(const float4*)(xr0 + d0 + dg * 4);
            float4 e1 = *(const float4*)(xr1 + d0 + dg * 4);
            float4 e2 = *(const float4*)(xr2 + d0 + dg * 4);
            float4 e3 = *(const float4*)(xr3 + d0 + dg * 4);
            #pragma unroll
            for (int j = 0; j < 4; ++j) {
                double wv = (double)wt[(dg * 4 + j) * 65 + n];
                acc[0] = fma((double)(&e0.x)[j], wv, acc[0]);
                acc[1] = fma((double)(&e1.x)[j], wv, acc[1]);
                acc[2] = fma((double)(&e2.x)[j], wv, acc[2]);
                acc[3] = fma((double)(&e3.x)[j], wv, acc[3]);
            }
        }
    }
    #pragma unroll
    for (int i = 0; i < 4; ++i)
        Sr[(size_t)(t0 + w * 4 + i) * NREF + n] = acc[i];
}

// ---------- K1 fast: top2(Sr) -> reflections -> scores_e(LDS We) ----------
// Block = 16 tokens (4 waves x 4 sequential). We staged once per block.
__global__ __launch_bounds__(256) void k1_fast(
    const double* __restrict__ Sr, const float* __restrict__ x,
    const float* __restrict__ We, const float* __restrict__ reflect_r,
    float* __restrict__ xprime, unsigned short* __restrict__ Ab,
    unsigned short* __restrict__ Xh, unsigned short* __restrict__ Xl,
    float* __restrict__ out_ir, float* __restrict__ out_w)
{
    __shared__ float we_lds[16 * 260];
    __shared__ float xs[4][260];
    const int tid = threadIdx.x;
    const int w = tid >> 6, lane = tid & 63;

    // stage We[16][256] -> we_lds (stride 260; conflict-free reads later)
    #pragma unroll
    for (int rep = 0; rep < 4; ++rep) {
        int f = rep * 256 + tid;
        int row = f >> 6, c4 = (f & 63) << 2;
        float4 v = *(const float4*)(We + (size_t)row * RNK + c4);
        *(float4*)&we_lds[row * 260 + c4] = v;
    }
    __syncthreads();

    for (int it = 0; it < 4; ++it) {
        const int t = blockIdx.x * 16 + it * 4 + w;

        float4 xv = *(const float4*)(x + (size_t)t * RNK + lane * 4);
        double s = Sr[(size_t)t * NREF + lane];
        int i0, i1;
        top2_64(s, lane, i0, i1);

        #pragma unroll
        for (int rr = 0; rr < 2; ++rr) {
            int idx = rr ? i1 : i0;
            float4 vv = *(const float4*)(reflect_r + (size_t)idx * RNK + lane * 4);
            float sv = vv.x * xv.x + vv.y * xv.y + vv.z * xv.z + vv.w * xv.w;
            float vn = vv.x * vv.x + vv.y * vv.y + vv.z * vv.z + vv.w * vv.w;
            #pragma unroll
            for (int m = 1; m < 64; m <<= 1) {
                sv += __shfl_xor(sv, m, 64);
                vn += __shfl_xor(vn, m, 64);
            }
            float coef = 2.0f * sv / (vn + 1e-8f);
            xv.x -= coef * vv.x; xv.y -= coef * vv.y;
            xv.z -= coef * vv.z; xv.w -= coef * vv.w;
        }

        // per-wave x' broadcast buffer (no cross-wave sharing -> no barrier)
        *(float4*)&xs[w][lane * 4] = xv;
        *(float4*)(xprime + (size_t)t * RNK + lane * 4) = xv;

        const int n16 = lane & 15;
        double se = 0.0;
        {
            const float* werow = &we_lds[n16 * 260];
            #pragma unroll 8
            for (int r4 = 0; r4 < RNK / 4; ++r4) {
                float4 xr = *(const float4*)(&xs[w][r4 * 4]);
                float4 wf = *(const float4*)(werow + r4 * 4);
                se += (double)xr.x * wf.x + (double)xr.y * wf.y
                    + (double)xr.z * wf.z + (double)xr.w * wf.w;
            }
        }
        float sef = (float)se;
        float mx = sef;
        #pragma unroll
        for (int m = 1; m < 16; m <<= 1) mx = fmaxf(mx, __shfl_xor(mx, m, 64));
        float ex = expf(sef - mx);
        float sm = ex;
        #pragma unroll
        for (int m = 1; m < 16; m <<= 1) sm += __shfl_xor(sm, m, 64);
        float wgt = ex / sm;

        if (lane < NEXP) out_w[(size_t)t * NEXP + lane] = wgt;
        if (lane == 0) {
            out_ir[(size_t)t * 2 + 0] = (float)i0;
            out_ir[(size_t)t * 2 + 1] = (float)i1;
        }

        unsigned short hx, lx, hy, ly, hz, lz, hw, lw;
        split2(xv.x, hx, lx); split2(xv.y, hy, ly);
        split2(xv.z, hz, lz); split2(xv.w, hw, lw);
        *(unsigned long long*)&Xh[(size_t)t * RNK + lane * 4] = pack4(hx, hy, hz, hw);
        *(unsigned long long*)&Xl[(size_t)t * RNK + lane * 4] = pack4(lx, ly, lz, lw);
        #pragma unroll
        for (int e = 0; e < NEXP; ++e) {
            float we = __shfl(wgt, e, 64);
            *(unsigned long long*)&Ab[(size_t)t * KTOT + e * RNK + lane * 4] =
                pack4(f2bf(we * xv.x), f2bf(we * xv.y),
                      f2bf(we * xv.z), f2bf(we * xv.w));
        }
    }
}

// ---------- K1 fallback (fp32 path, ws too small) ----------
__global__ __launch_bounds__(256) void k1_tokens(
    const float* __restrict__ x, const float* __restrict__ Wr,
    const float* __restrict__ We, const float* __restrict__ reflect_r,
    float* __restrict__ xprime, float* __restrict__ out_ir,
    float* __restrict__ out_w)
{
    __shared__ float xs[4][RNK];
    const int tid = threadIdx.x;
    const int w = tid >> 6, lane = tid & 63;
    const int t = blockIdx.x * 4 + w;

    float4 xv = *(const float4*)(x + (size_t)t * RNK + lane * 4);
    *(float4*)(&xs[w][lane * 4]) = xv;
    __syncthreads();

    double s = 0.0;
    {
        const float* wrow = Wr + (size_t)lane * RNK;
        for (int r4 = 0; r4 < RNK / 4; ++r4) {
            float4 xr = *(const float4*)(&xs[w][r4 * 4]);
            float4 wr = *(const float4*)(wrow + r4 * 4);
            s += (double)xr.x * wr.x + (double)xr.y * wr.y
               + (double)xr.z * wr.z + (double)xr.w * wr.w;
        }
    }
    int i0, i1;
    top2_64(s, lane, i0, i1);

    #pragma unroll
    for (int rr = 0; rr < 2; ++rr) {
        int idx = rr ? i1 : i0;
        float4 vv = *(const float4*)(reflect_r + (size_t)idx * RNK + lane * 4);
        float sv = vv.x * xv.x + vv.y * xv.y + vv.z * xv.z + vv.w * xv.w;
        float vn = vv.x * vv.x + vv.y * vv.y + vv.z * vv.z + vv.w * vv.w;
        #pragma unroll
        for (int m = 1; m < 64; m <<= 1) {
            sv += __shfl_xor(sv, m, 64);
            vn += __shfl_xor(vn, m, 64);
        }
        float coef = 2.0f * sv / (vn + 1e-8f);
        xv.x -= coef * vv.x; xv.y -= coef * vv.y;
        xv.z -= coef * vv.z; xv.w -= coef * vv.w;
    }
    __syncthreads();
    *(float4*)(&xs[w][lane * 4]) = xv;
    __syncthreads();

    *(float4*)(xprime + (size_t)t * RNK + lane * 4) = xv;

    const int n = lane & 15;
    double se = 0.0;
    {
        const float* werow = We + (size_t)n * RNK;
        for (int r4 = 0; r4 < RNK / 4; ++r4) {
            float4 xr = *(const float4*)(&xs[w][r4 * 4]);
            float4 wf = *(const float4*)(werow + r4 * 4);
            se += (double)xr.x * wf.x + (double)xr.y * wf.y
                + (double)xr.z * wf.z + (double)xr.w * wf.w;
        }
    }
    float sef = (float)se;
    float mx = sef;
    #pragma unroll
    for (int m = 1; m < 16; m <<= 1) mx = fmaxf(mx, __shfl_xor(mx, m, 64));
    float ex = expf(sef - mx);
    float sm = ex;
    #pragma unroll
    for (int m = 1; m < 16; m <<= 1) sm += __shfl_xor(sm, m, 64);
    float wgt = ex / sm;

    if (lane < NEXP) out_w[(size_t)t * NEXP + lane] = wgt;
    if (lane == 0) {
        out_ir[(size_t)t * 2 + 0] = (float)i0;
        out_ir[(size_t)t * 2 + 1] = (float)i1;
    }
}

// ---------- E transpose+convert: Ebt[d][k] = bf16(E[k][d]) ----------
__global__ __launch_bounds__(256) void e_transpose(
    const float* __restrict__ E, unsigned short* __restrict__ Ebt)
{
    __shared__ float lds[64][68];
    const int tid = threadIdx.x;
    const int k0 = blockIdx.x * 64, d0 = blockIdx.y * 64;
    #pragma unroll
    for (int rep = 0; rep < 4; ++rep) {
        int idx = rep * 256 + tid;
        int r = idx >> 4, c4 = (idx & 15) << 2;
        float4 v = *(const float4*)(E + (size_t)(k0 + r) * DM + d0 + c4);
        lds[r][c4 + 0] = v.x; lds[r][c4 + 1] = v.y;
        lds[r][c4 + 2] = v.z; lds[r][c4 + 3] = v.w;
    }
    __syncthreads();
    #pragma unroll
    for (int rep = 0; rep < 4; ++rep) {
        int idx = rep * 256 + tid;
        int dr = idx >> 4, kc4 = (idx & 15) << 2;
        *(unsigned long long*)&Ebt[(size_t)(d0 + dr) * KTOT + k0 + kc4] =
            pack4(f2bf(lds[kc4 + 0][dr]), f2bf(lds[kc4 + 1][dr]),
                  f2bf(lds[kc4 + 2][dr]), f2bf(lds[kc4 + 3][dr]));
    }
}

// ---------- G (fp64, LDS-tiled): G64t[n][k] = sum_d E[k,d]*Wd[n,d] ---------
__global__ __launch_bounds__(256) void g_fp64(
    const float* __restrict__ E, const float* __restrict__ Wd,
    double* __restrict__ G64t,
    unsigned short* __restrict__ Gth, unsigned short* __restrict__ Gtl)
{
    __shared__ float wt[64 * 65];
    const int tid = threadIdx.x;
    const int w = tid >> 6, n = tid & 63;
    const int k0 = blockIdx.x * 16;

    double acc[4] = {0.0, 0.0, 0.0, 0.0};
    const float* erow0 = E + (size_t)(k0 + w * 4 + 0) * DM;
    const float* erow1 = E + (size_t)(k0 + w * 4 + 1) * DM;
    const float* erow2 = E + (size_t)(k0 + w * 4 + 2) * DM;
    const float* erow3 = E + (size_t)(k0 + w * 4 + 3) * DM;

    for (int d0 = 0; d0 < DM; d0 += 64) {
        __syncthreads();
        #pragma unroll
        for (int rep = 0; rep < 4; ++rep) {
            int f = rep * 256 + tid;
            int nn = f >> 4, dg = (f & 15) << 2;
            float4 v = *(const float4*)(Wd + (size_t)nn * DM + d0 + dg);
            wt[(dg + 0) * 65 + nn] = v.x;
            wt[(dg + 1) * 65 + nn] = v.y;
            wt[(dg + 2) * 65 + nn] = v.z;
            wt[(dg + 3) * 65 + nn] = v.w;
        }
        __syncthreads();
        #pragma unroll
        for (int dg = 0; dg < 16; ++dg) {
            float4 e0 = *(const float4*)(erow0 + d0 + dg * 4);
            float4 e1 = *(const float4*)(erow1 + d0 + dg * 4);
            float4 e2 = *(const float4*)(erow2 + d0 + dg * 4);
            float4 e3 = *(const float4*)(erow3 + d0 + dg * 4);
            #pragma unroll
            for (int j = 0; j < 4; ++j) {
                double wv = (double)wt[(dg * 4 + j) * 65 + n];
                acc[0] = fma((double)(&e0.x)[j], wv, acc[0]);
                acc[1] = fma((double)(&e1.x)[j], wv, acc[1]);
                acc[2] = fma((double)(&e2.x)[j], wv, acc[2]);
                acc[3] = fma((double)(&e3.x)[j], wv, acc[3]);
            }
        }
    }

    #pragma unroll
    for (int i = 0; i < 4; ++i) {
        int k = k0 + w * 4 + i;
        G64t[(size_t)n * KTOT + k] = acc[i];
        float gf = (float)acc[i];
        unsigned short h, lo;
        split2(gf, h, lo);
        const int e = k >> 8, r = k & 255;
        Gth[((size_t)(e * NREF + n)) * RNK + r] = h;
        Gtl[((size_t)(e * NREF + n)) * RNK + r] = lo;
    }
}

// ---------- S approx: S[t][n] = sum_e w[t,e]*(x'[t,:].G_e[:,n]) ----------
__global__ __launch_bounds__(256) void s_mfma(
    const unsigned short* __restrict__ Xh, const unsigned short* __restrict__ Xl,
    const unsigned short* __restrict__ Gth, const unsigned short* __restrict__ Gtl,
    const float* __restrict__ wts, float* __restrict__ S)
{
    __shared__ float red[4][16][64];
    const int tid = threadIdx.x, l = tid & 63, w = tid >> 6;
    const int t0 = blockIdx.x * 16;

    short8 ah[8], al[8];
    {
        const size_t abase = (size_t)(t0 + (l & 15)) * RNK + (l >> 4) * 8;
        #pragma unroll
        for (int ks = 0; ks < 8; ++ks) {
            ah[ks] = *(const short8*)&Xh[abase + ks * 32];
            al[ks] = *(const short8*)&Xl[abase + ks * 32];
        }
    }

    f32x4 Sacc[4] = {};
    #pragma unroll
    for (int ei = 0; ei < 4; ++ei) {
        const int e = w * 4 + ei;
        f32x4 acc[4] = {};
        #pragma unroll
        for (int ks = 0; ks < 8; ++ks) {
            #pragma unroll
            for (int nn = 0; nn < 4; ++nn) {
                size_t gbase = ((size_t)(e * NREF + nn * 16 + (l & 15))) * RNK
                             + ks * 32 + (l >> 4) * 8;
                short8 bh = *(const short8*)&Gth[gbase];
                short8 bl = *(const short8*)&Gtl[gbase];
                acc[nn] = __builtin_amdgcn_mfma_f32_16x16x32_bf16(al[ks], bh, acc[nn], 0, 0, 0);
                acc[nn] = __builtin_amdgcn_mfma_f32_16x16x32_bf16(ah[ks], bl, acc[nn], 0, 0, 0);
                acc[nn] = __builtin_amdgcn_mfma_f32_16x16x32_bf16(ah[ks], bh, acc[nn], 0, 0, 0);
            }
        }
        #pragma unroll
        for (int j = 0; j < 4; ++j) {
            float wv = wts[(size_t)(t0 + (l >> 4) * 4 + j) * NEXP + e];
            #pragma unroll
            for (int nn = 0; nn < 4; ++nn) Sacc[nn][j] += wv * acc[nn][j];
        }
    }
    #pragma unroll
    for (int nn = 0; nn < 4; ++nn)
        #pragma unroll
        for (int j = 0; j < 4; ++j)
            red[w][(l >> 4) * 4 + j][nn * 16 + (l & 15)] = Sacc[nn][j];
    __syncthreads();
    for (int i = tid; i < 16 * 64; i += 256) {
        int tt = i >> 6, nn = i & 63;
        float sv = red[0][tt][nn] + red[1][tt][nn] + red[2][tt][nn] + red[3][tt][nn];
        S[(size_t)(t0 + tt) * NREF + nn] = sv;
    }
}

// ---------- refine: approx top-4 -> exact fp64 scores -> top-2 ----------
__global__ __launch_bounds__(256) void refine_top2(
    const float* __restrict__ S, const double* __restrict__ G64t,
    const float* __restrict__ xf, const float* __restrict__ wts,
    float* __restrict__ out_id)
{
    __shared__ float xs[4][RNK];
    __shared__ float wsh[4][NEXP];
    const int tid = threadIdx.x, w = tid >> 6, lane = tid & 63;
    const int t = blockIdx.x * 4 + w;

    *(float4*)&xs[w][lane * 4] = *(const float4*)(xf + (size_t)t * RNK + lane * 4);
    if (lane < NEXP) wsh[w][lane] = wts[(size_t)t * NEXP + lane];
    __syncthreads();

    float cur = S[(size_t)t * NREF + lane];
    int cand[4];
    #pragma unroll
    for (int c = 0; c < 4; ++c) {
        float bv = cur; int bi = lane;
        #pragma unroll
        for (int m = 1; m < 64; m <<= 1) {
            float ov = __shfl_xor(bv, m, 64);
            int   oi = __shfl_xor(bi, m, 64);
            if (ov > bv || (ov == bv && oi < bi)) { bv = ov; bi = oi; }
        }
        cand[c] = bi;
        if (lane == bi) cur = -INFINITY;
    }

    double rs[4];
    #pragma unroll
    for (int c = 0; c < 4; ++c) {
        const double* grow = G64t + (size_t)cand[c] * KTOT;
        double acc = 0.0;
        #pragma unroll 4
        for (int i = 0; i < 64; ++i) {
            int k = i * 64 + lane;
            double a = (double)wsh[w][k >> 8] * (double)xs[w][k & 255];
            acc = fma(a, grow[k], acc);
        }
        #pragma unroll
        for (int m = 1; m < 64; m <<= 1) acc += __shfl_xor(acc, m, 64);
        rs[c] = acc;
    }

    int b0 = 0;
    #pragma unroll
    for (int c = 1; c < 4; ++c)
        if (rs[c] > rs[b0] || (rs[c] == rs[b0] && cand[c] < cand[b0])) b0 = c;
    int b1 = (b0 == 0) ? 1 : 0;
    #pragma unroll
    for (int c = 0; c < 4; ++c) {
        if (c == b0) continue;
        if (rs[c] > rs[b1] || (rs[c] == rs[b1] && cand[c] < cand[b1])) b1 = c;
    }
    if (lane == 0) {
        out_id[(size_t)t * 2 + 0] = (float)cand[b0];
        out_id[(size_t)t * 2 + 1] = (float)cand[b1];
    }
}

// ---------- K2 (MFMA): y = Ab @ Ebt^T.  M=8192 N=1024 K=4096 bf16 ----------
__global__ __launch_bounds__(256) void k2_mfma(
    const unsigned short* __restrict__ Ab,
    const unsigned short* __restrict__ Ebt,
    float* __restrict__ y)
{
    __shared__ unsigned short As[128 * 32];
    __shared__ unsigned short Bs[128 * 32];
    const int tid = threadIdx.x;
    const int l = tid & 63, w = tid >> 6;
    const int wr = w >> 1, wc = w & 1;
    const int tm0 = blockIdx.y * 128, n0 = blockIdx.x * 128;
    const int lrow = l >> 2, s = l & 3, g = l >> 4;

    f32x4 acc[4][4] = {};

    for (int kb = 0; kb < KTOT / 32; ++kb) {
        __syncthreads();
        #pragma unroll
        for (int i = 0; i < 2; ++i) {
            int row = w * 32 + i * 16 + lrow;
            int sw = ((s ^ (row & 3)) << 4);
            const char* ga = (const char*)Ab
                + ((size_t)(tm0 + row) * KTOT + kb * 32) * 2 + sw;
            __builtin_amdgcn_global_load_lds((gptr_t)ga,
                (lptr_t)&As[(w * 32 + i * 16) * 32], 16, 0, 0);
            const char* gb = (const char*)Ebt
                + ((size_t)(n0 + row) * KTOT + kb * 32) * 2 + sw;
            __builtin_amdgcn_global_load_lds((gptr_t)gb,
                (lptr_t)&Bs[(w * 32 + i * 16) * 32], 16, 0, 0);
        }
        __syncthreads();

        short8 af[4], bv[4];
        #pragma unroll
        for (int m = 0; m < 4; ++m) {
            int row = wr * 64 + m * 16 + (l & 15);
            af[m] = *(const short8*)&As[row * 32 + ((g ^ (row & 3)) << 3)];
        }
        #pragma unroll
        for (int nn = 0; nn < 4; ++nn) {
            int row = wc * 64 + nn * 16 + (l & 15);
            bv[nn] = *(const short8*)&Bs[row * 32 + ((g ^ (row & 3)) << 3)];
        }
        #pragma unroll
        for (int m = 0; m < 4; ++m)
            #pragma unroll
            for (int nn = 0; nn < 4; ++nn)
                acc[m][nn] = __builtin_amdgcn_mfma_f32_16x16x32_bf16(
                    af[m], bv[nn], acc[m][nn], 0, 0, 0);
    }

    #pragma unroll
    for (int m = 0; m < 4; ++m) {
        int rbase = tm0 + wr * 64 + m * 16 + (l >> 4) * 4;
        #pragma unroll
        for (int nn = 0; nn < 4; ++nn) {
            int c = n0 + wc * 64 + nn * 16 + (l & 15);
            #pragma unroll
            for (int j = 0; j < 4; ++j)
                y[(size_t)(rbase + j) * DM + c] = acc[m][nn][j];
        }
    }
}

// ---------- K2 fp32 fallback ----------
__global__ __launch_bounds__(256) void k2_gemm(
    const float* __restrict__ xp, const float* __restrict__ wts,
    const float* __restrict__ E, float* __restrict__ y)
{
    __shared__ float As[16][132];
    __shared__ float Bs[16][132];
    const int tid = threadIdx.x;
    const int bn = blockIdx.x, bm = blockIdx.y;
    const int tm0 = bm * 128, tn0 = bn * 128;
    const int ty = tid >> 4, tx = tid & 15;
    float acc[8][8] = {};
    for (int kb = 0; kb < KTOT / 16; ++kb) {
        const int e = kb >> 4;
        const int rbase = (kb & 15) << 4;
        const int kglob = kb << 4;
        __syncthreads();
        #pragma unroll
        for (int h = 0; h < 2; ++h) {
            int f = tid + h * 256;
            int m = f >> 2, k4 = (f & 3) << 2;
            int t = tm0 + m;
            float4 a = *(const float4*)(xp + (size_t)t * RNK + rbase + k4);
            float wv = wts[(size_t)t * NEXP + e];
            As[k4 + 0][m] = a.x * wv; As[k4 + 1][m] = a.y * wv;
            As[k4 + 2][m] = a.z * wv; As[k4 + 3][m] = a.w * wv;
        }
        #pragma unroll
        for (int h = 0; h < 2; ++h) {
            int f = tid + h * 256;
            int kk = f >> 5, d4 = (f & 31) << 2;
            float4 b = *(const float4*)(E + (size_t)(kglob + kk) * DM + tn0 + d4);
            *(float4*)(&Bs[kk][d4]) = b;
        }
        __syncthreads();
        #pragma unroll
        for (int kk = 0; kk < 16; ++kk) {
            float4 a0 = *(const float4*)(&As[kk][ty * 8]);
            float4 a1 = *(const float4*)(&As[kk][ty * 8 + 4]);
            float4 b0 = *(const float4*)(&Bs[kk][tx * 8]);
            float4 b1 = *(const float4*)(&Bs[kk][tx * 8 + 4]);
            float av[8] = {a0.x, a0.y, a0.z, a0.w, a1.x, a1.y, a1.z, a1.w};
            float bw[8] = {b0.x, b0.y, b0.z, b0.w, b1.x, b1.y, b1.z, b1.w};
            #pragma unroll
            for (int i = 0; i < 8; ++i)
                #pragma unroll
                for (int j = 0; j < 8; ++j)
                    acc[i][j] = fmaf(av[i], bw[j], acc[i][j]);
        }
    }
    #pragma unroll
    for (int i = 0; i < 8; ++i) {
        int t = tm0 + ty * 8 + i;
        float* yrow = y + (size_t)t * DM + tn0 + tx * 8;
        *(float4*)yrow       = make_float4(acc[i][0], acc[i][1], acc[i][2], acc[i][3]);
        *(float4*)(yrow + 4) = make_float4(acc[i][4], acc[i][5], acc[i][6], acc[i][7]);
    }
}

// ---------- K3: read refined indices -> 2 reflections on y (in place) -----
__global__ __launch_bounds__(256) void k3_post(
    const float* __restrict__ out_id, const float* __restrict__ reflect_d,
    float* __restrict__ y)
{
    const int tid = threadIdx.x;
    const int w = tid >> 6, lane = tid & 63;
    const int t = blockIdx.x * 4 + w;

    float4 yv[4];
    #pragma unroll
    for (int c = 0; c < 4; ++c)
        yv[c] = *(const float4*)(y + (size_t)t * DM + lane * 16 + c * 4);

    const int i0 = (int)out_id[(size_t)t * 2 + 0];
    const int i1 = (int)out_id[(size_t)t * 2 + 1];

    #pragma unroll
    for (int rr = 0; rr < 2; ++rr) {
        int idx = rr ? i1 : i0;
        const float* vrow = reflect_d + (size_t)idx * DM + lane * 16;
        float sv = 0.f, vn = 0.f;
        float4 vv[4];
        #pragma unroll
        for (int c = 0; c < 4; ++c) {
            vv[c] = *(const float4*)(vrow + c * 4);
            sv += vv[c].x * yv[c].x + vv[c].y * yv[c].y
                + vv[c].z * yv[c].z + vv[c].w * yv[c].w;
            vn += vv[c].x * vv[c].x + vv[c].y * vv[c].y
                + vv[c].z * vv[c].z + vv[c].w * vv[c].w;
        }
        #pragma unroll
        for (int m = 1; m < 64; m <<= 1) {
            sv += __shfl_xor(sv, m, 64);
            vn += __shfl_xor(vn, m, 64);
        }
        float coef = 2.0f * sv / (vn + 1e-8f);
        #pragma unroll
        for (int c = 0; c < 4; ++c) {
            yv[c].x -= coef * vv[c].x; yv[c].y -= coef * vv[c].y;
            yv[c].z -= coef * vv[c].z; yv[c].w -= coef * vv[c].w;
        }
    }
    #pragma unroll
    for (int c = 0; c < 4; ++c)
        *(float4*)(y + (size_t)t * DM + lane * 16 + c * 4) = yv[c];
}

// ---------- K3 fallback (scores_d from fp32 y, top2, reflect) ----------
__global__ __launch_bounds__(256) void k3_full(
    const float* __restrict__ Wd, const float* __restrict__ reflect_d,
    float* __restrict__ y, float* __restrict__ out_id)
{
    __shared__ float ys[4][DM];
    __shared__ float wds[64][17];
    const int tid = threadIdx.x;
    const int w = tid >> 6, lane = tid & 63;
    const int t = blockIdx.x * 4 + w;

    float4 yv[4];
    #pragma unroll
    for (int c = 0; c < 4; ++c) {
        yv[c] = *(const float4*)(y + (size_t)t * DM + lane * 16 + c * 4);
        *(float4*)(&ys[w][lane * 16 + c * 4]) = yv[c];
    }
    double s = 0.0;
    for (int kb = 0; kb < DM / 16; ++kb) {
        __syncthreads();
        {
            int row = tid >> 2, c4 = (tid & 3) << 2;
            float4 wv = *(const float4*)(Wd + (size_t)row * DM + kb * 16 + c4);
            wds[row][c4 + 0] = wv.x; wds[row][c4 + 1] = wv.y;
            wds[row][c4 + 2] = wv.z; wds[row][c4 + 3] = wv.w;
        }
        __syncthreads();
        #pragma unroll
        for (int i = 0; i < 16; ++i)
            s += (double)ys[w][kb * 16 + i] * (double)wds[lane][i];
    }
    int i0, i1;
    top2_64(s, lane, i0, i1);
    #pragma unroll
    for (int rr = 0; rr < 2; ++rr) {
        int idx = rr ? i1 : i0;
        const float* vrow = reflect_d + (size_t)idx * DM + lane * 16;
        float sv = 0.f, vn = 0.f;
        float4 vv[4];
        #pragma unroll
        for (int c = 0; c < 4; ++c) {
            vv[c] = *(const float4*)(vrow + c * 4);
            sv += vv[c].x * yv[c].x + vv[c].y * yv[c].y
                + vv[c].z * yv[c].z + vv[c].w * yv[c].w;
            vn += vv[c].x * vv[c].x + vv[c].y * vv[c].y
                + vv[c].z * vv[c].z + vv[c].w * vv[c].w;
        }
        #pragma unroll
        for (int m = 1; m < 64; m <<= 1) {
            sv += __shfl_xor(sv, m, 64);
            vn += __shfl_xor(vn, m, 64);
        }
        float coef = 2.0f * sv / (vn + 1e-8f);
        #pragma unroll
        for (int c = 0; c < 4; ++c) {
            yv[c].x -= coef * vv[c].x; yv[c].y -= coef * vv[c].y;
            yv[c].z -= coef * vv[c].z; yv[c].w -= coef * vv[c].w;
        }
    }
    #pragma unroll
    for (int c = 0; c < 4; ++c)
        *(float4*)(y + (size_t)t * DM + lane * 16 + c * 4) = yv[c];
    if (lane == 0) {
        out_id[(size_t)t * 2 + 0] = (float)i0;
        out_id[(size_t)t * 2 + 1] = (float)i1;
    }
}

extern "C" void kernel_launch(void* const* d_in, const int* in_sizes, int n_in,
                              void* d_out, int out_size, void* d_ws, size_t ws_size,
                              hipStream_t stream) {
    const float* x  = (const float*)d_in[0];
    const float* Wr = (const float*)d_in[1];
    const float* We = (const float*)d_in[2];
    const float* Wd = (const float*)d_in[3];
    const float* E  = (const float*)d_in[4];
    const float* rr = (const float*)d_in[5];
    const float* rd = (const float*)d_in[6];

    float* out    = (float*)d_out;
    float* y      = out + Y_OFF;
    float* out_ir = out + IR_OFF;
    float* out_w  = out + W_OFF;
    float* out_id = out + ID_OFF;

    if (ws_size >= WS_FULL) {
        char* p = (char*)d_ws;
        unsigned short* Ab  = (unsigned short*)p;  p += AB_BYTES;
        unsigned short* Ebt = (unsigned short*)p;  p += EBT_BYTES;
        float*          Xf  = (float*)p;           p += XF_BYTES;
        unsigned short* Xh  = (unsigned short*)p;  p += XH_BYTES;
        unsigned short* Xl  = (unsigned short*)p;  p += XH_BYTES;
        unsigned short* Gth = (unsigned short*)p;  p += GT_BYTES;
        unsigned short* Gtl = (unsigned short*)p;  p += GT_BYTES;
        float*          Sb  = (float*)p;           p += S_BYTES;
        double*         G64 = (double*)p;          p += G64_BYTES;
        double*         Srb = (double*)p;

        sr_fp64<<<TOK / 16, 256, 0, stream>>>(x, Wr, Srb);
        e_transpose<<<dim3(KTOT / 64, DM / 64), 256, 0, stream>>>(E, Ebt);
        g_fp64<<<KTOT / 16, 256, 0, stream>>>(E, Wd, G64, Gth, Gtl);
        k1_fast<<<TOK / 16, 256, 0, stream>>>(Srb, x, We, rr, Xf, Ab,
                                              Xh, Xl, out_ir, out_w);
        k2_mfma<<<dim3(DM / 128, TOK / 128), 256, 0, stream>>>(Ab, Ebt, y);
        s_mfma<<<TOK / 16, 256, 0, stream>>>(Xh, Xl, Gth, Gtl, out_w, Sb);
        refine_top2<<<TOK / 4, 256, 0, stream>>>(Sb, G64, Xf, out_w, out_id);
        k3_post<<<TOK / 4, 256, 0, stream>>>(out_id, rd, y);
    } else {
        float* xprime = (float*)d_ws;
        k1_tokens<<<TOK / 4, 256, 0, stream>>>(x, Wr, We, rr, xprime,
                                               out_ir, out_w);
        k2_gemm<<<dim3(DM / 128, TOK / 128), 256, 0, stream>>>(xprime, out_w, E, y);
        k3_full<<<TOK / 4, 256, 0, stream>>>(Wd, rd, y, out_id);
    }
}

// Round 7
// 397.846 us; speedup vs baseline: 2.7152x; 1.0666x over previous
//
#include <hip/hip_runtime.h>
#include <cmath>

#define TOK   8192
#define RNK   256
#define NEXP  16
#define NREF  64
#define DM    1024
#define KTOT  4096

#define Y_OFF  0
#define IR_OFF (TOK*DM)
#define W_OFF  (IR_OFF + TOK*2)
#define ID_OFF (W_OFF + TOK*NEXP)

#define EBT_BYTES ((size_t)DM * KTOT * 2)         // 8 MB
#define XF_BYTES  ((size_t)TOK * RNK * 4)         // 8 MB
#define XH_BYTES  ((size_t)TOK * RNK * 2)         // 4 MB
#define GT_BYTES  ((size_t)NEXP * NREF * RNK * 2) // 512 KB
#define S_BYTES   ((size_t)TOK * NREF * 4)        // 2 MB
#define G64_BYTES ((size_t)NREF * KTOT * 8)       // 2 MB
#define SR_BYTES  ((size_t)TOK * NREF * 8)        // 4 MB
#define WS_FULL   (EBT_BYTES + XF_BYTES + 2*XH_BYTES + 2*GT_BYTES + S_BYTES + G64_BYTES + SR_BYTES)

typedef __attribute__((ext_vector_type(8))) short short8;
typedef __attribute__((ext_vector_type(4))) float f32x4;
typedef const __attribute__((address_space(1))) void* gptr_t;
typedef __attribute__((address_space(3))) void* lptr_t;

__device__ inline unsigned short f2bf(float f) {    // RNE float->bf16
    unsigned int u = __float_as_uint(f);
    return (unsigned short)((u + 0x7fffu + ((u >> 16) & 1u)) >> 16);
}
__device__ inline float bf2f(unsigned short h) {
    return __uint_as_float(((unsigned int)h) << 16);
}
__device__ inline void split2(float v, unsigned short& h, unsigned short& l) {
    h = f2bf(v);
    l = f2bf(v - bf2f(h));
}
__device__ inline unsigned long long pack4(unsigned short a, unsigned short b,
                                           unsigned short c, unsigned short d) {
    return (unsigned long long)a | ((unsigned long long)b << 16)
         | ((unsigned long long)c << 32) | ((unsigned long long)d << 48);
}

// ---------- top-2 across a 64-lane wave, lax.top_k tie semantics ----------
__device__ inline void top2_64(double v, int idx, int& i0, int& i1) {
    double bv = v; int bi = idx;
    #pragma unroll
    for (int m = 1; m < 64; m <<= 1) {
        double ov = __shfl_xor(bv, m, 64);
        int    oi = __shfl_xor(bi, m, 64);
        if (ov > bv || (ov == bv && oi < bi)) { bv = ov; bi = oi; }
    }
    i0 = bi;
    double v2 = (idx == i0) ? -INFINITY : v;
    double bv2 = v2; int bi2 = idx;
    #pragma unroll
    for (int m = 1; m < 64; m <<= 1) {
        double ov = __shfl_xor(bv2, m, 64);
        int    oi = __shfl_xor(bi2, m, 64);
        if (ov > bv2 || (ov == bv2 && oi < bi2)) { bv2 = ov; bi2 = oi; }
    }
    i1 = bi2;
}

// ---------- Sr (fp64, LDS-tiled): Sr[t][n] = sum_r x[t,r]*Wr[n,r] ----------
__global__ __launch_bounds__(256) void sr_fp64(
    const float* __restrict__ x, const float* __restrict__ Wr,
    double* __restrict__ Sr)
{
    __shared__ float wt[64 * 65];
    const int tid = threadIdx.x;
    const int w = tid >> 6, n = tid & 63;
    const int t0 = blockIdx.x * 16;

    double acc[4] = {0.0, 0.0, 0.0, 0.0};
    const float* xr0 = x + (size_t)(t0 + w * 4 + 0) * RNK;
    const float* xr1 = x + (size_t)(t0 + w * 4 + 1) * RNK;
    const float* xr2 = x + (size_t)(t0 + w * 4 + 2) * RNK;
    const float* xr3 = x + (size_t)(t0 + w * 4 + 3) * RNK;

    for (int d0 = 0; d0 < RNK; d0 += 64) {
        __syncthreads();
        #pragma unroll
        for (int rep = 0; rep < 4; ++rep) {
            int f = rep * 256 + tid;
            int nn = f >> 4, dg = (f & 15) << 2;
            float4 v = *(const float4*)(Wr + (size_t)nn * RNK + d0 + dg);
            wt[(dg + 0) * 65 + nn] = v.x;
            wt[(dg + 1) * 65 + nn] = v.y;
            wt[(dg + 2) * 65 + nn] = v.z;
            wt[(dg + 3) * 65 + nn] = v.w;
        }
        __syncthreads();
        #pragma unroll
        for (int dg = 0; dg < 16; ++dg) {
            float4 e0 = *(const float4*)(xr0 + d0 + dg * 4);
            float4 e1 = *(const float4*)(xr1 + d0 + dg * 4);
            float4 e2 = *(const float4*)(xr2 + d0 + dg * 4);
            float4 e3 = *(const float4*)(xr3 + d0 + dg * 4);
            #pragma unroll
            for (int j = 0; j < 4; ++j) {
                double wv = (double)wt[(dg * 4 + j) * 65 + n];
                acc[0] = fma((double)(&e0.x)[j], wv, acc[0]);
                acc[1] = fma((double)(&e1.x)[j], wv, acc[1]);
                acc[2] = fma((double)(&e2.x)[j], wv, acc[2]);
                acc[3] = fma((double)(&e3.x)[j], wv, acc[3]);
            }
        }
    }
    #pragma unroll
    for (int i = 0; i < 4; ++i)
        Sr[(size_t)(t0 + w * 4 + i) * NREF + n] = acc[i];
}

// ---------- K1 fast: top2(Sr) -> reflections -> scores_e(LDS We) ----------
// No Ab production (k2_fused reads Xh directly).
__global__ __launch_bounds__(256) void k1_fast(
    const double* __restrict__ Sr, const float* __restrict__ x,
    const float* __restrict__ We, const float* __restrict__ reflect_r,
    float* __restrict__ xprime,
    unsigned short* __restrict__ Xh, unsigned short* __restrict__ Xl,
    float* __restrict__ out_ir, float* __restrict__ out_w)
{
    __shared__ float we_lds[16 * 260];
    __shared__ float xs[4][260];
    const int tid = threadIdx.x;
    const int w = tid >> 6, lane = tid & 63;

    #pragma unroll
    for (int rep = 0; rep < 4; ++rep) {
        int f = rep * 256 + tid;
        int row = f >> 6, c4 = (f & 63) << 2;
        float4 v = *(const float4*)(We + (size_t)row * RNK + c4);
        *(float4*)&we_lds[row * 260 + c4] = v;
    }
    __syncthreads();

    for (int it = 0; it < 4; ++it) {
        const int t = blockIdx.x * 16 + it * 4 + w;

        float4 xv = *(const float4*)(x + (size_t)t * RNK + lane * 4);
        double s = Sr[(size_t)t * NREF + lane];
        int i0, i1;
        top2_64(s, lane, i0, i1);

        #pragma unroll
        for (int rr = 0; rr < 2; ++rr) {
            int idx = rr ? i1 : i0;
            float4 vv = *(const float4*)(reflect_r + (size_t)idx * RNK + lane * 4);
            float sv = vv.x * xv.x + vv.y * xv.y + vv.z * xv.z + vv.w * xv.w;
            float vn = vv.x * vv.x + vv.y * vv.y + vv.z * vv.z + vv.w * vv.w;
            #pragma unroll
            for (int m = 1; m < 64; m <<= 1) {
                sv += __shfl_xor(sv, m, 64);
                vn += __shfl_xor(vn, m, 64);
            }
            float coef = 2.0f * sv / (vn + 1e-8f);
            xv.x -= coef * vv.x; xv.y -= coef * vv.y;
            xv.z -= coef * vv.z; xv.w -= coef * vv.w;
        }

        *(float4*)&xs[w][lane * 4] = xv;
        *(float4*)(xprime + (size_t)t * RNK + lane * 4) = xv;

        const int n16 = lane & 15;
        double se = 0.0;
        {
            const float* werow = &we_lds[n16 * 260];
            #pragma unroll 8
            for (int r4 = 0; r4 < RNK / 4; ++r4) {
                float4 xr = *(const float4*)(&xs[w][r4 * 4]);
                float4 wf = *(const float4*)(werow + r4 * 4);
                se += (double)xr.x * wf.x + (double)xr.y * wf.y
                    + (double)xr.z * wf.z + (double)xr.w * wf.w;
            }
        }
        float sef = (float)se;
        float mx = sef;
        #pragma unroll
        for (int m = 1; m < 16; m <<= 1) mx = fmaxf(mx, __shfl_xor(mx, m, 64));
        float ex = expf(sef - mx);
        float sm = ex;
        #pragma unroll
        for (int m = 1; m < 16; m <<= 1) sm += __shfl_xor(sm, m, 64);
        float wgt = ex / sm;

        if (lane < NEXP) out_w[(size_t)t * NEXP + lane] = wgt;
        if (lane == 0) {
            out_ir[(size_t)t * 2 + 0] = (float)i0;
            out_ir[(size_t)t * 2 + 1] = (float)i1;
        }

        unsigned short hx, lx, hy, ly, hz, lz, hw, lw;
        split2(xv.x, hx, lx); split2(xv.y, hy, ly);
        split2(xv.z, hz, lz); split2(xv.w, hw, lw);
        *(unsigned long long*)&Xh[(size_t)t * RNK + lane * 4] = pack4(hx, hy, hz, hw);
        *(unsigned long long*)&Xl[(size_t)t * RNK + lane * 4] = pack4(lx, ly, lz, lw);
    }
}

// ---------- K1 fallback (fp32 path, ws too small) ----------
__global__ __launch_bounds__(256) void k1_tokens(
    const float* __restrict__ x, const float* __restrict__ Wr,
    const float* __restrict__ We, const float* __restrict__ reflect_r,
    float* __restrict__ xprime, float* __restrict__ out_ir,
    float* __restrict__ out_w)
{
    __shared__ float xs[4][RNK];
    const int tid = threadIdx.x;
    const int w = tid >> 6, lane = tid & 63;
    const int t = blockIdx.x * 4 + w;

    float4 xv = *(const float4*)(x + (size_t)t * RNK + lane * 4);
    *(float4*)(&xs[w][lane * 4]) = xv;
    __syncthreads();

    double s = 0.0;
    {
        const float* wrow = Wr + (size_t)lane * RNK;
        for (int r4 = 0; r4 < RNK / 4; ++r4) {
            float4 xr = *(const float4*)(&xs[w][r4 * 4]);
            float4 wr = *(const float4*)(wrow + r4 * 4);
            s += (double)xr.x * wr.x + (double)xr.y * wr.y
               + (double)xr.z * wr.z + (double)xr.w * wr.w;
        }
    }
    int i0, i1;
    top2_64(s, lane, i0, i1);

    #pragma unroll
    for (int rr = 0; rr < 2; ++rr) {
        int idx = rr ? i1 : i0;
        float4 vv = *(const float4*)(reflect_r + (size_t)idx * RNK + lane * 4);
        float sv = vv.x * xv.x + vv.y * xv.y + vv.z * xv.z + vv.w * xv.w;
        float vn = vv.x * vv.x + vv.y * vv.y + vv.z * vv.z + vv.w * vv.w;
        #pragma unroll
        for (int m = 1; m < 64; m <<= 1) {
            sv += __shfl_xor(sv, m, 64);
            vn += __shfl_xor(vn, m, 64);
        }
        float coef = 2.0f * sv / (vn + 1e-8f);
        xv.x -= coef * vv.x; xv.y -= coef * vv.y;
        xv.z -= coef * vv.z; xv.w -= coef * vv.w;
    }
    __syncthreads();
    *(float4*)(&xs[w][lane * 4]) = xv;
    __syncthreads();

    *(float4*)(xprime + (size_t)t * RNK + lane * 4) = xv;

    const int n = lane & 15;
    double se = 0.0;
    {
        const float* werow = We + (size_t)n * RNK;
        for (int r4 = 0; r4 < RNK / 4; ++r4) {
            float4 xr = *(const float4*)(&xs[w][r4 * 4]);
            float4 wf = *(const float4*)(werow + r4 * 4);
            se += (double)xr.x * wf.x + (double)xr.y * wf.y
                + (double)xr.z * wf.z + (double)xr.w * wf.w;
        }
    }
    float sef = (float)se;
    float mx = sef;
    #pragma unroll
    for (int m = 1; m < 16; m <<= 1) mx = fmaxf(mx, __shfl_xor(mx, m, 64));
    float ex = expf(sef - mx);
    float sm = ex;
    #pragma unroll
    for (int m = 1; m < 16; m <<= 1) sm += __shfl_xor(sm, m, 64);
    float wgt = ex / sm;

    if (lane < NEXP) out_w[(size_t)t * NEXP + lane] = wgt;
    if (lane == 0) {
        out_ir[(size_t)t * 2 + 0] = (float)i0;
        out_ir[(size_t)t * 2 + 1] = (float)i1;
    }
}

// ---------- E transpose+convert: Ebt[d][k] = bf16(E[k][d]) ----------
__global__ __launch_bounds__(256) void e_transpose(
    const float* __restrict__ E, unsigned short* __restrict__ Ebt)
{
    __shared__ float lds[64][68];
    const int tid = threadIdx.x;
    const int k0 = blockIdx.x * 64, d0 = blockIdx.y * 64;
    #pragma unroll
    for (int rep = 0; rep < 4; ++rep) {
        int idx = rep * 256 + tid;
        int r = idx >> 4, c4 = (idx & 15) << 2;
        float4 v = *(const float4*)(E + (size_t)(k0 + r) * DM + d0 + c4);
        lds[r][c4 + 0] = v.x; lds[r][c4 + 1] = v.y;
        lds[r][c4 + 2] = v.z; lds[r][c4 + 3] = v.w;
    }
    __syncthreads();
    #pragma unroll
    for (int rep = 0; rep < 4; ++rep) {
        int idx = rep * 256 + tid;
        int dr = idx >> 4, kc4 = (idx & 15) << 2;
        *(unsigned long long*)&Ebt[(size_t)(d0 + dr) * KTOT + k0 + kc4] =
            pack4(f2bf(lds[kc4 + 0][dr]), f2bf(lds[kc4 + 1][dr]),
                  f2bf(lds[kc4 + 2][dr]), f2bf(lds[kc4 + 3][dr]));
    }
}

// ---------- G (fp64, LDS-tiled): G64t[n][k] = sum_d E[k,d]*Wd[n,d] ---------
__global__ __launch_bounds__(256) void g_fp64(
    const float* __restrict__ E, const float* __restrict__ Wd,
    double* __restrict__ G64t,
    unsigned short* __restrict__ Gth, unsigned short* __restrict__ Gtl)
{
    __shared__ float wt[64 * 65];
    const int tid = threadIdx.x;
    const int w = tid >> 6, n = tid & 63;
    const int k0 = blockIdx.x * 16;

    double acc[4] = {0.0, 0.0, 0.0, 0.0};
    const float* erow0 = E + (size_t)(k0 + w * 4 + 0) * DM;
    const float* erow1 = E + (size_t)(k0 + w * 4 + 1) * DM;
    const float* erow2 = E + (size_t)(k0 + w * 4 + 2) * DM;
    const float* erow3 = E + (size_t)(k0 + w * 4 + 3) * DM;

    for (int d0 = 0; d0 < DM; d0 += 64) {
        __syncthreads();
        #pragma unroll
        for (int rep = 0; rep < 4; ++rep) {
            int f = rep * 256 + tid;
            int nn = f >> 4, dg = (f & 15) << 2;
            float4 v = *(const float4*)(Wd + (size_t)nn * DM + d0 + dg);
            wt[(dg + 0) * 65 + nn] = v.x;
            wt[(dg + 1) * 65 + nn] = v.y;
            wt[(dg + 2) * 65 + nn] = v.z;
            wt[(dg + 3) * 65 + nn] = v.w;
        }
        __syncthreads();
        #pragma unroll
        for (int dg = 0; dg < 16; ++dg) {
            float4 e0 = *(const float4*)(erow0 + d0 + dg * 4);
            float4 e1 = *(const float4*)(erow1 + d0 + dg * 4);
            float4 e2 = *(const float4*)(erow2 + d0 + dg * 4);
            float4 e3 = *(const float4*)(erow3 + d0 + dg * 4);
            #pragma unroll
            for (int j = 0; j < 4; ++j) {
                double wv = (double)wt[(dg * 4 + j) * 65 + n];
                acc[0] = fma((double)(&e0.x)[j], wv, acc[0]);
                acc[1] = fma((double)(&e1.x)[j], wv, acc[1]);
                acc[2] = fma((double)(&e2.x)[j], wv, acc[2]);
                acc[3] = fma((double)(&e3.x)[j], wv, acc[3]);
            }
        }
    }

    #pragma unroll
    for (int i = 0; i < 4; ++i) {
        int k = k0 + w * 4 + i;
        G64t[(size_t)n * KTOT + k] = acc[i];
        float gf = (float)acc[i];
        unsigned short h, lo;
        split2(gf, h, lo);
        const int e = k >> 8, r = k & 255;
        Gth[((size_t)(e * NREF + n)) * RNK + r] = h;
        Gtl[((size_t)(e * NREF + n)) * RNK + r] = lo;
    }
}

// ---------- S approx: S[t][n] = sum_e w[t,e]*(x'[t,:].G_e[:,n]) ----------
__global__ __launch_bounds__(256) void s_mfma(
    const unsigned short* __restrict__ Xh, const unsigned short* __restrict__ Xl,
    const unsigned short* __restrict__ Gth, const unsigned short* __restrict__ Gtl,
    const float* __restrict__ wts, float* __restrict__ S)
{
    __shared__ float red[4][16][64];
    const int tid = threadIdx.x, l = tid & 63, w = tid >> 6;
    const int t0 = blockIdx.x * 16;

    short8 ah[8], al[8];
    {
        const size_t abase = (size_t)(t0 + (l & 15)) * RNK + (l >> 4) * 8;
        #pragma unroll
        for (int ks = 0; ks < 8; ++ks) {
            ah[ks] = *(const short8*)&Xh[abase + ks * 32];
            al[ks] = *(const short8*)&Xl[abase + ks * 32];
        }
    }

    f32x4 Sacc[4] = {};
    #pragma unroll
    for (int ei = 0; ei < 4; ++ei) {
        const int e = w * 4 + ei;
        f32x4 acc[4] = {};
        #pragma unroll
        for (int ks = 0; ks < 8; ++ks) {
            #pragma unroll
            for (int nn = 0; nn < 4; ++nn) {
                size_t gbase = ((size_t)(e * NREF + nn * 16 + (l & 15))) * RNK
                             + ks * 32 + (l >> 4) * 8;
                short8 bh = *(const short8*)&Gth[gbase];
                short8 bl = *(const short8*)&Gtl[gbase];
                acc[nn] = __builtin_amdgcn_mfma_f32_16x16x32_bf16(al[ks], bh, acc[nn], 0, 0, 0);
                acc[nn] = __builtin_amdgcn_mfma_f32_16x16x32_bf16(ah[ks], bl, acc[nn], 0, 0, 0);
                acc[nn] = __builtin_amdgcn_mfma_f32_16x16x32_bf16(ah[ks], bh, acc[nn], 0, 0, 0);
            }
        }
        #pragma unroll
        for (int j = 0; j < 4; ++j) {
            float wv = wts[(size_t)(t0 + (l >> 4) * 4 + j) * NEXP + e];
            #pragma unroll
            for (int nn = 0; nn < 4; ++nn) Sacc[nn][j] += wv * acc[nn][j];
        }
    }
    #pragma unroll
    for (int nn = 0; nn < 4; ++nn)
        #pragma unroll
        for (int j = 0; j < 4; ++j)
            red[w][(l >> 4) * 4 + j][nn * 16 + (l & 15)] = Sacc[nn][j];
    __syncthreads();
    for (int i = tid; i < 16 * 64; i += 256) {
        int tt = i >> 6, nn = i & 63;
        float sv = red[0][tt][nn] + red[1][tt][nn] + red[2][tt][nn] + red[3][tt][nn];
        S[(size_t)(t0 + tt) * NREF + nn] = sv;
    }
}

// ---------- refine: approx top-4 -> exact fp64 scores -> top-2 ----------
__global__ __launch_bounds__(256) void refine_top2(
    const float* __restrict__ S, const double* __restrict__ G64t,
    const float* __restrict__ xf, const float* __restrict__ wts,
    float* __restrict__ out_id)
{
    __shared__ float xs[4][RNK];
    __shared__ float wsh[4][NEXP];
    const int tid = threadIdx.x, w = tid >> 6, lane = tid & 63;
    const int t = blockIdx.x * 4 + w;

    *(float4*)&xs[w][lane * 4] = *(const float4*)(xf + (size_t)t * RNK + lane * 4);
    if (lane < NEXP) wsh[w][lane] = wts[(size_t)t * NEXP + lane];
    __syncthreads();

    float cur = S[(size_t)t * NREF + lane];
    int cand[4];
    #pragma unroll
    for (int c = 0; c < 4; ++c) {
        float bv = cur; int bi = lane;
        #pragma unroll
        for (int m = 1; m < 64; m <<= 1) {
            float ov = __shfl_xor(bv, m, 64);
            int   oi = __shfl_xor(bi, m, 64);
            if (ov > bv || (ov == bv && oi < bi)) { bv = ov; bi = oi; }
        }
        cand[c] = bi;
        if (lane == bi) cur = -INFINITY;
    }

    double rs[4];
    #pragma unroll
    for (int c = 0; c < 4; ++c) {
        const double* grow = G64t + (size_t)cand[c] * KTOT;
        double acc = 0.0;
        #pragma unroll 4
        for (int i = 0; i < 64; ++i) {
            int k = i * 64 + lane;
            double a = (double)wsh[w][k >> 8] * (double)xs[w][k & 255];
            acc = fma(a, grow[k], acc);
        }
        #pragma unroll
        for (int m = 1; m < 64; m <<= 1) acc += __shfl_xor(acc, m, 64);
        rs[c] = acc;
    }

    int b0 = 0;
    #pragma unroll
    for (int c = 1; c < 4; ++c)
        if (rs[c] > rs[b0] || (rs[c] == rs[b0] && cand[c] < cand[b0])) b0 = c;
    int b1 = (b0 == 0) ? 1 : 0;
    #pragma unroll
    for (int c = 0; c < 4; ++c) {
        if (c == b0) continue;
        if (rs[c] > rs[b1] || (rs[c] == rs[b1] && cand[c] < cand[b1])) b1 = c;
    }
    if (lane == 0) {
        out_id[(size_t)t * 2 + 0] = (float)cand[b0];
        out_id[(size_t)t * 2 + 1] = (float)cand[b1];
    }
}

// ---------- K2 fused: y[t,d] = sum_e w[t,e] * (Xh[t,:] @ E_e[:,d]) ---------
// A-tiles straight from Xh (L2/L3-resident), per-expert fp32 fold of w.
// Swizzle p(row) = (row>>1)&3 -> 2-way bank aliasing only (free).
__global__ __launch_bounds__(256) void k2_fused(
    const unsigned short* __restrict__ Xh,
    const unsigned short* __restrict__ Ebt,
    const float* __restrict__ wts,
    float* __restrict__ y)
{
    __shared__ unsigned short As[128 * 32];
    __shared__ unsigned short Bs[128 * 32];
    __shared__ float wt[NEXP * 132];
    const int tid = threadIdx.x;
    const int l = tid & 63, w = tid >> 6;
    const int wr = w >> 1, wc = w & 1;
    const int tm0 = blockIdx.y * 128, n0 = blockIdx.x * 128;
    const int lrow = l >> 2, s = l & 3, g = l >> 4;

    // stage w transposed: wt[e][row], 128 tokens x 16 experts
    #pragma unroll
    for (int rep = 0; rep < 8; ++rep) {
        int f = rep * 256 + tid;
        int row = f >> 4, e = f & 15;
        wt[e * 132 + row] = wts[(size_t)(tm0 + row) * NEXP + e];
    }

    f32x4 acc[4][4] = {};

    for (int e = 0; e < NEXP; ++e) {
        f32x4 acc_e[4][4] = {};
        for (int kb8 = 0; kb8 < 8; ++kb8) {
            const int kb = e * 8 + kb8;
            __syncthreads();
            #pragma unroll
            for (int i = 0; i < 2; ++i) {
                int row = w * 32 + i * 16 + lrow;
                int sw = ((s ^ ((row >> 1) & 3)) << 4);
                const char* ga = (const char*)Xh
                    + ((size_t)(tm0 + row) * RNK + kb8 * 32) * 2 + sw;
                __builtin_amdgcn_global_load_lds((gptr_t)ga,
                    (lptr_t)&As[(w * 32 + i * 16) * 32], 16, 0, 0);
                const char* gb = (const char*)Ebt
                    + ((size_t)(n0 + row) * KTOT + kb * 32) * 2 + sw;
                __builtin_amdgcn_global_load_lds((gptr_t)gb,
                    (lptr_t)&Bs[(w * 32 + i * 16) * 32], 16, 0, 0);
            }
            __syncthreads();

            short8 af[4], bv[4];
            #pragma unroll
            for (int m = 0; m < 4; ++m) {
                int row = wr * 64 + m * 16 + (l & 15);
                af[m] = *(const short8*)&As[row * 32 + ((g ^ ((row >> 1) & 3)) << 3)];
            }
            #pragma unroll
            for (int nn = 0; nn < 4; ++nn) {
                int row = wc * 64 + nn * 16 + (l & 15);
                bv[nn] = *(const short8*)&Bs[row * 32 + ((g ^ ((row >> 1) & 3)) << 3)];
            }
            #pragma unroll
            for (int m = 0; m < 4; ++m)
                #pragma unroll
                for (int nn = 0; nn < 4; ++nn)
                    acc_e[m][nn] = __builtin_amdgcn_mfma_f32_16x16x32_bf16(
                        af[m], bv[nn], acc_e[m][nn], 0, 0, 0);
        }
        // fold expert weight in fp32
        #pragma unroll
        for (int m = 0; m < 4; ++m) {
            int rowb = wr * 64 + m * 16 + (l >> 4) * 4;
            float4 wm = *(const float4*)&wt[e * 132 + rowb];
            #pragma unroll
            for (int nn = 0; nn < 4; ++nn) {
                #pragma unroll
                for (int j = 0; j < 4; ++j)
                    acc[m][nn][j] += (&wm.x)[j] * acc_e[m][nn][j];
            }
        }
    }

    #pragma unroll
    for (int m = 0; m < 4; ++m) {
        int rbase = tm0 + wr * 64 + m * 16 + (l >> 4) * 4;
        #pragma unroll
        for (int nn = 0; nn < 4; ++nn) {
            int c = n0 + wc * 64 + nn * 16 + (l & 15);
            #pragma unroll
            for (int j = 0; j < 4; ++j)
                y[(size_t)(rbase + j) * DM + c] = acc[m][nn][j];
        }
    }
}

// ---------- K2 fp32 fallback ----------
__global__ __launch_bounds__(256) void k2_gemm(
    const float* __restrict__ xp, const float* __restrict__ wts,
    const float* __restrict__ E, float* __restrict__ y)
{
    __shared__ float As[16][132];
    __shared__ float Bs[16][132];
    const int tid = threadIdx.x;
    const int bn = blockIdx.x, bm = blockIdx.y;
    const int tm0 = bm * 128, tn0 = bn * 128;
    const int ty = tid >> 4, tx = tid & 15;
    float acc[8][8] = {};
    for (int kb = 0; kb < KTOT / 16; ++kb) {
        const int e = kb >> 4;
        const int rbase = (kb & 15) << 4;
        const int kglob = kb << 4;
        __syncthreads();
        #pragma unroll
        for (int h = 0; h < 2; ++h) {
            int f = tid + h * 256;
            int m = f >> 2, k4 = (f & 3) << 2;
            int t = tm0 + m;
            float4 a = *(const float4*)(xp + (size_t)t * RNK + rbase + k4);
            float wv = wts[(size_t)t * NEXP + e];
            As[k4 + 0][m] = a.x * wv; As[k4 + 1][m] = a.y * wv;
            As[k4 + 2][m] = a.z * wv; As[k4 + 3][m] = a.w * wv;
        }
        #pragma unroll
        for (int h = 0; h < 2; ++h) {
            int f = tid + h * 256;
            int kk = f >> 5, d4 = (f & 31) << 2;
            float4 b = *(const float4*)(E + (size_t)(kglob + kk) * DM + tn0 + d4);
            *(float4*)(&Bs[kk][d4]) = b;
        }
        __syncthreads();
        #pragma unroll
        for (int kk = 0; kk < 16; ++kk) {
            float4 a0 = *(const float4*)(&As[kk][ty * 8]);
            float4 a1 = *(const float4*)(&As[kk][ty * 8 + 4]);
            float4 b0 = *(const float4*)(&Bs[kk][tx * 8]);
            float4 b1 = *(const float4*)(&Bs[kk][tx * 8 + 4]);
            float av[8] = {a0.x, a0.y, a0.z, a0.w, a1.x, a1.y, a1.z, a1.w};
            float bw[8] = {b0.x, b0.y, b0.z, b0.w, b1.x, b1.y, b1.z, b1.w};
            #pragma unroll
            for (int i = 0; i < 8; ++i)
                #pragma unroll
                for (int j = 0; j < 8; ++j)
                    acc[i][j] = fmaf(av[i], bw[j], acc[i][j]);
        }
    }
    #pragma unroll
    for (int i = 0; i < 8; ++i) {
        int t = tm0 + ty * 8 + i;
        float* yrow = y + (size_t)t * DM + tn0 + tx * 8;
        *(float4*)yrow       = make_float4(acc[i][0], acc[i][1], acc[i][2], acc[i][3]);
        *(float4*)(yrow + 4) = make_float4(acc[i][4], acc[i][5], acc[i][6], acc[i][7]);
    }
}

// ---------- K3: read refined indices -> 2 reflections on y (in place) -----
__global__ __launch_bounds__(256) void k3_post(
    const float* __restrict__ out_id, const float* __restrict__ reflect_d,
    float* __restrict__ y)
{
    const int tid = threadIdx.x;
    const int w = tid >> 6, lane = tid & 63;
    const int t = blockIdx.x * 4 + w;

    float4 yv[4];
    #pragma unroll
    for (int c = 0; c < 4; ++c)
        yv[c] = *(const float4*)(y + (size_t)t * DM + lane * 16 + c * 4);

    const int i0 = (int)out_id[(size_t)t * 2 + 0];
    const int i1 = (int)out_id[(size_t)t * 2 + 1];

    #pragma unroll
    for (int rr = 0; rr < 2; ++rr) {
        int idx = rr ? i1 : i0;
        const float* vrow = reflect_d + (size_t)idx * DM + lane * 16;
        float sv = 0.f, vn = 0.f;
        float4 vv[4];
        #pragma unroll
        for (int c = 0; c < 4; ++c) {
            vv[c] = *(const float4*)(vrow + c * 4);
            sv += vv[c].x * yv[c].x + vv[c].y * yv[c].y
                + vv[c].z * yv[c].z + vv[c].w * yv[c].w;
            vn += vv[c].x * vv[c].x + vv[c].y * vv[c].y
                + vv[c].z * vv[c].z + vv[c].w * vv[c].w;
        }
        #pragma unroll
        for (int m = 1; m < 64; m <<= 1) {
            sv += __shfl_xor(sv, m, 64);
            vn += __shfl_xor(vn, m, 64);
        }
        float coef = 2.0f * sv / (vn + 1e-8f);
        #pragma unroll
        for (int c = 0; c < 4; ++c) {
            yv[c].x -= coef * vv[c].x; yv[c].y -= coef * vv[c].y;
            yv[c].z -= coef * vv[c].z; yv[c].w -= coef * vv[c].w;
        }
    }
    #pragma unroll
    for (int c = 0; c < 4; ++c)
        *(float4*)(y + (size_t)t * DM + lane * 16 + c * 4) = yv[c];
}

// ---------- K3 fallback (scores_d from fp32 y, top2, reflect) ----------
__global__ __launch_bounds__(256) void k3_full(
    const float* __restrict__ Wd, const float* __restrict__ reflect_d,
    float* __restrict__ y, float* __restrict__ out_id)
{
    __shared__ float ys[4][DM];
    __shared__ float wds[64][17];
    const int tid = threadIdx.x;
    const int w = tid >> 6, lane = tid & 63;
    const int t = blockIdx.x * 4 + w;

    float4 yv[4];
    #pragma unroll
    for (int c = 0; c < 4; ++c) {
        yv[c] = *(const float4*)(y + (size_t)t * DM + lane * 16 + c * 4);
        *(float4*)(&ys[w][lane * 16 + c * 4]) = yv[c];
    }
    double s = 0.0;
    for (int kb = 0; kb < DM / 16; ++kb) {
        __syncthreads();
        {
            int row = tid >> 2, c4 = (tid & 3) << 2;
            float4 wv = *(const float4*)(Wd + (size_t)row * DM + kb * 16 + c4);
            wds[row][c4 + 0] = wv.x; wds[row][c4 + 1] = wv.y;
            wds[row][c4 + 2] = wv.z; wds[row][c4 + 3] = wv.w;
        }
        __syncthreads();
        #pragma unroll
        for (int i = 0; i < 16; ++i)
            s += (double)ys[w][kb * 16 + i] * (double)wds[lane][i];
    }
    int i0, i1;
    top2_64(s, lane, i0, i1);
    #pragma unroll
    for (int rr = 0; rr < 2; ++rr) {
        int idx = rr ? i1 : i0;
        const float* vrow = reflect_d + (size_t)idx * DM + lane * 16;
        float sv = 0.f, vn = 0.f;
        float4 vv[4];
        #pragma unroll
        for (int c = 0; c < 4; ++c) {
            vv[c] = *(const float4*)(vrow + c * 4);
            sv += vv[c].x * yv[c].x + vv[c].y * yv[c].y
                + vv[c].z * yv[c].z + vv[c].w * yv[c].w;
            vn += vv[c].x * vv[c].x + vv[c].y * vv[c].y
                + vv[c].z * vv[c].z + vv[c].w * vv[c].w;
        }
        #pragma unroll
        for (int m = 1; m < 64; m <<= 1) {
            sv += __shfl_xor(sv, m, 64);
            vn += __shfl_xor(vn, m, 64);
        }
        float coef = 2.0f * sv / (vn + 1e-8f);
        #pragma unroll
        for (int c = 0; c < 4; ++c) {
            yv[c].x -= coef * vv[c].x; yv[c].y -= coef * vv[c].y;
            yv[c].z -= coef * vv[c].z; yv[c].w -= coef * vv[c].w;
        }
    }
    #pragma unroll
    for (int c = 0; c < 4; ++c)
        *(float4*)(y + (size_t)t * DM + lane * 16 + c * 4) = yv[c];
    if (lane == 0) {
        out_id[(size_t)t * 2 + 0] = (float)i0;
        out_id[(size_t)t * 2 + 1] = (float)i1;
    }
}

extern "C" void kernel_launch(void* const* d_in, const int* in_sizes, int n_in,
                              void* d_out, int out_size, void* d_ws, size_t ws_size,
                              hipStream_t stream) {
    const float* x  = (const float*)d_in[0];
    const float* Wr = (const float*)d_in[1];
    const float* We = (const float*)d_in[2];
    const float* Wd = (const float*)d_in[3];
    const float* E  = (const float*)d_in[4];
    const float* rr = (const float*)d_in[5];
    const float* rd = (const float*)d_in[6];

    float* out    = (float*)d_out;
    float* y      = out + Y_OFF;
    float* out_ir = out + IR_OFF;
    float* out_w  = out + W_OFF;
    float* out_id = out + ID_OFF;

    if (ws_size >= WS_FULL) {
        char* p = (char*)d_ws;
        unsigned short* Ebt = (unsigned short*)p;  p += EBT_BYTES;
        float*          Xf  = (float*)p;           p += XF_BYTES;
        unsigned short* Xh  = (unsigned short*)p;  p += XH_BYTES;
        unsigned short* Xl  = (unsigned short*)p;  p += XH_BYTES;
        unsigned short* Gth = (unsigned short*)p;  p += GT_BYTES;
        unsigned short* Gtl = (unsigned short*)p;  p += GT_BYTES;
        float*          Sb  = (float*)p;           p += S_BYTES;
        double*         G64 = (double*)p;          p += G64_BYTES;
        double*         Srb = (double*)p;

        sr_fp64<<<TOK / 16, 256, 0, stream>>>(x, Wr, Srb);
        e_transpose<<<dim3(KTOT / 64, DM / 64), 256, 0, stream>>>(E, Ebt);
        g_fp64<<<KTOT / 16, 256, 0, stream>>>(E, Wd, G64, Gth, Gtl);
        k1_fast<<<TOK / 16, 256, 0, stream>>>(Srb, x, We, rr, Xf,
                                              Xh, Xl, out_ir, out_w);
        k2_fused<<<dim3(DM / 128, TOK / 128), 256, 0, stream>>>(Xh, Ebt, out_w, y);
        s_mfma<<<TOK / 16, 256, 0, stream>>>(Xh, Xl, Gth, Gtl, out_w, Sb);
        refine_top2<<<TOK / 4, 256, 0, stream>>>(Sb, G64, Xf, out_w, out_id);
        k3_post<<<TOK / 4, 256, 0, stream>>>(out_id, rd, y);
    } else {
        float* xprime = (float*)d_ws;
        k1_tokens<<<TOK / 4, 256, 0, stream>>>(x, Wr, We, rr, xprime,
                                               out_ir, out_w);
        k2_gemm<<<dim3(DM / 128, TOK / 128), 256, 0, stream>>>(xprime, out_w, E, y);
        k3_full<<<TOK / 4, 256, 0, stream>>>(Wd, rd, y, out_id);
    }
}

// Round 8
// 333.213 us; speedup vs baseline: 3.2418x; 1.1940x over previous
//
#include <hip/hip_runtime.h>
#include <cmath>

#define TOK   8192
#define RNK   256
#define NEXP  16
#define NREF  64
#define DM    1024
#define KTOT  4096

#define Y_OFF  0
#define IR_OFF (TOK*DM)
#define W_OFF  (IR_OFF + TOK*2)
#define ID_OFF (W_OFF + TOK*NEXP)

#define EBT_BYTES ((size_t)DM * KTOT * 2)         // 8 MB
#define XF_BYTES  ((size_t)TOK * RNK * 4)         // 8 MB
#define XH_BYTES  ((size_t)TOK * RNK * 2)         // 4 MB
#define GT_BYTES  ((size_t)NEXP * NREF * RNK * 2) // 512 KB
#define S_BYTES   ((size_t)TOK * NREF * 4)        // 2 MB
#define G64_BYTES ((size_t)NREF * KTOT * 8)       // 2 MB
#define SR_BYTES  ((size_t)TOK * NREF * 8)        // 4 MB
#define WS_FULL   (EBT_BYTES + XF_BYTES + 2*XH_BYTES + 2*GT_BYTES + S_BYTES + G64_BYTES + SR_BYTES)

typedef __attribute__((ext_vector_type(8))) short short8;
typedef __attribute__((ext_vector_type(4))) float f32x4;
typedef const __attribute__((address_space(1))) void* gptr_t;
typedef __attribute__((address_space(3))) void* lptr_t;

__device__ inline unsigned short f2bf(float f) {    // RNE float->bf16
    unsigned int u = __float_as_uint(f);
    return (unsigned short)((u + 0x7fffu + ((u >> 16) & 1u)) >> 16);
}
__device__ inline float bf2f(unsigned short h) {
    return __uint_as_float(((unsigned int)h) << 16);
}
__device__ inline void split2(float v, unsigned short& h, unsigned short& l) {
    h = f2bf(v);
    l = f2bf(v - bf2f(h));
}
__device__ inline unsigned long long pack4(unsigned short a, unsigned short b,
                                           unsigned short c, unsigned short d) {
    return (unsigned long long)a | ((unsigned long long)b << 16)
         | ((unsigned long long)c << 32) | ((unsigned long long)d << 48);
}

// ---------- top-2 across a 64-lane wave, lax.top_k tie semantics ----------
__device__ inline void top2_64(double v, int idx, int& i0, int& i1) {
    double bv = v; int bi = idx;
    #pragma unroll
    for (int m = 1; m < 64; m <<= 1) {
        double ov = __shfl_xor(bv, m, 64);
        int    oi = __shfl_xor(bi, m, 64);
        if (ov > bv || (ov == bv && oi < bi)) { bv = ov; bi = oi; }
    }
    i0 = bi;
    double v2 = (idx == i0) ? -INFINITY : v;
    double bv2 = v2; int bi2 = idx;
    #pragma unroll
    for (int m = 1; m < 64; m <<= 1) {
        double ov = __shfl_xor(bv2, m, 64);
        int    oi = __shfl_xor(bi2, m, 64);
        if (ov > bv2 || (ov == bv2 && oi < bi2)) { bv2 = ov; bi2 = oi; }
    }
    i1 = bi2;
}

// ---------- Sr (fp64, LDS-tiled): Sr[t][n] = sum_r x[t,r]*Wr[n,r] ----------
// Block = 8 tokens x 64 n (2 tokens/thread) -> 1024 blocks, 4 blocks/CU.
// Per-token d-order identical to previous version -> bit-identical Sr.
__global__ __launch_bounds__(256) void sr_fp64(
    const float* __restrict__ x, const float* __restrict__ Wr,
    double* __restrict__ Sr)
{
    __shared__ float wt[64 * 65];
    const int tid = threadIdx.x;
    const int w = tid >> 6, n = tid & 63;
    const int t0 = blockIdx.x * 8;

    double acc[2] = {0.0, 0.0};
    const float* xr0 = x + (size_t)(t0 + w * 2 + 0) * RNK;
    const float* xr1 = x + (size_t)(t0 + w * 2 + 1) * RNK;

    for (int d0 = 0; d0 < RNK; d0 += 64) {
        __syncthreads();
        #pragma unroll
        for (int rep = 0; rep < 4; ++rep) {
            int f = rep * 256 + tid;
            int nn = f >> 4, dg = (f & 15) << 2;
            float4 v = *(const float4*)(Wr + (size_t)nn * RNK + d0 + dg);
            wt[(dg + 0) * 65 + nn] = v.x;
            wt[(dg + 1) * 65 + nn] = v.y;
            wt[(dg + 2) * 65 + nn] = v.z;
            wt[(dg + 3) * 65 + nn] = v.w;
        }
        __syncthreads();
        #pragma unroll
        for (int dg = 0; dg < 16; ++dg) {
            float4 e0 = *(const float4*)(xr0 + d0 + dg * 4);
            float4 e1 = *(const float4*)(xr1 + d0 + dg * 4);
            #pragma unroll
            for (int j = 0; j < 4; ++j) {
                double wv = (double)wt[(dg * 4 + j) * 65 + n];
                acc[0] = fma((double)(&e0.x)[j], wv, acc[0]);
                acc[1] = fma((double)(&e1.x)[j], wv, acc[1]);
            }
        }
    }
    #pragma unroll
    for (int i = 0; i < 2; ++i)
        Sr[(size_t)(t0 + w * 2 + i) * NREF + n] = acc[i];
}

// ---------- K1 fast: top2(Sr) -> reflections -> scores_e(LDS We) ----------
__global__ __launch_bounds__(256) void k1_fast(
    const double* __restrict__ Sr, const float* __restrict__ x,
    const float* __restrict__ We, const float* __restrict__ reflect_r,
    float* __restrict__ xprime,
    unsigned short* __restrict__ Xh, unsigned short* __restrict__ Xl,
    float* __restrict__ out_ir, float* __restrict__ out_w)
{
    __shared__ float we_lds[16 * 260];
    __shared__ float xs[4][260];
    const int tid = threadIdx.x;
    const int w = tid >> 6, lane = tid & 63;

    #pragma unroll
    for (int rep = 0; rep < 4; ++rep) {
        int f = rep * 256 + tid;
        int row = f >> 6, c4 = (f & 63) << 2;
        float4 v = *(const float4*)(We + (size_t)row * RNK + c4);
        *(float4*)&we_lds[row * 260 + c4] = v;
    }
    __syncthreads();

    for (int it = 0; it < 4; ++it) {
        const int t = blockIdx.x * 16 + it * 4 + w;

        float4 xv = *(const float4*)(x + (size_t)t * RNK + lane * 4);
        double s = Sr[(size_t)t * NREF + lane];
        int i0, i1;
        top2_64(s, lane, i0, i1);

        #pragma unroll
        for (int rr = 0; rr < 2; ++rr) {
            int idx = rr ? i1 : i0;
            float4 vv = *(const float4*)(reflect_r + (size_t)idx * RNK + lane * 4);
            float sv = vv.x * xv.x + vv.y * xv.y + vv.z * xv.z + vv.w * xv.w;
            float vn = vv.x * vv.x + vv.y * vv.y + vv.z * vv.z + vv.w * vv.w;
            #pragma unroll
            for (int m = 1; m < 64; m <<= 1) {
                sv += __shfl_xor(sv, m, 64);
                vn += __shfl_xor(vn, m, 64);
            }
            float coef = 2.0f * sv / (vn + 1e-8f);
            xv.x -= coef * vv.x; xv.y -= coef * vv.y;
            xv.z -= coef * vv.z; xv.w -= coef * vv.w;
        }

        *(float4*)&xs[w][lane * 4] = xv;
        *(float4*)(xprime + (size_t)t * RNK + lane * 4) = xv;

        const int n16 = lane & 15;
        double se = 0.0;
        {
            const float* werow = &we_lds[n16 * 260];
            #pragma unroll 8
            for (int r4 = 0; r4 < RNK / 4; ++r4) {
                float4 xr = *(const float4*)(&xs[w][r4 * 4]);
                float4 wf = *(const float4*)(werow + r4 * 4);
                se += (double)xr.x * wf.x + (double)xr.y * wf.y
                    + (double)xr.z * wf.z + (double)xr.w * wf.w;
            }
        }
        float sef = (float)se;
        float mx = sef;
        #pragma unroll
        for (int m = 1; m < 16; m <<= 1) mx = fmaxf(mx, __shfl_xor(mx, m, 64));
        float ex = expf(sef - mx);
        float sm = ex;
        #pragma unroll
        for (int m = 1; m < 16; m <<= 1) sm += __shfl_xor(sm, m, 64);
        float wgt = ex / sm;

        if (lane < NEXP) out_w[(size_t)t * NEXP + lane] = wgt;
        if (lane == 0) {
            out_ir[(size_t)t * 2 + 0] = (float)i0;
            out_ir[(size_t)t * 2 + 1] = (float)i1;
        }

        unsigned short hx, lx, hy, ly, hz, lz, hw, lw;
        split2(xv.x, hx, lx); split2(xv.y, hy, ly);
        split2(xv.z, hz, lz); split2(xv.w, hw, lw);
        *(unsigned long long*)&Xh[(size_t)t * RNK + lane * 4] = pack4(hx, hy, hz, hw);
        *(unsigned long long*)&Xl[(size_t)t * RNK + lane * 4] = pack4(lx, ly, lz, lw);
    }
}

// ---------- K1 fallback (fp32 path, ws too small) ----------
__global__ __launch_bounds__(256) void k1_tokens(
    const float* __restrict__ x, const float* __restrict__ Wr,
    const float* __restrict__ We, const float* __restrict__ reflect_r,
    float* __restrict__ xprime, float* __restrict__ out_ir,
    float* __restrict__ out_w)
{
    __shared__ float xs[4][RNK];
    const int tid = threadIdx.x;
    const int w = tid >> 6, lane = tid & 63;
    const int t = blockIdx.x * 4 + w;

    float4 xv = *(const float4*)(x + (size_t)t * RNK + lane * 4);
    *(float4*)(&xs[w][lane * 4]) = xv;
    __syncthreads();

    double s = 0.0;
    {
        const float* wrow = Wr + (size_t)lane * RNK;
        for (int r4 = 0; r4 < RNK / 4; ++r4) {
            float4 xr = *(const float4*)(&xs[w][r4 * 4]);
            float4 wr = *(const float4*)(wrow + r4 * 4);
            s += (double)xr.x * wr.x + (double)xr.y * wr.y
               + (double)xr.z * wr.z + (double)xr.w * wr.w;
        }
    }
    int i0, i1;
    top2_64(s, lane, i0, i1);

    #pragma unroll
    for (int rr = 0; rr < 2; ++rr) {
        int idx = rr ? i1 : i0;
        float4 vv = *(const float4*)(reflect_r + (size_t)idx * RNK + lane * 4);
        float sv = vv.x * xv.x + vv.y * xv.y + vv.z * xv.z + vv.w * xv.w;
        float vn = vv.x * vv.x + vv.y * vv.y + vv.z * vv.z + vv.w * vv.w;
        #pragma unroll
        for (int m = 1; m < 64; m <<= 1) {
            sv += __shfl_xor(sv, m, 64);
            vn += __shfl_xor(vn, m, 64);
        }
        float coef = 2.0f * sv / (vn + 1e-8f);
        xv.x -= coef * vv.x; xv.y -= coef * vv.y;
        xv.z -= coef * vv.z; xv.w -= coef * vv.w;
    }
    __syncthreads();
    *(float4*)(&xs[w][lane * 4]) = xv;
    __syncthreads();

    *(float4*)(xprime + (size_t)t * RNK + lane * 4) = xv;

    const int n = lane & 15;
    double se = 0.0;
    {
        const float* werow = We + (size_t)n * RNK;
        for (int r4 = 0; r4 < RNK / 4; ++r4) {
            float4 xr = *(const float4*)(&xs[w][r4 * 4]);
            float4 wf = *(const float4*)(werow + r4 * 4);
            se += (double)xr.x * wf.x + (double)xr.y * wf.y
                + (double)xr.z * wf.z + (double)xr.w * wf.w;
        }
    }
    float sef = (float)se;
    float mx = sef;
    #pragma unroll
    for (int m = 1; m < 16; m <<= 1) mx = fmaxf(mx, __shfl_xor(mx, m, 64));
    float ex = expf(sef - mx);
    float sm = ex;
    #pragma unroll
    for (int m = 1; m < 16; m <<= 1) sm += __shfl_xor(sm, m, 64);
    float wgt = ex / sm;

    if (lane < NEXP) out_w[(size_t)t * NEXP + lane] = wgt;
    if (lane == 0) {
        out_ir[(size_t)t * 2 + 0] = (float)i0;
        out_ir[(size_t)t * 2 + 1] = (float)i1;
    }
}

// ---------- E transpose+convert: Ebt[d][k] = bf16(E[k][d]) ----------
__global__ __launch_bounds__(256) void e_transpose(
    const float* __restrict__ E, unsigned short* __restrict__ Ebt)
{
    __shared__ float lds[64][68];
    const int tid = threadIdx.x;
    const int k0 = blockIdx.x * 64, d0 = blockIdx.y * 64;
    #pragma unroll
    for (int rep = 0; rep < 4; ++rep) {
        int idx = rep * 256 + tid;
        int r = idx >> 4, c4 = (idx & 15) << 2;
        float4 v = *(const float4*)(E + (size_t)(k0 + r) * DM + d0 + c4);
        lds[r][c4 + 0] = v.x; lds[r][c4 + 1] = v.y;
        lds[r][c4 + 2] = v.z; lds[r][c4 + 3] = v.w;
    }
    __syncthreads();
    #pragma unroll
    for (int rep = 0; rep < 4; ++rep) {
        int idx = rep * 256 + tid;
        int dr = idx >> 4, kc4 = (idx & 15) << 2;
        *(unsigned long long*)&Ebt[(size_t)(d0 + dr) * KTOT + k0 + kc4] =
            pack4(f2bf(lds[kc4 + 0][dr]), f2bf(lds[kc4 + 1][dr]),
                  f2bf(lds[kc4 + 2][dr]), f2bf(lds[kc4 + 3][dr]));
    }
}

// ---------- G (fp64, LDS-tiled): G64t[n][k] = sum_d E[k,d]*Wd[n,d] ---------
// Block = 4 k-rows (1/wave) x 64 n -> 1024 blocks, 4 blocks/CU for latency
// hiding. Per-(n,k) d-order identical to previous version -> bit-identical.
__global__ __launch_bounds__(256) void g_fp64(
    const float* __restrict__ E, const float* __restrict__ Wd,
    double* __restrict__ G64t,
    unsigned short* __restrict__ Gth, unsigned short* __restrict__ Gtl)
{
    __shared__ float wt[64 * 65];
    const int tid = threadIdx.x;
    const int w = tid >> 6, n = tid & 63;
    const int k = blockIdx.x * 4 + w;

    double acc = 0.0;
    const float* erow = E + (size_t)k * DM;

    for (int d0 = 0; d0 < DM; d0 += 64) {
        __syncthreads();
        #pragma unroll
        for (int rep = 0; rep < 4; ++rep) {
            int f = rep * 256 + tid;
            int nn = f >> 4, dg = (f & 15) << 2;
            float4 v = *(const float4*)(Wd + (size_t)nn * DM + d0 + dg);
            wt[(dg + 0) * 65 + nn] = v.x;
            wt[(dg + 1) * 65 + nn] = v.y;
            wt[(dg + 2) * 65 + nn] = v.z;
            wt[(dg + 3) * 65 + nn] = v.w;
        }
        __syncthreads();
        #pragma unroll
        for (int dg = 0; dg < 16; ++dg) {
            float4 e0 = *(const float4*)(erow + d0 + dg * 4);
            #pragma unroll
            for (int j = 0; j < 4; ++j) {
                double wv = (double)wt[(dg * 4 + j) * 65 + n];
                acc = fma((double)(&e0.x)[j], wv, acc);
            }
        }
    }

    G64t[(size_t)n * KTOT + k] = acc;
    float gf = (float)acc;
    unsigned short h, lo;
    split2(gf, h, lo);
    const int e = k >> 8, r = k & 255;
    Gth[((size_t)(e * NREF + n)) * RNK + r] = h;
    Gtl[((size_t)(e * NREF + n)) * RNK + r] = lo;
}

// ---------- S approx: S[t][n] = sum_e w[t,e]*(x'[t,:].G_e[:,n]) ----------
__global__ __launch_bounds__(256) void s_mfma(
    const unsigned short* __restrict__ Xh, const unsigned short* __restrict__ Xl,
    const unsigned short* __restrict__ Gth, const unsigned short* __restrict__ Gtl,
    const float* __restrict__ wts, float* __restrict__ S)
{
    __shared__ float red[4][16][64];
    const int tid = threadIdx.x, l = tid & 63, w = tid >> 6;
    const int t0 = blockIdx.x * 16;

    short8 ah[8], al[8];
    {
        const size_t abase = (size_t)(t0 + (l & 15)) * RNK + (l >> 4) * 8;
        #pragma unroll
        for (int ks = 0; ks < 8; ++ks) {
            ah[ks] = *(const short8*)&Xh[abase + ks * 32];
            al[ks] = *(const short8*)&Xl[abase + ks * 32];
        }
    }

    f32x4 Sacc[4] = {};
    #pragma unroll
    for (int ei = 0; ei < 4; ++ei) {
        const int e = w * 4 + ei;
        f32x4 acc[4] = {};
        #pragma unroll
        for (int ks = 0; ks < 8; ++ks) {
            #pragma unroll
            for (int nn = 0; nn < 4; ++nn) {
                size_t gbase = ((size_t)(e * NREF + nn * 16 + (l & 15))) * RNK
                             + ks * 32 + (l >> 4) * 8;
                short8 bh = *(const short8*)&Gth[gbase];
                short8 bl = *(const short8*)&Gtl[gbase];
                acc[nn] = __builtin_amdgcn_mfma_f32_16x16x32_bf16(al[ks], bh, acc[nn], 0, 0, 0);
                acc[nn] = __builtin_amdgcn_mfma_f32_16x16x32_bf16(ah[ks], bl, acc[nn], 0, 0, 0);
                acc[nn] = __builtin_amdgcn_mfma_f32_16x16x32_bf16(ah[ks], bh, acc[nn], 0, 0, 0);
            }
        }
        #pragma unroll
        for (int j = 0; j < 4; ++j) {
            float wv = wts[(size_t)(t0 + (l >> 4) * 4 + j) * NEXP + e];
            #pragma unroll
            for (int nn = 0; nn < 4; ++nn) Sacc[nn][j] += wv * acc[nn][j];
        }
    }
    #pragma unroll
    for (int nn = 0; nn < 4; ++nn)
        #pragma unroll
        for (int j = 0; j < 4; ++j)
            red[w][(l >> 4) * 4 + j][nn * 16 + (l & 15)] = Sacc[nn][j];
    __syncthreads();
    for (int i = tid; i < 16 * 64; i += 256) {
        int tt = i >> 6, nn = i & 63;
        float sv = red[0][tt][nn] + red[1][tt][nn] + red[2][tt][nn] + red[3][tt][nn];
        S[(size_t)(t0 + tt) * NREF + nn] = sv;
    }
}

// ---------- refine: approx top-4 -> exact fp64 scores -> top-2 ----------
__global__ __launch_bounds__(256) void refine_top2(
    const float* __restrict__ S, const double* __restrict__ G64t,
    const float* __restrict__ xf, const float* __restrict__ wts,
    float* __restrict__ out_id)
{
    __shared__ float xs[4][RNK];
    __shared__ float wsh[4][NEXP];
    const int tid = threadIdx.x, w = tid >> 6, lane = tid & 63;
    const int t = blockIdx.x * 4 + w;

    *(float4*)&xs[w][lane * 4] = *(const float4*)(xf + (size_t)t * RNK + lane * 4);
    if (lane < NEXP) wsh[w][lane] = wts[(size_t)t * NEXP + lane];
    __syncthreads();

    float cur = S[(size_t)t * NREF + lane];
    int cand[4];
    #pragma unroll
    for (int c = 0; c < 4; ++c) {
        float bv = cur; int bi = lane;
        #pragma unroll
        for (int m = 1; m < 64; m <<= 1) {
            float ov = __shfl_xor(bv, m, 64);
            int   oi = __shfl_xor(bi, m, 64);
            if (ov > bv || (ov == bv && oi < bi)) { bv = ov; bi = oi; }
        }
        cand[c] = bi;
        if (lane == bi) cur = -INFINITY;
    }

    double rs[4];
    #pragma unroll
    for (int c = 0; c < 4; ++c) {
        const double* grow = G64t + (size_t)cand[c] * KTOT;
        double acc = 0.0;
        #pragma unroll 4
        for (int i = 0; i < 64; ++i) {
            int k = i * 64 + lane;
            double a = (double)wsh[w][k >> 8] * (double)xs[w][k & 255];
            acc = fma(a, grow[k], acc);
        }
        #pragma unroll
        for (int m = 1; m < 64; m <<= 1) acc += __shfl_xor(acc, m, 64);
        rs[c] = acc;
    }

    int b0 = 0;
    #pragma unroll
    for (int c = 1; c < 4; ++c)
        if (rs[c] > rs[b0] || (rs[c] == rs[b0] && cand[c] < cand[b0])) b0 = c;
    int b1 = (b0 == 0) ? 1 : 0;
    #pragma unroll
    for (int c = 0; c < 4; ++c) {
        if (c == b0) continue;
        if (rs[c] > rs[b1] || (rs[c] == rs[b1] && cand[c] < cand[b1])) b1 = c;
    }
    if (lane == 0) {
        out_id[(size_t)t * 2 + 0] = (float)cand[b0];
        out_id[(size_t)t * 2 + 1] = (float)cand[b1];
    }
}

// ---------- K2 fused: y[t,d] = sum_e w[t,e] * (Xh[t,:] @ E_e[:,d]) ---------
__global__ __launch_bounds__(256) void k2_fused(
    const unsigned short* __restrict__ Xh,
    const unsigned short* __restrict__ Ebt,
    const float* __restrict__ wts,
    float* __restrict__ y)
{
    __shared__ unsigned short As[128 * 32];
    __shared__ unsigned short Bs[128 * 32];
    __shared__ float wt[NEXP * 132];
    const int tid = threadIdx.x;
    const int l = tid & 63, w = tid >> 6;
    const int wr = w >> 1, wc = w & 1;
    const int tm0 = blockIdx.y * 128, n0 = blockIdx.x * 128;
    const int lrow = l >> 2, s = l & 3, g = l >> 4;

    #pragma unroll
    for (int rep = 0; rep < 8; ++rep) {
        int f = rep * 256 + tid;
        int row = f >> 4, e = f & 15;
        wt[e * 132 + row] = wts[(size_t)(tm0 + row) * NEXP + e];
    }

    f32x4 acc[4][4] = {};

    for (int e = 0; e < NEXP; ++e) {
        f32x4 acc_e[4][4] = {};
        for (int kb8 = 0; kb8 < 8; ++kb8) {
            const int kb = e * 8 + kb8;
            __syncthreads();
            #pragma unroll
            for (int i = 0; i < 2; ++i) {
                int row = w * 32 + i * 16 + lrow;
                int sw = ((s ^ ((row >> 1) & 3)) << 4);
                const char* ga = (const char*)Xh
                    + ((size_t)(tm0 + row) * RNK + kb8 * 32) * 2 + sw;
                __builtin_amdgcn_global_load_lds((gptr_t)ga,
                    (lptr_t)&As[(w * 32 + i * 16) * 32], 16, 0, 0);
                const char* gb = (const char*)Ebt
                    + ((size_t)(n0 + row) * KTOT + kb * 32) * 2 + sw;
                __builtin_amdgcn_global_load_lds((gptr_t)gb,
                    (lptr_t)&Bs[(w * 32 + i * 16) * 32], 16, 0, 0);
            }
            __syncthreads();

            short8 af[4], bv[4];
            #pragma unroll
            for (int m = 0; m < 4; ++m) {
                int row = wr * 64 + m * 16 + (l & 15);
                af[m] = *(const short8*)&As[row * 32 + ((g ^ ((row >> 1) & 3)) << 3)];
            }
            #pragma unroll
            for (int nn = 0; nn < 4; ++nn) {
                int row = wc * 64 + nn * 16 + (l & 15);
                bv[nn] = *(const short8*)&Bs[row * 32 + ((g ^ ((row >> 1) & 3)) << 3)];
            }
            #pragma unroll
            for (int m = 0; m < 4; ++m)
                #pragma unroll
                for (int nn = 0; nn < 4; ++nn)
                    acc_e[m][nn] = __builtin_amdgcn_mfma_f32_16x16x32_bf16(
                        af[m], bv[nn], acc_e[m][nn], 0, 0, 0);
        }
        #pragma unroll
        for (int m = 0; m < 4; ++m) {
            int rowb = wr * 64 + m * 16 + (l >> 4) * 4;
            float4 wm = *(const float4*)&wt[e * 132 + rowb];
            #pragma unroll
            for (int nn = 0; nn < 4; ++nn) {
                #pragma unroll
                for (int j = 0; j < 4; ++j)
                    acc[m][nn][j] += (&wm.x)[j] * acc_e[m][nn][j];
            }
        }
    }

    #pragma unroll
    for (int m = 0; m < 4; ++m) {
        int rbase = tm0 + wr * 64 + m * 16 + (l >> 4) * 4;
        #pragma unroll
        for (int nn = 0; nn < 4; ++nn) {
            int c = n0 + wc * 64 + nn * 16 + (l & 15);
            #pragma unroll
            for (int j = 0; j < 4; ++j)
                y[(size_t)(rbase + j) * DM + c] = acc[m][nn][j];
        }
    }
}

// ---------- K2 fp32 fallback ----------
__global__ __launch_bounds__(256) void k2_gemm(
    const float* __restrict__ xp, const float* __restrict__ wts,
    const float* __restrict__ E, float* __restrict__ y)
{
    __shared__ float As[16][132];
    __shared__ float Bs[16][132];
    const int tid = threadIdx.x;
    const int bn = blockIdx.x, bm = blockIdx.y;
    const int tm0 = bm * 128, tn0 = bn * 128;
    const int ty = tid >> 4, tx = tid & 15;
    float acc[8][8] = {};
    for (int kb = 0; kb < KTOT / 16; ++kb) {
        const int e = kb >> 4;
        const int rbase = (kb & 15) << 4;
        const int kglob = kb << 4;
        __syncthreads();
        #pragma unroll
        for (int h = 0; h < 2; ++h) {
            int f = tid + h * 256;
            int m = f >> 2, k4 = (f & 3) << 2;
            int t = tm0 + m;
            float4 a = *(const float4*)(xp + (size_t)t * RNK + rbase + k4);
            float wv = wts[(size_t)t * NEXP + e];
            As[k4 + 0][m] = a.x * wv; As[k4 + 1][m] = a.y * wv;
            As[k4 + 2][m] = a.z * wv; As[k4 + 3][m] = a.w * wv;
        }
        #pragma unroll
        for (int h = 0; h < 2; ++h) {
            int f = tid + h * 256;
            int kk = f >> 5, d4 = (f & 31) << 2;
            float4 b = *(const float4*)(E + (size_t)(kglob + kk) * DM + tn0 + d4);
            *(float4*)(&Bs[kk][d4]) = b;
        }
        __syncthreads();
        #pragma unroll
        for (int kk = 0; kk < 16; ++kk) {
            float4 a0 = *(const float4*)(&As[kk][ty * 8]);
            float4 a1 = *(const float4*)(&As[kk][ty * 8 + 4]);
            float4 b0 = *(const float4*)(&Bs[kk][tx * 8]);
            float4 b1 = *(const float4*)(&Bs[kk][tx * 8 + 4]);
            float av[8] = {a0.x, a0.y, a0.z, a0.w, a1.x, a1.y, a1.z, a1.w};
            float bw[8] = {b0.x, b0.y, b0.z, b0.w, b1.x, b1.y, b1.z, b1.w};
            #pragma unroll
            for (int i = 0; i < 8; ++i)
                #pragma unroll
                for (int j = 0; j < 8; ++j)
                    acc[i][j] = fmaf(av[i], bw[j], acc[i][j]);
        }
    }
    #pragma unroll
    for (int i = 0; i < 8; ++i) {
        int t = tm0 + ty * 8 + i;
        float* yrow = y + (size_t)t * DM + tn0 + tx * 8;
        *(float4*)yrow       = make_float4(acc[i][0], acc[i][1], acc[i][2], acc[i][3]);
        *(float4*)(yrow + 4) = make_float4(acc[i][4], acc[i][5], acc[i][6], acc[i][7]);
    }
}

// ---------- K3: read refined indices -> 2 reflections on y (in place) -----
__global__ __launch_bounds__(256) void k3_post(
    const float* __restrict__ out_id, const float* __restrict__ reflect_d,
    float* __restrict__ y)
{
    const int tid = threadIdx.x;
    const int w = tid >> 6, lane = tid & 63;
    const int t = blockIdx.x * 4 + w;

    float4 yv[4];
    #pragma unroll
    for (int c = 0; c < 4; ++c)
        yv[c] = *(const float4*)(y + (size_t)t * DM + lane * 16 + c * 4);

    const int i0 = (int)out_id[(size_t)t * 2 + 0];
    const int i1 = (int)out_id[(size_t)t * 2 + 1];

    #pragma unroll
    for (int rr = 0; rr < 2; ++rr) {
        int idx = rr ? i1 : i0;
        const float* vrow = reflect_d + (size_t)idx * DM + lane * 16;
        float sv = 0.f, vn = 0.f;
        float4 vv[4];
        #pragma unroll
        for (int c = 0; c < 4; ++c) {
            vv[c] = *(const float4*)(vrow + c * 4);
            sv += vv[c].x * yv[c].x + vv[c].y * yv[c].y
                + vv[c].z * yv[c].z + vv[c].w * yv[c].w;
            vn += vv[c].x * vv[c].x + vv[c].y * vv[c].y
                + vv[c].z * vv[c].z + vv[c].w * vv[c].w;
        }
        #pragma unroll
        for (int m = 1; m < 64; m <<= 1) {
            sv += __shfl_xor(sv, m, 64);
            vn += __shfl_xor(vn, m, 64);
        }
        float coef = 2.0f * sv / (vn + 1e-8f);
        #pragma unroll
        for (int c = 0; c < 4; ++c) {
            yv[c].x -= coef * vv[c].x; yv[c].y -= coef * vv[c].y;
            yv[c].z -= coef * vv[c].z; yv[c].w -= coef * vv[c].w;
        }
    }
    #pragma unroll
    for (int c = 0; c < 4; ++c)
        *(float4*)(y + (size_t)t * DM + lane * 16 + c * 4) = yv[c];
}

// ---------- K3 fallback (scores_d from fp32 y, top2, reflect) ----------
__global__ __launch_bounds__(256) void k3_full(
    const float* __restrict__ Wd, const float* __restrict__ reflect_d,
    float* __restrict__ y, float* __restrict__ out_id)
{
    __shared__ float ys[4][DM];
    __shared__ float wds[64][17];
    const int tid = threadIdx.x;
    const int w = tid >> 6, lane = tid & 63;
    const int t = blockIdx.x * 4 + w;

    float4 yv[4];
    #pragma unroll
    for (int c = 0; c < 4; ++c) {
        yv[c] = *(const float4*)(y + (size_t)t * DM + lane * 16 + c * 4);
        *(float4*)(&ys[w][lane * 16 + c * 4]) = yv[c];
    }
    double s = 0.0;
    for (int kb = 0; kb < DM / 16; ++kb) {
        __syncthreads();
        {
            int row = tid >> 2, c4 = (tid & 3) << 2;
            float4 wv = *(const float4*)(Wd + (size_t)row * DM + kb * 16 + c4);
            wds[row][c4 + 0] = wv.x; wds[row][c4 + 1] = wv.y;
            wds[row][c4 + 2] = wv.z; wds[row][c4 + 3] = wv.w;
        }
        __syncthreads();
        #pragma unroll
        for (int i = 0; i < 16; ++i)
            s += (double)ys[w][kb * 16 + i] * (double)wds[lane][i];
    }
    int i0, i1;
    top2_64(s, lane, i0, i1);
    #pragma unroll
    for (int rr = 0; rr < 2; ++rr) {
        int idx = rr ? i1 : i0;
        const float* vrow = reflect_d + (size_t)idx * DM + lane * 16;
        float sv = 0.f, vn = 0.f;
        float4 vv[4];
        #pragma unroll
        for (int c = 0; c < 4; ++c) {
            vv[c] = *(const float4*)(vrow + c * 4);
            sv += vv[c].x * yv[c].x + vv[c].y * yv[c].y
                + vv[c].z * yv[c].z + vv[c].w * yv[c].w;
            vn += vv[c].x * vv[c].x + vv[c].y * vv[c].y
                + vv[c].z * vv[c].z + vv[c].w * vv[c].w;
        }
        #pragma unroll
        for (int m = 1; m < 64; m <<= 1) {
            sv += __shfl_xor(sv, m, 64);
            vn += __shfl_xor(vn, m, 64);
        }
        float coef = 2.0f * sv / (vn + 1e-8f);
        #pragma unroll
        for (int c = 0; c < 4; ++c) {
            yv[c].x -= coef * vv[c].x; yv[c].y -= coef * vv[c].y;
            yv[c].z -= coef * vv[c].z; yv[c].w -= coef * vv[c].w;
        }
    }
    #pragma unroll
    for (int c = 0; c < 4; ++c)
        *(float4*)(y + (size_t)t * DM + lane * 16 + c * 4) = yv[c];
    if (lane == 0) {
        out_id[(size_t)t * 2 + 0] = (float)i0;
        out_id[(size_t)t * 2 + 1] = (float)i1;
    }
}

extern "C" void kernel_launch(void* const* d_in, const int* in_sizes, int n_in,
                              void* d_out, int out_size, void* d_ws, size_t ws_size,
                              hipStream_t stream) {
    const float* x  = (const float*)d_in[0];
    const float* Wr = (const float*)d_in[1];
    const float* We = (const float*)d_in[2];
    const float* Wd = (const float*)d_in[3];
    const float* E  = (const float*)d_in[4];
    const float* rr = (const float*)d_in[5];
    const float* rd = (const float*)d_in[6];

    float* out    = (float*)d_out;
    float* y      = out + Y_OFF;
    float* out_ir = out + IR_OFF;
    float* out_w  = out + W_OFF;
    float* out_id = out + ID_OFF;

    if (ws_size >= WS_FULL) {
        char* p = (char*)d_ws;
        unsigned short* Ebt = (unsigned short*)p;  p += EBT_BYTES;
        float*          Xf  = (float*)p;           p += XF_BYTES;
        unsigned short* Xh  = (unsigned short*)p;  p += XH_BYTES;
        unsigned short* Xl  = (unsigned short*)p;  p += XH_BYTES;
        unsigned short* Gth = (unsigned short*)p;  p += GT_BYTES;
        unsigned short* Gtl = (unsigned short*)p;  p += GT_BYTES;
        float*          Sb  = (float*)p;           p += S_BYTES;
        double*         G64 = (double*)p;          p += G64_BYTES;
        double*         Srb = (double*)p;

        sr_fp64<<<TOK / 8, 256, 0, stream>>>(x, Wr, Srb);
        e_transpose<<<dim3(KTOT / 64, DM / 64), 256, 0, stream>>>(E, Ebt);
        g_fp64<<<KTOT / 4, 256, 0, stream>>>(E, Wd, G64, Gth, Gtl);
        k1_fast<<<TOK / 16, 256, 0, stream>>>(Srb, x, We, rr, Xf,
                                              Xh, Xl, out_ir, out_w);
        k2_fused<<<dim3(DM / 128, TOK / 128), 256, 0, stream>>>(Xh, Ebt, out_w, y);
        s_mfma<<<TOK / 16, 256, 0, stream>>>(Xh, Xl, Gth, Gtl, out_w, Sb);
        refine_top2<<<TOK / 4, 256, 0, stream>>>(Sb, G64, Xf, out_w, out_id);
        k3_post<<<TOK / 4, 256, 0, stream>>>(out_id, rd, y);
    } else {
        float* xprime = (float*)d_ws;
        k1_tokens<<<TOK / 4, 256, 0, stream>>>(x, Wr, We, rr, xprime,
                                               out_ir, out_w);
        k2_gemm<<<dim3(DM / 128, TOK / 128), 256, 0, stream>>>(xprime, out_w, E, y);
        k3_full<<<TOK / 4, 256, 0, stream>>>(Wd, rd, y, out_id);
    }
}

// Round 9
// 324.634 us; speedup vs baseline: 3.3275x; 1.0264x over previous
//
#include <hip/hip_runtime.h>
#include <cmath>

#define TOK   8192
#define RNK   256
#define NEXP  16
#define NREF  64
#define DM    1024
#define KTOT  4096

#define Y_OFF  0
#define IR_OFF (TOK*DM)
#define W_OFF  (IR_OFF + TOK*2)
#define ID_OFF (W_OFF + TOK*NEXP)

#define EBT_BYTES ((size_t)DM * KTOT * 2)         // 8 MB
#define XF_BYTES  ((size_t)TOK * RNK * 4)         // 8 MB
#define XH_BYTES  ((size_t)TOK * RNK * 2)         // 4 MB
#define GT_BYTES  ((size_t)NEXP * NREF * RNK * 2) // 512 KB
#define S_BYTES   ((size_t)TOK * NREF * 4)        // 2 MB
#define G64_BYTES ((size_t)NREF * KTOT * 8)       // 2 MB
#define SR_BYTES  ((size_t)TOK * NREF * 8)        // 4 MB
#define WS_FULL   (EBT_BYTES + XF_BYTES + 2*XH_BYTES + 2*GT_BYTES + S_BYTES + G64_BYTES + SR_BYTES)

typedef __attribute__((ext_vector_type(8))) short short8;
typedef __attribute__((ext_vector_type(4))) float f32x4;
typedef const __attribute__((address_space(1))) void* gptr_t;
typedef __attribute__((address_space(3))) void* lptr_t;

__device__ inline unsigned short f2bf(float f) {    // RNE float->bf16
    unsigned int u = __float_as_uint(f);
    return (unsigned short)((u + 0x7fffu + ((u >> 16) & 1u)) >> 16);
}
__device__ inline float bf2f(unsigned short h) {
    return __uint_as_float(((unsigned int)h) << 16);
}
__device__ inline void split2(float v, unsigned short& h, unsigned short& l) {
    h = f2bf(v);
    l = f2bf(v - bf2f(h));
}
__device__ inline unsigned long long pack4(unsigned short a, unsigned short b,
                                           unsigned short c, unsigned short d) {
    return (unsigned long long)a | ((unsigned long long)b << 16)
         | ((unsigned long long)c << 32) | ((unsigned long long)d << 48);
}

// ---------- top-2 across a 64-lane wave, lax.top_k tie semantics ----------
__device__ inline void top2_64(double v, int idx, int& i0, int& i1) {
    double bv = v; int bi = idx;
    #pragma unroll
    for (int m = 1; m < 64; m <<= 1) {
        double ov = __shfl_xor(bv, m, 64);
        int    oi = __shfl_xor(bi, m, 64);
        if (ov > bv || (ov == bv && oi < bi)) { bv = ov; bi = oi; }
    }
    i0 = bi;
    double v2 = (idx == i0) ? -INFINITY : v;
    double bv2 = v2; int bi2 = idx;
    #pragma unroll
    for (int m = 1; m < 64; m <<= 1) {
        double ov = __shfl_xor(bv2, m, 64);
        int    oi = __shfl_xor(bi2, m, 64);
        if (ov > bv2 || (ov == bv2 && oi < bi2)) { bv2 = ov; bi2 = oi; }
    }
    i1 = bi2;
}

// ======== PREP: sr_fp64 (0..1023) | e_transpose (1024..2047) | g_fp64 ======
// Three independent producers co-scheduled in one launch. Each branch's FP
// order is identical to the round-8 standalone kernels -> bit-identical out.
__global__ __launch_bounds__(256) void prep(
    const float* __restrict__ x, const float* __restrict__ Wr,
    const float* __restrict__ E, const float* __restrict__ Wd,
    double* __restrict__ Sr, unsigned short* __restrict__ Ebt,
    double* __restrict__ G64t,
    unsigned short* __restrict__ Gth, unsigned short* __restrict__ Gtl)
{
    __shared__ __align__(16) float lds_raw[64 * 68];
    const int bid = blockIdx.x;
    const int tid = threadIdx.x;
    const int w = tid >> 6, n = tid & 63;

    if (bid < 1024) {
        // ---- sr_fp64: 8 tokens/block ----
        float* wt = lds_raw;                 // 64*65
        const int t0 = bid * 8;
        double acc[2] = {0.0, 0.0};
        const float* xr0 = x + (size_t)(t0 + w * 2 + 0) * RNK;
        const float* xr1 = x + (size_t)(t0 + w * 2 + 1) * RNK;
        for (int d0 = 0; d0 < RNK; d0 += 64) {
            __syncthreads();
            #pragma unroll
            for (int rep = 0; rep < 4; ++rep) {
                int f = rep * 256 + tid;
                int nn = f >> 4, dg = (f & 15) << 2;
                float4 v = *(const float4*)(Wr + (size_t)nn * RNK + d0 + dg);
                wt[(dg + 0) * 65 + nn] = v.x;
                wt[(dg + 1) * 65 + nn] = v.y;
                wt[(dg + 2) * 65 + nn] = v.z;
                wt[(dg + 3) * 65 + nn] = v.w;
            }
            __syncthreads();
            #pragma unroll
            for (int dg = 0; dg < 16; ++dg) {
                float4 e0 = *(const float4*)(xr0 + d0 + dg * 4);
                float4 e1 = *(const float4*)(xr1 + d0 + dg * 4);
                #pragma unroll
                for (int j = 0; j < 4; ++j) {
                    double wv = (double)wt[(dg * 4 + j) * 65 + n];
                    acc[0] = fma((double)(&e0.x)[j], wv, acc[0]);
                    acc[1] = fma((double)(&e1.x)[j], wv, acc[1]);
                }
            }
        }
        #pragma unroll
        for (int i = 0; i < 2; ++i)
            Sr[(size_t)(t0 + w * 2 + i) * NREF + n] = acc[i];
    } else if (bid < 2048) {
        // ---- e_transpose: Ebt[d][k] = bf16(E[k][d]) ----
        const int id = bid - 1024;
        const int k0 = (id & 63) * 64, d0 = (id >> 6) * 64;
        #pragma unroll
        for (int rep = 0; rep < 4; ++rep) {
            int idx = rep * 256 + tid;
            int r = idx >> 4, c4 = (idx & 15) << 2;
            float4 v = *(const float4*)(E + (size_t)(k0 + r) * DM + d0 + c4);
            lds_raw[r * 68 + c4 + 0] = v.x; lds_raw[r * 68 + c4 + 1] = v.y;
            lds_raw[r * 68 + c4 + 2] = v.z; lds_raw[r * 68 + c4 + 3] = v.w;
        }
        __syncthreads();
        #pragma unroll
        for (int rep = 0; rep < 4; ++rep) {
            int idx = rep * 256 + tid;
            int dr = idx >> 4, kc4 = (idx & 15) << 2;
            *(unsigned long long*)&Ebt[(size_t)(d0 + dr) * KTOT + k0 + kc4] =
                pack4(f2bf(lds_raw[(kc4 + 0) * 68 + dr]),
                      f2bf(lds_raw[(kc4 + 1) * 68 + dr]),
                      f2bf(lds_raw[(kc4 + 2) * 68 + dr]),
                      f2bf(lds_raw[(kc4 + 3) * 68 + dr]));
        }
    } else {
        // ---- g_fp64: 4 k-rows/block (1 per wave) ----
        float* wt = lds_raw;                 // 64*65
        const int k = (bid - 2048) * 4 + w;
        double acc = 0.0;
        const float* erow = E + (size_t)k * DM;
        for (int d0 = 0; d0 < DM; d0 += 64) {
            __syncthreads();
            #pragma unroll
            for (int rep = 0; rep < 4; ++rep) {
                int f = rep * 256 + tid;
                int nn = f >> 4, dg = (f & 15) << 2;
                float4 v = *(const float4*)(Wd + (size_t)nn * DM + d0 + dg);
                wt[(dg + 0) * 65 + nn] = v.x;
                wt[(dg + 1) * 65 + nn] = v.y;
                wt[(dg + 2) * 65 + nn] = v.z;
                wt[(dg + 3) * 65 + nn] = v.w;
            }
            __syncthreads();
            #pragma unroll
            for (int dg = 0; dg < 16; ++dg) {
                float4 e0 = *(const float4*)(erow + d0 + dg * 4);
                #pragma unroll
                for (int j = 0; j < 4; ++j) {
                    double wv = (double)wt[(dg * 4 + j) * 65 + n];
                    acc = fma((double)(&e0.x)[j], wv, acc);
                }
            }
        }
        G64t[(size_t)n * KTOT + k] = acc;
        float gf = (float)acc;
        unsigned short h, lo;
        split2(gf, h, lo);
        const int e = k >> 8, r = k & 255;
        Gth[((size_t)(e * NREF + n)) * RNK + r] = h;
        Gtl[((size_t)(e * NREF + n)) * RNK + r] = lo;
    }
}

// ---------- K1 fast: top2(Sr) -> reflections -> scores_e(LDS We) ----------
__global__ __launch_bounds__(256) void k1_fast(
    const double* __restrict__ Sr, const float* __restrict__ x,
    const float* __restrict__ We, const float* __restrict__ reflect_r,
    float* __restrict__ xprime,
    unsigned short* __restrict__ Xh, unsigned short* __restrict__ Xl,
    float* __restrict__ out_ir, float* __restrict__ out_w)
{
    __shared__ float we_lds[16 * 260];
    __shared__ float xs[4][260];
    const int tid = threadIdx.x;
    const int w = tid >> 6, lane = tid & 63;

    #pragma unroll
    for (int rep = 0; rep < 4; ++rep) {
        int f = rep * 256 + tid;
        int row = f >> 6, c4 = (f & 63) << 2;
        float4 v = *(const float4*)(We + (size_t)row * RNK + c4);
        *(float4*)&we_lds[row * 260 + c4] = v;
    }
    __syncthreads();

    for (int it = 0; it < 4; ++it) {
        const int t = blockIdx.x * 16 + it * 4 + w;

        float4 xv = *(const float4*)(x + (size_t)t * RNK + lane * 4);
        double s = Sr[(size_t)t * NREF + lane];
        int i0, i1;
        top2_64(s, lane, i0, i1);

        #pragma unroll
        for (int rr = 0; rr < 2; ++rr) {
            int idx = rr ? i1 : i0;
            float4 vv = *(const float4*)(reflect_r + (size_t)idx * RNK + lane * 4);
            float sv = vv.x * xv.x + vv.y * xv.y + vv.z * xv.z + vv.w * xv.w;
            float vn = vv.x * vv.x + vv.y * vv.y + vv.z * vv.z + vv.w * vv.w;
            #pragma unroll
            for (int m = 1; m < 64; m <<= 1) {
                sv += __shfl_xor(sv, m, 64);
                vn += __shfl_xor(vn, m, 64);
            }
            float coef = 2.0f * sv / (vn + 1e-8f);
            xv.x -= coef * vv.x; xv.y -= coef * vv.y;
            xv.z -= coef * vv.z; xv.w -= coef * vv.w;
        }

        *(float4*)&xs[w][lane * 4] = xv;
        *(float4*)(xprime + (size_t)t * RNK + lane * 4) = xv;

        const int n16 = lane & 15;
        double se = 0.0;
        {
            const float* werow = &we_lds[n16 * 260];
            #pragma unroll 8
            for (int r4 = 0; r4 < RNK / 4; ++r4) {
                float4 xr = *(const float4*)(&xs[w][r4 * 4]);
                float4 wf = *(const float4*)(werow + r4 * 4);
                se += (double)xr.x * wf.x + (double)xr.y * wf.y
                    + (double)xr.z * wf.z + (double)xr.w * wf.w;
            }
        }
        float sef = (float)se;
        float mx = sef;
        #pragma unroll
        for (int m = 1; m < 16; m <<= 1) mx = fmaxf(mx, __shfl_xor(mx, m, 64));
        float ex = expf(sef - mx);
        float sm = ex;
        #pragma unroll
        for (int m = 1; m < 16; m <<= 1) sm += __shfl_xor(sm, m, 64);
        float wgt = ex / sm;

        if (lane < NEXP) out_w[(size_t)t * NEXP + lane] = wgt;
        if (lane == 0) {
            out_ir[(size_t)t * 2 + 0] = (float)i0;
            out_ir[(size_t)t * 2 + 1] = (float)i1;
        }

        unsigned short hx, lx, hy, ly, hz, lz, hw, lw;
        split2(xv.x, hx, lx); split2(xv.y, hy, ly);
        split2(xv.z, hz, lz); split2(xv.w, hw, lw);
        *(unsigned long long*)&Xh[(size_t)t * RNK + lane * 4] = pack4(hx, hy, hz, hw);
        *(unsigned long long*)&Xl[(size_t)t * RNK + lane * 4] = pack4(lx, ly, lz, lw);
    }
}

// ======== K2S: k2_fused (blocks 0..511) | s_mfma (blocks 512..1023) ========
__global__ __launch_bounds__(256) void k2s(
    const unsigned short* __restrict__ Xh, const unsigned short* __restrict__ Xl,
    const unsigned short* __restrict__ Ebt,
    const unsigned short* __restrict__ Gth, const unsigned short* __restrict__ Gtl,
    const float* __restrict__ wts, float* __restrict__ y, float* __restrict__ S)
{
    __shared__ __align__(16) char smem[24832];
    const int bid = blockIdx.x;
    const int tid = threadIdx.x;
    const int l = tid & 63, w = tid >> 6;

    if (bid < 512) {
        // ---- k2_fused; column->XCD mapping preserved (n0 = (bid&7)*128) ----
        unsigned short* As = (unsigned short*)smem;            // 8 KB
        unsigned short* Bs = (unsigned short*)(smem + 8192);   // 8 KB
        float* wt = (float*)(smem + 16384);                    // 16*132 floats
        const int wr = w >> 1, wc = w & 1;
        const int tm0 = (bid >> 3) * 128, n0 = (bid & 7) * 128;
        const int lrow = l >> 2, s = l & 3, g = l >> 4;

        #pragma unroll
        for (int rep = 0; rep < 8; ++rep) {
            int f = rep * 256 + tid;
            int row = f >> 4, e = f & 15;
            wt[e * 132 + row] = wts[(size_t)(tm0 + row) * NEXP + e];
        }

        f32x4 acc[4][4] = {};

        for (int e = 0; e < NEXP; ++e) {
            f32x4 acc_e[4][4] = {};
            for (int kb8 = 0; kb8 < 8; ++kb8) {
                const int kb = e * 8 + kb8;
                __syncthreads();
                #pragma unroll
                for (int i = 0; i < 2; ++i) {
                    int row = w * 32 + i * 16 + lrow;
                    int sw = ((s ^ ((row >> 1) & 3)) << 4);
                    const char* ga = (const char*)Xh
                        + ((size_t)(tm0 + row) * RNK + kb8 * 32) * 2 + sw;
                    __builtin_amdgcn_global_load_lds((gptr_t)ga,
                        (lptr_t)&As[(w * 32 + i * 16) * 32], 16, 0, 0);
                    const char* gb = (const char*)Ebt
                        + ((size_t)(n0 + row) * KTOT + kb * 32) * 2 + sw;
                    __builtin_amdgcn_global_load_lds((gptr_t)gb,
                        (lptr_t)&Bs[(w * 32 + i * 16) * 32], 16, 0, 0);
                }
                __syncthreads();

                short8 af[4], bv[4];
                #pragma unroll
                for (int m = 0; m < 4; ++m) {
                    int row = wr * 64 + m * 16 + (l & 15);
                    af[m] = *(const short8*)&As[row * 32 + ((g ^ ((row >> 1) & 3)) << 3)];
                }
                #pragma unroll
                for (int nn = 0; nn < 4; ++nn) {
                    int row = wc * 64 + nn * 16 + (l & 15);
                    bv[nn] = *(const short8*)&Bs[row * 32 + ((g ^ ((row >> 1) & 3)) << 3)];
                }
                #pragma unroll
                for (int m = 0; m < 4; ++m)
                    #pragma unroll
                    for (int nn = 0; nn < 4; ++nn)
                        acc_e[m][nn] = __builtin_amdgcn_mfma_f32_16x16x32_bf16(
                            af[m], bv[nn], acc_e[m][nn], 0, 0, 0);
            }
            #pragma unroll
            for (int m = 0; m < 4; ++m) {
                int rowb = wr * 64 + m * 16 + (l >> 4) * 4;
                float4 wm = *(const float4*)&wt[e * 132 + rowb];
                #pragma unroll
                for (int nn = 0; nn < 4; ++nn) {
                    #pragma unroll
                    for (int j = 0; j < 4; ++j)
                        acc[m][nn][j] += (&wm.x)[j] * acc_e[m][nn][j];
                }
            }
        }

        #pragma unroll
        for (int m = 0; m < 4; ++m) {
            int rbase = tm0 + wr * 64 + m * 16 + (l >> 4) * 4;
            #pragma unroll
            for (int nn = 0; nn < 4; ++nn) {
                int c = n0 + wc * 64 + nn * 16 + (l & 15);
                #pragma unroll
                for (int j = 0; j < 4; ++j)
                    y[(size_t)(rbase + j) * DM + c] = acc[m][nn][j];
            }
        }
    } else {
        // ---- s_mfma: S[t][n] = sum_e w[t,e]*(x'[t,:].G_e[:,n]) ----
        float* red = (float*)smem;    // [4][16][64]
        const int t0 = (bid - 512) * 16;

        short8 ah[8], al[8];
        {
            const size_t abase = (size_t)(t0 + (l & 15)) * RNK + (l >> 4) * 8;
            #pragma unroll
            for (int ks = 0; ks < 8; ++ks) {
                ah[ks] = *(const short8*)&Xh[abase + ks * 32];
                al[ks] = *(const short8*)&Xl[abase + ks * 32];
            }
        }

        f32x4 Sacc[4] = {};
        #pragma unroll
        for (int ei = 0; ei < 4; ++ei) {
            const int e = w * 4 + ei;
            f32x4 acc[4] = {};
            #pragma unroll
            for (int ks = 0; ks < 8; ++ks) {
                #pragma unroll
                for (int nn = 0; nn < 4; ++nn) {
                    size_t gbase = ((size_t)(e * NREF + nn * 16 + (l & 15))) * RNK
                                 + ks * 32 + (l >> 4) * 8;
                    short8 bh = *(const short8*)&Gth[gbase];
                    short8 bl = *(const short8*)&Gtl[gbase];
                    acc[nn] = __builtin_amdgcn_mfma_f32_16x16x32_bf16(al[ks], bh, acc[nn], 0, 0, 0);
                    acc[nn] = __builtin_amdgcn_mfma_f32_16x16x32_bf16(ah[ks], bl, acc[nn], 0, 0, 0);
                    acc[nn] = __builtin_amdgcn_mfma_f32_16x16x32_bf16(ah[ks], bh, acc[nn], 0, 0, 0);
                }
            }
            #pragma unroll
            for (int j = 0; j < 4; ++j) {
                float wv = wts[(size_t)(t0 + (l >> 4) * 4 + j) * NEXP + e];
                #pragma unroll
                for (int nn = 0; nn < 4; ++nn) Sacc[nn][j] += wv * acc[nn][j];
            }
        }
        #pragma unroll
        for (int nn = 0; nn < 4; ++nn)
            #pragma unroll
            for (int j = 0; j < 4; ++j)
                red[(w * 16 + (l >> 4) * 4 + j) * 64 + nn * 16 + (l & 15)] = Sacc[nn][j];
        __syncthreads();
        for (int i = tid; i < 16 * 64; i += 256) {
            int tt = i >> 6, nn = i & 63;
            float sv = red[(0 * 16 + tt) * 64 + nn] + red[(1 * 16 + tt) * 64 + nn]
                     + red[(2 * 16 + tt) * 64 + nn] + red[(3 * 16 + tt) * 64 + nn];
            S[(size_t)(t0 + tt) * NREF + nn] = sv;
        }
    }
}

// ======== REFINE+K3: approx top4 -> fp64 rescore -> top2 -> reflect y ======
__global__ __launch_bounds__(256) void refine_k3(
    const float* __restrict__ S, const double* __restrict__ G64t,
    const float* __restrict__ xf, const float* __restrict__ wts,
    const float* __restrict__ reflect_d,
    float* __restrict__ y, float* __restrict__ out_id)
{
    __shared__ float xs[4][RNK];
    __shared__ float wsh[4][NEXP];
    const int tid = threadIdx.x, w = tid >> 6, lane = tid & 63;
    const int t = blockIdx.x * 4 + w;

    *(float4*)&xs[w][lane * 4] = *(const float4*)(xf + (size_t)t * RNK + lane * 4);
    if (lane < NEXP) wsh[w][lane] = wts[(size_t)t * NEXP + lane];
    __syncthreads();

    float cur = S[(size_t)t * NREF + lane];
    int cand[4];
    #pragma unroll
    for (int c = 0; c < 4; ++c) {
        float bv = cur; int bi = lane;
        #pragma unroll
        for (int m = 1; m < 64; m <<= 1) {
            float ov = __shfl_xor(bv, m, 64);
            int   oi = __shfl_xor(bi, m, 64);
            if (ov > bv || (ov == bv && oi < bi)) { bv = ov; bi = oi; }
        }
        cand[c] = bi;
        if (lane == bi) cur = -INFINITY;
    }

    double rs[4];
    #pragma unroll
    for (int c = 0; c < 4; ++c) {
        const double* grow = G64t + (size_t)cand[c] * KTOT;
        double acc = 0.0;
        #pragma unroll 4
        for (int i = 0; i < 64; ++i) {
            int k = i * 64 + lane;
            double a = (double)wsh[w][k >> 8] * (double)xs[w][k & 255];
            acc = fma(a, grow[k], acc);
        }
        #pragma unroll
        for (int m = 1; m < 64; m <<= 1) acc += __shfl_xor(acc, m, 64);
        rs[c] = acc;
    }

    int b0 = 0;
    #pragma unroll
    for (int c = 1; c < 4; ++c)
        if (rs[c] > rs[b0] || (rs[c] == rs[b0] && cand[c] < cand[b0])) b0 = c;
    int b1 = (b0 == 0) ? 1 : 0;
    #pragma unroll
    for (int c = 0; c < 4; ++c) {
        if (c == b0) continue;
        if (rs[c] > rs[b1] || (rs[c] == rs[b1] && cand[c] < cand[b1])) b1 = c;
    }
    const int i0 = cand[b0], i1 = cand[b1];   // wave-uniform
    if (lane == 0) {
        out_id[(size_t)t * 2 + 0] = (float)i0;
        out_id[(size_t)t * 2 + 1] = (float)i1;
    }

    // ---- k3: apply the two reflections to y in place ----
    float4 yv[4];
    #pragma unroll
    for (int c = 0; c < 4; ++c)
        yv[c] = *(const float4*)(y + (size_t)t * DM + lane * 16 + c * 4);

    #pragma unroll
    for (int rr = 0; rr < 2; ++rr) {
        int idx = rr ? i1 : i0;
        const float* vrow = reflect_d + (size_t)idx * DM + lane * 16;
        float sv = 0.f, vn = 0.f;
        float4 vv[4];
        #pragma unroll
        for (int c = 0; c < 4; ++c) {
            vv[c] = *(const float4*)(vrow + c * 4);
            sv += vv[c].x * yv[c].x + vv[c].y * yv[c].y
                + vv[c].z * yv[c].z + vv[c].w * yv[c].w;
            vn += vv[c].x * vv[c].x + vv[c].y * vv[c].y
                + vv[c].z * vv[c].z + vv[c].w * vv[c].w;
        }
        #pragma unroll
        for (int m = 1; m < 64; m <<= 1) {
            sv += __shfl_xor(sv, m, 64);
            vn += __shfl_xor(vn, m, 64);
        }
        float coef = 2.0f * sv / (vn + 1e-8f);
        #pragma unroll
        for (int c = 0; c < 4; ++c) {
            yv[c].x -= coef * vv[c].x; yv[c].y -= coef * vv[c].y;
            yv[c].z -= coef * vv[c].z; yv[c].w -= coef * vv[c].w;
        }
    }
    #pragma unroll
    for (int c = 0; c < 4; ++c)
        *(float4*)(y + (size_t)t * DM + lane * 16 + c * 4) = yv[c];
}

// ================= fallback path (ws too small), unchanged =================
__global__ __launch_bounds__(256) void k1_tokens(
    const float* __restrict__ x, const float* __restrict__ Wr,
    const float* __restrict__ We, const float* __restrict__ reflect_r,
    float* __restrict__ xprime, float* __restrict__ out_ir,
    float* __restrict__ out_w)
{
    __shared__ float xs[4][RNK];
    const int tid = threadIdx.x;
    const int w = tid >> 6, lane = tid & 63;
    const int t = blockIdx.x * 4 + w;

    float4 xv = *(const float4*)(x + (size_t)t * RNK + lane * 4);
    *(float4*)(&xs[w][lane * 4]) = xv;
    __syncthreads();

    double s = 0.0;
    {
        const float* wrow = Wr + (size_t)lane * RNK;
        for (int r4 = 0; r4 < RNK / 4; ++r4) {
            float4 xr = *(const float4*)(&xs[w][r4 * 4]);
            float4 wr = *(const float4*)(wrow + r4 * 4);
            s += (double)xr.x * wr.x + (double)xr.y * wr.y
               + (double)xr.z * wr.z + (double)xr.w * wr.w;
        }
    }
    int i0, i1;
    top2_64(s, lane, i0, i1);

    #pragma unroll
    for (int rr = 0; rr < 2; ++rr) {
        int idx = rr ? i1 : i0;
        float4 vv = *(const float4*)(reflect_r + (size_t)idx * RNK + lane * 4);
        float sv = vv.x * xv.x + vv.y * xv.y + vv.z * xv.z + vv.w * xv.w;
        float vn = vv.x * vv.x + vv.y * vv.y + vv.z * vv.z + vv.w * vv.w;
        #pragma unroll
        for (int m = 1; m < 64; m <<= 1) {
            sv += __shfl_xor(sv, m, 64);
            vn += __shfl_xor(vn, m, 64);
        }
        float coef = 2.0f * sv / (vn + 1e-8f);
        xv.x -= coef * vv.x; xv.y -= coef * vv.y;
        xv.z -= coef * vv.z; xv.w -= coef * vv.w;
    }
    __syncthreads();
    *(float4*)(&xs[w][lane * 4]) = xv;
    __syncthreads();

    *(float4*)(xprime + (size_t)t * RNK + lane * 4) = xv;

    const int n = lane & 15;
    double se = 0.0;
    {
        const float* werow = We + (size_t)n * RNK;
        for (int r4 = 0; r4 < RNK / 4; ++r4) {
            float4 xr = *(const float4*)(&xs[w][r4 * 4]);
            float4 wf = *(const float4*)(werow + r4 * 4);
            se += (double)xr.x * wf.x + (double)xr.y * wf.y
                + (double)xr.z * wf.z + (double)xr.w * wf.w;
        }
    }
    float sef = (float)se;
    float mx = sef;
    #pragma unroll
    for (int m = 1; m < 16; m <<= 1) mx = fmaxf(mx, __shfl_xor(mx, m, 64));
    float ex = expf(sef - mx);
    float sm = ex;
    #pragma unroll
    for (int m = 1; m < 16; m <<= 1) sm += __shfl_xor(sm, m, 64);
    float wgt = ex / sm;

    if (lane < NEXP) out_w[(size_t)t * NEXP + lane] = wgt;
    if (lane == 0) {
        out_ir[(size_t)t * 2 + 0] = (float)i0;
        out_ir[(size_t)t * 2 + 1] = (float)i1;
    }
}

__global__ __launch_bounds__(256) void k2_gemm(
    const float* __restrict__ xp, const float* __restrict__ wts,
    const float* __restrict__ E, float* __restrict__ y)
{
    __shared__ float As[16][132];
    __shared__ float Bs[16][132];
    const int tid = threadIdx.x;
    const int bn = blockIdx.x, bm = blockIdx.y;
    const int tm0 = bm * 128, tn0 = bn * 128;
    const int ty = tid >> 4, tx = tid & 15;
    float acc[8][8] = {};
    for (int kb = 0; kb < KTOT / 16; ++kb) {
        const int e = kb >> 4;
        const int rbase = (kb & 15) << 4;
        const int kglob = kb << 4;
        __syncthreads();
        #pragma unroll
        for (int h = 0; h < 2; ++h) {
            int f = tid + h * 256;
            int m = f >> 2, k4 = (f & 3) << 2;
            int t = tm0 + m;
            float4 a = *(const float4*)(xp + (size_t)t * RNK + rbase + k4);
            float wv = wts[(size_t)t * NEXP + e];
            As[k4 + 0][m] = a.x * wv; As[k4 + 1][m] = a.y * wv;
            As[k4 + 2][m] = a.z * wv; As[k4 + 3][m] = a.w * wv;
        }
        #pragma unroll
        for (int h = 0; h < 2; ++h) {
            int f = tid + h * 256;
            int kk = f >> 5, d4 = (f & 31) << 2;
            float4 b = *(const float4*)(E + (size_t)(kglob + kk) * DM + tn0 + d4);
            *(float4*)(&Bs[kk][d4]) = b;
        }
        __syncthreads();
        #pragma unroll
        for (int kk = 0; kk < 16; ++kk) {
            float4 a0 = *(const float4*)(&As[kk][ty * 8]);
            float4 a1 = *(const float4*)(&As[kk][ty * 8 + 4]);
            float4 b0 = *(const float4*)(&Bs[kk][tx * 8]);
            float4 b1 = *(const float4*)(&Bs[kk][tx * 8 + 4]);
            float av[8] = {a0.x, a0.y, a0.z, a0.w, a1.x, a1.y, a1.z, a1.w};
            float bw[8] = {b0.x, b0.y, b0.z, b0.w, b1.x, b1.y, b1.z, b1.w};
            #pragma unroll
            for (int i = 0; i < 8; ++i)
                #pragma unroll
                for (int j = 0; j < 8; ++j)
                    acc[i][j] = fmaf(av[i], bw[j], acc[i][j]);
        }
    }
    #pragma unroll
    for (int i = 0; i < 8; ++i) {
        int t = tm0 + ty * 8 + i;
        float* yrow = y + (size_t)t * DM + tn0 + tx * 8;
        *(float4*)yrow       = make_float4(acc[i][0], acc[i][1], acc[i][2], acc[i][3]);
        *(float4*)(yrow + 4) = make_float4(acc[i][4], acc[i][5], acc[i][6], acc[i][7]);
    }
}

__global__ __launch_bounds__(256) void k3_full(
    const float* __restrict__ Wd, const float* __restrict__ reflect_d,
    float* __restrict__ y, float* __restrict__ out_id)
{
    __shared__ float ys[4][DM];
    __shared__ float wds[64][17];
    const int tid = threadIdx.x;
    const int w = tid >> 6, lane = tid & 63;
    const int t = blockIdx.x * 4 + w;

    float4 yv[4];
    #pragma unroll
    for (int c = 0; c < 4; ++c) {
        yv[c] = *(const float4*)(y + (size_t)t * DM + lane * 16 + c * 4);
        *(float4*)(&ys[w][lane * 16 + c * 4]) = yv[c];
    }
    double s = 0.0;
    for (int kb = 0; kb < DM / 16; ++kb) {
        __syncthreads();
        {
            int row = tid >> 2, c4 = (tid & 3) << 2;
            float4 wv = *(const float4*)(Wd + (size_t)row * DM + kb * 16 + c4);
            wds[row][c4 + 0] = wv.x; wds[row][c4 + 1] = wv.y;
            wds[row][c4 + 2] = wv.z; wds[row][c4 + 3] = wv.w;
        }
        __syncthreads();
        #pragma unroll
        for (int i = 0; i < 16; ++i)
            s += (double)ys[w][kb * 16 + i] * (double)wds[lane][i];
    }
    int i0, i1;
    top2_64(s, lane, i0, i1);
    #pragma unroll
    for (int rr = 0; rr < 2; ++rr) {
        int idx = rr ? i1 : i0;
        const float* vrow = reflect_d + (size_t)idx * DM + lane * 16;
        float sv = 0.f, vn = 0.f;
        float4 vv[4];
        #pragma unroll
        for (int c = 0; c < 4; ++c) {
            vv[c] = *(const float4*)(vrow + c * 4);
            sv += vv[c].x * yv[c].x + vv[c].y * yv[c].y
                + vv[c].z * yv[c].z + vv[c].w * yv[c].w;
            vn += vv[c].x * vv[c].x + vv[c].y * vv[c].y
                + vv[c].z * vv[c].z + vv[c].w * vv[c].w;
        }
        #pragma unroll
        for (int m = 1; m < 64; m <<= 1) {
            sv += __shfl_xor(sv, m, 64);
            vn += __shfl_xor(vn, m, 64);
        }
        float coef = 2.0f * sv / (vn + 1e-8f);
        #pragma unroll
        for (int c = 0; c < 4; ++c) {
            yv[c].x -= coef * vv[c].x; yv[c].y -= coef * vv[c].y;
            yv[c].z -= coef * vv[c].z; yv[c].w -= coef * vv[c].w;
        }
    }
    #pragma unroll
    for (int c = 0; c < 4; ++c)
        *(float4*)(y + (size_t)t * DM + lane * 16 + c * 4) = yv[c];
    if (lane == 0) {
        out_id[(size_t)t * 2 + 0] = (float)i0;
        out_id[(size_t)t * 2 + 1] = (float)i1;
    }
}

extern "C" void kernel_launch(void* const* d_in, const int* in_sizes, int n_in,
                              void* d_out, int out_size, void* d_ws, size_t ws_size,
                              hipStream_t stream) {
    const float* x  = (const float*)d_in[0];
    const float* Wr = (const float*)d_in[1];
    const float* We = (const float*)d_in[2];
    const float* Wd = (const float*)d_in[3];
    const float* E  = (const float*)d_in[4];
    const float* rr = (const float*)d_in[5];
    const float* rd = (const float*)d_in[6];

    float* out    = (float*)d_out;
    float* y      = out + Y_OFF;
    float* out_ir = out + IR_OFF;
    float* out_w  = out + W_OFF;
    float* out_id = out + ID_OFF;

    if (ws_size >= WS_FULL) {
        char* p = (char*)d_ws;
        unsigned short* Ebt = (unsigned short*)p;  p += EBT_BYTES;
        float*          Xf  = (float*)p;           p += XF_BYTES;
        unsigned short* Xh  = (unsigned short*)p;  p += XH_BYTES;
        unsigned short* Xl  = (unsigned short*)p;  p += XH_BYTES;
        unsigned short* Gth = (unsigned short*)p;  p += GT_BYTES;
        unsigned short* Gtl = (unsigned short*)p;  p += GT_BYTES;
        float*          Sb  = (float*)p;           p += S_BYTES;
        double*         G64 = (double*)p;          p += G64_BYTES;
        double*         Srb = (double*)p;

        prep<<<3072, 256, 0, stream>>>(x, Wr, E, Wd, Srb, Ebt, G64, Gth, Gtl);
        k1_fast<<<TOK / 16, 256, 0, stream>>>(Srb, x, We, rr, Xf,
                                              Xh, Xl, out_ir, out_w);
        k2s<<<1024, 256, 0, stream>>>(Xh, Xl, Ebt, Gth, Gtl, out_w, y, Sb);
        refine_k3<<<TOK / 4, 256, 0, stream>>>(Sb, G64, Xf, out_w, rd, y, out_id);
    } else {
        float* xprime = (float*)d_ws;
        k1_tokens<<<TOK / 4, 256, 0, stream>>>(x, Wr, We, rr, xprime,
                                               out_ir, out_w);
        k2_gemm<<<dim3(DM / 128, TOK / 128), 256, 0, stream>>>(xprime, out_w, E, y);
        k3_full<<<TOK / 4, 256, 0, stream>>>(Wd, rd, y, out_id);
    }
}

// Round 10
// 317.662 us; speedup vs baseline: 3.4005x; 1.0219x over previous
//
#include <hip/hip_runtime.h>
#include <cmath>

#define TOK   8192
#define RNK   256
#define NEXP  16
#define NREF  64
#define DM    1024
#define KTOT  4096

#define Y_OFF  0
#define IR_OFF (TOK*DM)
#define W_OFF  (IR_OFF + TOK*2)
#define ID_OFF (W_OFF + TOK*NEXP)

#define EBT_BYTES ((size_t)DM * KTOT * 2)         // 8 MB
#define XF_BYTES  ((size_t)TOK * RNK * 4)         // 8 MB
#define XH_BYTES  ((size_t)TOK * RNK * 2)         // 4 MB
#define GT_BYTES  ((size_t)NEXP * NREF * RNK * 2) // 512 KB
#define S_BYTES   ((size_t)TOK * NREF * 4)        // 2 MB
#define G64_BYTES ((size_t)NREF * KTOT * 8)       // 2 MB
#define SR_BYTES  ((size_t)TOK * NREF * 8)        // 4 MB
#define WS_FULL   (EBT_BYTES + XF_BYTES + 2*XH_BYTES + 2*GT_BYTES + S_BYTES + G64_BYTES + SR_BYTES)

typedef __attribute__((ext_vector_type(8))) short short8;
typedef __attribute__((ext_vector_type(4))) float f32x4;
typedef const __attribute__((address_space(1))) void* gptr_t;
typedef __attribute__((address_space(3))) void* lptr_t;

__device__ inline unsigned short f2bf(float f) {    // RNE float->bf16
    unsigned int u = __float_as_uint(f);
    return (unsigned short)((u + 0x7fffu + ((u >> 16) & 1u)) >> 16);
}
__device__ inline float bf2f(unsigned short h) {
    return __uint_as_float(((unsigned int)h) << 16);
}
__device__ inline void split2(float v, unsigned short& h, unsigned short& l) {
    h = f2bf(v);
    l = f2bf(v - bf2f(h));
}
__device__ inline unsigned long long pack4(unsigned short a, unsigned short b,
                                           unsigned short c, unsigned short d) {
    return (unsigned long long)a | ((unsigned long long)b << 16)
         | ((unsigned long long)c << 32) | ((unsigned long long)d << 48);
}

// ---------- top-2 across a 64-lane wave, lax.top_k tie semantics ----------
__device__ inline void top2_64(double v, int idx, int& i0, int& i1) {
    double bv = v; int bi = idx;
    #pragma unroll
    for (int m = 1; m < 64; m <<= 1) {
        double ov = __shfl_xor(bv, m, 64);
        int    oi = __shfl_xor(bi, m, 64);
        if (ov > bv || (ov == bv && oi < bi)) { bv = ov; bi = oi; }
    }
    i0 = bi;
    double v2 = (idx == i0) ? -INFINITY : v;
    double bv2 = v2; int bi2 = idx;
    #pragma unroll
    for (int m = 1; m < 64; m <<= 1) {
        double ov = __shfl_xor(bv2, m, 64);
        int    oi = __shfl_xor(bi2, m, 64);
        if (ov > bv2 || (ov == bv2 && oi < bi2)) { bv2 = ov; bi2 = oi; }
    }
    i1 = bi2;
}

// ======== PREP: sr_fp64 (0..1023) | e_transpose (1024..2047) | g_fp64 ======
__global__ __launch_bounds__(256) void prep(
    const float* __restrict__ x, const float* __restrict__ Wr,
    const float* __restrict__ E, const float* __restrict__ Wd,
    double* __restrict__ Sr, unsigned short* __restrict__ Ebt,
    double* __restrict__ G64t,
    unsigned short* __restrict__ Gth, unsigned short* __restrict__ Gtl)
{
    __shared__ __align__(16) float lds_raw[64 * 68];
    const int bid = blockIdx.x;
    const int tid = threadIdx.x;
    const int w = tid >> 6, n = tid & 63;

    if (bid < 1024) {
        // ---- sr_fp64: 8 tokens/block ----
        float* wt = lds_raw;
        const int t0 = bid * 8;
        double acc[2] = {0.0, 0.0};
        const float* xr0 = x + (size_t)(t0 + w * 2 + 0) * RNK;
        const float* xr1 = x + (size_t)(t0 + w * 2 + 1) * RNK;
        for (int d0 = 0; d0 < RNK; d0 += 64) {
            __syncthreads();
            #pragma unroll
            for (int rep = 0; rep < 4; ++rep) {
                int f = rep * 256 + tid;
                int nn = f >> 4, dg = (f & 15) << 2;
                float4 v = *(const float4*)(Wr + (size_t)nn * RNK + d0 + dg);
                wt[(dg + 0) * 65 + nn] = v.x;
                wt[(dg + 1) * 65 + nn] = v.y;
                wt[(dg + 2) * 65 + nn] = v.z;
                wt[(dg + 3) * 65 + nn] = v.w;
            }
            __syncthreads();
            #pragma unroll
            for (int dg = 0; dg < 16; ++dg) {
                float4 e0 = *(const float4*)(xr0 + d0 + dg * 4);
                float4 e1 = *(const float4*)(xr1 + d0 + dg * 4);
                #pragma unroll
                for (int j = 0; j < 4; ++j) {
                    double wv = (double)wt[(dg * 4 + j) * 65 + n];
                    acc[0] = fma((double)(&e0.x)[j], wv, acc[0]);
                    acc[1] = fma((double)(&e1.x)[j], wv, acc[1]);
                }
            }
        }
        #pragma unroll
        for (int i = 0; i < 2; ++i)
            Sr[(size_t)(t0 + w * 2 + i) * NREF + n] = acc[i];
    } else if (bid < 2048) {
        // ---- e_transpose ----
        const int id = bid - 1024;
        const int k0 = (id & 63) * 64, d0 = (id >> 6) * 64;
        #pragma unroll
        for (int rep = 0; rep < 4; ++rep) {
            int idx = rep * 256 + tid;
            int r = idx >> 4, c4 = (idx & 15) << 2;
            float4 v = *(const float4*)(E + (size_t)(k0 + r) * DM + d0 + c4);
            lds_raw[r * 68 + c4 + 0] = v.x; lds_raw[r * 68 + c4 + 1] = v.y;
            lds_raw[r * 68 + c4 + 2] = v.z; lds_raw[r * 68 + c4 + 3] = v.w;
        }
        __syncthreads();
        #pragma unroll
        for (int rep = 0; rep < 4; ++rep) {
            int idx = rep * 256 + tid;
            int dr = idx >> 4, kc4 = (idx & 15) << 2;
            *(unsigned long long*)&Ebt[(size_t)(d0 + dr) * KTOT + k0 + kc4] =
                pack4(f2bf(lds_raw[(kc4 + 0) * 68 + dr]),
                      f2bf(lds_raw[(kc4 + 1) * 68 + dr]),
                      f2bf(lds_raw[(kc4 + 2) * 68 + dr]),
                      f2bf(lds_raw[(kc4 + 3) * 68 + dr]));
        }
    } else {
        // ---- g_fp64: 4 k-rows/block ----
        float* wt = lds_raw;
        const int k = (bid - 2048) * 4 + w;
        double acc = 0.0;
        const float* erow = E + (size_t)k * DM;
        for (int d0 = 0; d0 < DM; d0 += 64) {
            __syncthreads();
            #pragma unroll
            for (int rep = 0; rep < 4; ++rep) {
                int f = rep * 256 + tid;
                int nn = f >> 4, dg = (f & 15) << 2;
                float4 v = *(const float4*)(Wd + (size_t)nn * DM + d0 + dg);
                wt[(dg + 0) * 65 + nn] = v.x;
                wt[(dg + 1) * 65 + nn] = v.y;
                wt[(dg + 2) * 65 + nn] = v.z;
                wt[(dg + 3) * 65 + nn] = v.w;
            }
            __syncthreads();
            #pragma unroll
            for (int dg = 0; dg < 16; ++dg) {
                float4 e0 = *(const float4*)(erow + d0 + dg * 4);
                #pragma unroll
                for (int j = 0; j < 4; ++j) {
                    double wv = (double)wt[(dg * 4 + j) * 65 + n];
                    acc = fma((double)(&e0.x)[j], wv, acc);
                }
            }
        }
        G64t[(size_t)n * KTOT + k] = acc;
        float gf = (float)acc;
        unsigned short h, lo;
        split2(gf, h, lo);
        const int e = k >> 8, r = k & 255;
        Gth[((size_t)(e * NREF + n)) * RNK + r] = h;
        Gtl[((size_t)(e * NREF + n)) * RNK + r] = lo;
    }
}

// ======== K1S: k1 (VALU/latency) + s_mfma (MFMA) fused per 16 tokens ======
// s-body reads Xh/Xl from LDS (row stride 264 -> 2-way bank alias, free) and
// w from LDS stash. MFMA sequence identical to round-8 s_mfma -> bit-identical S.
__global__ __launch_bounds__(256) void k1s(
    const double* __restrict__ Sr, const float* __restrict__ x,
    const float* __restrict__ We, const float* __restrict__ reflect_r,
    const unsigned short* __restrict__ Gth, const unsigned short* __restrict__ Gtl,
    float* __restrict__ xprime,
    unsigned short* __restrict__ Xh, unsigned short* __restrict__ Xl,
    float* __restrict__ out_ir, float* __restrict__ out_w, float* __restrict__ S)
{
    __shared__ __align__(16) char smem_u[16640];     // we_lds, later red
    __shared__ float xs[4][260];
    __shared__ __align__(16) unsigned short xh_lds[16][264];
    __shared__ __align__(16) unsigned short xl_lds[16][264];
    __shared__ float wsh[16][16];
    float* we_lds = (float*)smem_u;                  // 16*260 floats
    float* red    = (float*)smem_u;                  // [4][16][64] after loop

    const int tid = threadIdx.x;
    const int w = tid >> 6, lane = tid & 63;
    const int t0 = blockIdx.x * 16;

    #pragma unroll
    for (int rep = 0; rep < 4; ++rep) {
        int f = rep * 256 + tid;
        int row = f >> 6, c4 = (f & 63) << 2;
        float4 v = *(const float4*)(We + (size_t)row * RNK + c4);
        *(float4*)&we_lds[row * 260 + c4] = v;
    }
    __syncthreads();

    for (int it = 0; it < 4; ++it) {
        const int tloc = it * 4 + w;
        const int t = t0 + tloc;

        float4 xv = *(const float4*)(x + (size_t)t * RNK + lane * 4);
        double s = Sr[(size_t)t * NREF + lane];
        int i0, i1;
        top2_64(s, lane, i0, i1);

        #pragma unroll
        for (int rr = 0; rr < 2; ++rr) {
            int idx = rr ? i1 : i0;
            float4 vv = *(const float4*)(reflect_r + (size_t)idx * RNK + lane * 4);
            float sv = vv.x * xv.x + vv.y * xv.y + vv.z * xv.z + vv.w * xv.w;
            float vn = vv.x * vv.x + vv.y * vv.y + vv.z * vv.z + vv.w * vv.w;
            #pragma unroll
            for (int m = 1; m < 64; m <<= 1) {
                sv += __shfl_xor(sv, m, 64);
                vn += __shfl_xor(vn, m, 64);
            }
            float coef = 2.0f * sv / (vn + 1e-8f);
            xv.x -= coef * vv.x; xv.y -= coef * vv.y;
            xv.z -= coef * vv.z; xv.w -= coef * vv.w;
        }

        *(float4*)&xs[w][lane * 4] = xv;
        *(float4*)(xprime + (size_t)t * RNK + lane * 4) = xv;

        const int n16 = lane & 15;
        double se = 0.0;
        {
            const float* werow = &we_lds[n16 * 260];
            #pragma unroll 8
            for (int r4 = 0; r4 < RNK / 4; ++r4) {
                float4 xr = *(const float4*)(&xs[w][r4 * 4]);
                float4 wf = *(const float4*)(werow + r4 * 4);
                se += (double)xr.x * wf.x + (double)xr.y * wf.y
                    + (double)xr.z * wf.z + (double)xr.w * wf.w;
            }
        }
        float sef = (float)se;
        float mx = sef;
        #pragma unroll
        for (int m = 1; m < 16; m <<= 1) mx = fmaxf(mx, __shfl_xor(mx, m, 64));
        float ex = expf(sef - mx);
        float sm = ex;
        #pragma unroll
        for (int m = 1; m < 16; m <<= 1) sm += __shfl_xor(sm, m, 64);
        float wgt = ex / sm;

        if (lane < NEXP) {
            out_w[(size_t)t * NEXP + lane] = wgt;
            wsh[tloc][lane] = wgt;
        }
        if (lane == 0) {
            out_ir[(size_t)t * 2 + 0] = (float)i0;
            out_ir[(size_t)t * 2 + 1] = (float)i1;
        }

        unsigned short hx, lx, hy, ly, hz, lz, hw, lw;
        split2(xv.x, hx, lx); split2(xv.y, hy, ly);
        split2(xv.z, hz, lz); split2(xv.w, hw, lw);
        unsigned long long ph = pack4(hx, hy, hz, hw);
        unsigned long long pl = pack4(lx, ly, lz, lw);
        *(unsigned long long*)&Xh[(size_t)t * RNK + lane * 4] = ph;
        *(unsigned long long*)&Xl[(size_t)t * RNK + lane * 4] = pl;
        *(unsigned long long*)&xh_lds[tloc][lane * 4] = ph;
        *(unsigned long long*)&xl_lds[tloc][lane * 4] = pl;
    }
    __syncthreads();   // xh/xl/wsh complete; we_lds reads done (red may overwrite)

    // ---- s-body: S[t][n] = sum_e w[t,e]*(x'[t,:].G_e[:,n]) ----
    const int l = lane;
    short8 ah[8], al[8];
    {
        const int trow = l & 15;
        #pragma unroll
        for (int ks = 0; ks < 8; ++ks) {
            ah[ks] = *(const short8*)&xh_lds[trow][ks * 32 + (l >> 4) * 8];
            al[ks] = *(const short8*)&xl_lds[trow][ks * 32 + (l >> 4) * 8];
        }
    }

    f32x4 Sacc[4] = {};
    #pragma unroll
    for (int ei = 0; ei < 4; ++ei) {
        const int e = w * 4 + ei;
        f32x4 acc[4] = {};
        #pragma unroll
        for (int ks = 0; ks < 8; ++ks) {
            #pragma unroll
            for (int nn = 0; nn < 4; ++nn) {
                size_t gbase = ((size_t)(e * NREF + nn * 16 + (l & 15))) * RNK
                             + ks * 32 + (l >> 4) * 8;
                short8 bh = *(const short8*)&Gth[gbase];
                short8 bl = *(const short8*)&Gtl[gbase];
                acc[nn] = __builtin_amdgcn_mfma_f32_16x16x32_bf16(al[ks], bh, acc[nn], 0, 0, 0);
                acc[nn] = __builtin_amdgcn_mfma_f32_16x16x32_bf16(ah[ks], bl, acc[nn], 0, 0, 0);
                acc[nn] = __builtin_amdgcn_mfma_f32_16x16x32_bf16(ah[ks], bh, acc[nn], 0, 0, 0);
            }
        }
        #pragma unroll
        for (int j = 0; j < 4; ++j) {
            float wv = wsh[(l >> 4) * 4 + j][e];
            #pragma unroll
            for (int nn = 0; nn < 4; ++nn) Sacc[nn][j] += wv * acc[nn][j];
        }
    }
    #pragma unroll
    for (int nn = 0; nn < 4; ++nn)
        #pragma unroll
        for (int j = 0; j < 4; ++j)
            red[(w * 16 + (l >> 4) * 4 + j) * 64 + nn * 16 + (l & 15)] = Sacc[nn][j];
    __syncthreads();
    for (int i = tid; i < 16 * 64; i += 256) {
        int tt = i >> 6, nn = i & 63;
        float sv = red[(0 * 16 + tt) * 64 + nn] + red[(1 * 16 + tt) * 64 + nn]
                 + red[(2 * 16 + tt) * 64 + nn] + red[(3 * 16 + tt) * 64 + nn];
        S[(size_t)(t0 + tt) * NREF + nn] = sv;
    }
}

// ---------- K2 fused: y[t,d] = sum_e w[t,e] * (Xh[t,:] @ E_e[:,d]) ---------
__global__ __launch_bounds__(256) void k2_fused(
    const unsigned short* __restrict__ Xh,
    const unsigned short* __restrict__ Ebt,
    const float* __restrict__ wts,
    float* __restrict__ y)
{
    __shared__ unsigned short As[128 * 32];
    __shared__ unsigned short Bs[128 * 32];
    __shared__ float wt[NEXP * 132];
    const int tid = threadIdx.x;
    const int l = tid & 63, w = tid >> 6;
    const int wr = w >> 1, wc = w & 1;
    const int tm0 = blockIdx.y * 128, n0 = blockIdx.x * 128;
    const int lrow = l >> 2, s = l & 3, g = l >> 4;

    #pragma unroll
    for (int rep = 0; rep < 8; ++rep) {
        int f = rep * 256 + tid;
        int row = f >> 4, e = f & 15;
        wt[e * 132 + row] = wts[(size_t)(tm0 + row) * NEXP + e];
    }

    f32x4 acc[4][4] = {};

    for (int e = 0; e < NEXP; ++e) {
        f32x4 acc_e[4][4] = {};
        for (int kb8 = 0; kb8 < 8; ++kb8) {
            const int kb = e * 8 + kb8;
            __syncthreads();
            #pragma unroll
            for (int i = 0; i < 2; ++i) {
                int row = w * 32 + i * 16 + lrow;
                int sw = ((s ^ ((row >> 1) & 3)) << 4);
                const char* ga = (const char*)Xh
                    + ((size_t)(tm0 + row) * RNK + kb8 * 32) * 2 + sw;
                __builtin_amdgcn_global_load_lds((gptr_t)ga,
                    (lptr_t)&As[(w * 32 + i * 16) * 32], 16, 0, 0);
                const char* gb = (const char*)Ebt
                    + ((size_t)(n0 + row) * KTOT + kb * 32) * 2 + sw;
                __builtin_amdgcn_global_load_lds((gptr_t)gb,
                    (lptr_t)&Bs[(w * 32 + i * 16) * 32], 16, 0, 0);
            }
            __syncthreads();

            short8 af[4], bv[4];
            #pragma unroll
            for (int m = 0; m < 4; ++m) {
                int row = wr * 64 + m * 16 + (l & 15);
                af[m] = *(const short8*)&As[row * 32 + ((g ^ ((row >> 1) & 3)) << 3)];
            }
            #pragma unroll
            for (int nn = 0; nn < 4; ++nn) {
                int row = wc * 64 + nn * 16 + (l & 15);
                bv[nn] = *(const short8*)&Bs[row * 32 + ((g ^ ((row >> 1) & 3)) << 3)];
            }
            #pragma unroll
            for (int m = 0; m < 4; ++m)
                #pragma unroll
                for (int nn = 0; nn < 4; ++nn)
                    acc_e[m][nn] = __builtin_amdgcn_mfma_f32_16x16x32_bf16(
                        af[m], bv[nn], acc_e[m][nn], 0, 0, 0);
        }
        #pragma unroll
        for (int m = 0; m < 4; ++m) {
            int rowb = wr * 64 + m * 16 + (l >> 4) * 4;
            float4 wm = *(const float4*)&wt[e * 132 + rowb];
            #pragma unroll
            for (int nn = 0; nn < 4; ++nn) {
                #pragma unroll
                for (int j = 0; j < 4; ++j)
                    acc[m][nn][j] += (&wm.x)[j] * acc_e[m][nn][j];
            }
        }
    }

    #pragma unroll
    for (int m = 0; m < 4; ++m) {
        int rbase = tm0 + wr * 64 + m * 16 + (l >> 4) * 4;
        #pragma unroll
        for (int nn = 0; nn < 4; ++nn) {
            int c = n0 + wc * 64 + nn * 16 + (l & 15);
            #pragma unroll
            for (int j = 0; j < 4; ++j)
                y[(size_t)(rbase + j) * DM + c] = acc[m][nn][j];
        }
    }
}

// ======== REFINE+K3: approx top4 -> fp64 rescore -> top2 -> reflect y ======
__global__ __launch_bounds__(256) void refine_k3(
    const float* __restrict__ S, const double* __restrict__ G64t,
    const float* __restrict__ xf, const float* __restrict__ wts,
    const float* __restrict__ reflect_d,
    float* __restrict__ y, float* __restrict__ out_id)
{
    __shared__ float xs[4][RNK];
    __shared__ float wsh[4][NEXP];
    const int tid = threadIdx.x, w = tid >> 6, lane = tid & 63;
    const int t = blockIdx.x * 4 + w;

    *(float4*)&xs[w][lane * 4] = *(const float4*)(xf + (size_t)t * RNK + lane * 4);
    if (lane < NEXP) wsh[w][lane] = wts[(size_t)t * NEXP + lane];
    __syncthreads();

    float cur = S[(size_t)t * NREF + lane];
    int cand[4];
    #pragma unroll
    for (int c = 0; c < 4; ++c) {
        float bv = cur; int bi = lane;
        #pragma unroll
        for (int m = 1; m < 64; m <<= 1) {
            float ov = __shfl_xor(bv, m, 64);
            int   oi = __shfl_xor(bi, m, 64);
            if (ov > bv || (ov == bv && oi < bi)) { bv = ov; bi = oi; }
        }
        cand[c] = bi;
        if (lane == bi) cur = -INFINITY;
    }

    double rs[4];
    #pragma unroll
    for (int c = 0; c < 4; ++c) {
        const double* grow = G64t + (size_t)cand[c] * KTOT;
        double acc = 0.0;
        #pragma unroll 4
        for (int i = 0; i < 64; ++i) {
            int k = i * 64 + lane;
            double a = (double)wsh[w][k >> 8] * (double)xs[w][k & 255];
            acc = fma(a, grow[k], acc);
        }
        #pragma unroll
        for (int m = 1; m < 64; m <<= 1) acc += __shfl_xor(acc, m, 64);
        rs[c] = acc;
    }

    int b0 = 0;
    #pragma unroll
    for (int c = 1; c < 4; ++c)
        if (rs[c] > rs[b0] || (rs[c] == rs[b0] && cand[c] < cand[b0])) b0 = c;
    int b1 = (b0 == 0) ? 1 : 0;
    #pragma unroll
    for (int c = 0; c < 4; ++c) {
        if (c == b0) continue;
        if (rs[c] > rs[b1] || (rs[c] == rs[b1] && cand[c] < cand[b1])) b1 = c;
    }
    const int i0 = cand[b0], i1 = cand[b1];
    if (lane == 0) {
        out_id[(size_t)t * 2 + 0] = (float)i0;
        out_id[(size_t)t * 2 + 1] = (float)i1;
    }

    float4 yv[4];
    #pragma unroll
    for (int c = 0; c < 4; ++c)
        yv[c] = *(const float4*)(y + (size_t)t * DM + lane * 16 + c * 4);

    #pragma unroll
    for (int rr = 0; rr < 2; ++rr) {
        int idx = rr ? i1 : i0;
        const float* vrow = reflect_d + (size_t)idx * DM + lane * 16;
        float sv = 0.f, vn = 0.f;
        float4 vv[4];
        #pragma unroll
        for (int c = 0; c < 4; ++c) {
            vv[c] = *(const float4*)(vrow + c * 4);
            sv += vv[c].x * yv[c].x + vv[c].y * yv[c].y
                + vv[c].z * yv[c].z + vv[c].w * yv[c].w;
            vn += vv[c].x * vv[c].x + vv[c].y * vv[c].y
                + vv[c].z * vv[c].z + vv[c].w * vv[c].w;
        }
        #pragma unroll
        for (int m = 1; m < 64; m <<= 1) {
            sv += __shfl_xor(sv, m, 64);
            vn += __shfl_xor(vn, m, 64);
        }
        float coef = 2.0f * sv / (vn + 1e-8f);
        #pragma unroll
        for (int c = 0; c < 4; ++c) {
            yv[c].x -= coef * vv[c].x; yv[c].y -= coef * vv[c].y;
            yv[c].z -= coef * vv[c].z; yv[c].w -= coef * vv[c].w;
        }
    }
    #pragma unroll
    for (int c = 0; c < 4; ++c)
        *(float4*)(y + (size_t)t * DM + lane * 16 + c * 4) = yv[c];
}

// ================= fallback path (ws too small), unchanged =================
__global__ __launch_bounds__(256) void k1_tokens(
    const float* __restrict__ x, const float* __restrict__ Wr,
    const float* __restrict__ We, const float* __restrict__ reflect_r,
    float* __restrict__ xprime, float* __restrict__ out_ir,
    float* __restrict__ out_w)
{
    __shared__ float xs[4][RNK];
    const int tid = threadIdx.x;
    const int w = tid >> 6, lane = tid & 63;
    const int t = blockIdx.x * 4 + w;

    float4 xv = *(const float4*)(x + (size_t)t * RNK + lane * 4);
    *(float4*)(&xs[w][lane * 4]) = xv;
    __syncthreads();

    double s = 0.0;
    {
        const float* wrow = Wr + (size_t)lane * RNK;
        for (int r4 = 0; r4 < RNK / 4; ++r4) {
            float4 xr = *(const float4*)(&xs[w][r4 * 4]);
            float4 wr = *(const float4*)(wrow + r4 * 4);
            s += (double)xr.x * wr.x + (double)xr.y * wr.y
               + (double)xr.z * wr.z + (double)xr.w * wr.w;
        }
    }
    int i0, i1;
    top2_64(s, lane, i0, i1);

    #pragma unroll
    for (int rr = 0; rr < 2; ++rr) {
        int idx = rr ? i1 : i0;
        float4 vv = *(const float4*)(reflect_r + (size_t)idx * RNK + lane * 4);
        float sv = vv.x * xv.x + vv.y * xv.y + vv.z * xv.z + vv.w * xv.w;
        float vn = vv.x * vv.x + vv.y * vv.y + vv.z * vv.z + vv.w * vv.w;
        #pragma unroll
        for (int m = 1; m < 64; m <<= 1) {
            sv += __shfl_xor(sv, m, 64);
            vn += __shfl_xor(vn, m, 64);
        }
        float coef = 2.0f * sv / (vn + 1e-8f);
        xv.x -= coef * vv.x; xv.y -= coef * vv.y;
        xv.z -= coef * vv.z; xv.w -= coef * vv.w;
    }
    __syncthreads();
    *(float4*)(&xs[w][lane * 4]) = xv;
    __syncthreads();

    *(float4*)(xprime + (size_t)t * RNK + lane * 4) = xv;

    const int n = lane & 15;
    double se = 0.0;
    {
        const float* werow = We + (size_t)n * RNK;
        for (int r4 = 0; r4 < RNK / 4; ++r4) {
            float4 xr = *(const float4*)(&xs[w][r4 * 4]);
            float4 wf = *(const float4*)(werow + r4 * 4);
            se += (double)xr.x * wf.x + (double)xr.y * wf.y
                + (double)xr.z * wf.z + (double)xr.w * wf.w;
        }
    }
    float sef = (float)se;
    float mx = sef;
    #pragma unroll
    for (int m = 1; m < 16; m <<= 1) mx = fmaxf(mx, __shfl_xor(mx, m, 64));
    float ex = expf(sef - mx);
    float sm = ex;
    #pragma unroll
    for (int m = 1; m < 16; m <<= 1) sm += __shfl_xor(sm, m, 64);
    float wgt = ex / sm;

    if (lane < NEXP) out_w[(size_t)t * NEXP + lane] = wgt;
    if (lane == 0) {
        out_ir[(size_t)t * 2 + 0] = (float)i0;
        out_ir[(size_t)t * 2 + 1] = (float)i1;
    }
}

__global__ __launch_bounds__(256) void k2_gemm(
    const float* __restrict__ xp, const float* __restrict__ wts,
    const float* __restrict__ E, float* __restrict__ y)
{
    __shared__ float As[16][132];
    __shared__ float Bs[16][132];
    const int tid = threadIdx.x;
    const int bn = blockIdx.x, bm = blockIdx.y;
    const int tm0 = bm * 128, tn0 = bn * 128;
    const int ty = tid >> 4, tx = tid & 15;
    float acc[8][8] = {};
    for (int kb = 0; kb < KTOT / 16; ++kb) {
        const int e = kb >> 4;
        const int rbase = (kb & 15) << 4;
        const int kglob = kb << 4;
        __syncthreads();
        #pragma unroll
        for (int h = 0; h < 2; ++h) {
            int f = tid + h * 256;
            int m = f >> 2, k4 = (f & 3) << 2;
            int t = tm0 + m;
            float4 a = *(const float4*)(xp + (size_t)t * RNK + rbase + k4);
            float wv = wts[(size_t)t * NEXP + e];
            As[k4 + 0][m] = a.x * wv; As[k4 + 1][m] = a.y * wv;
            As[k4 + 2][m] = a.z * wv; As[k4 + 3][m] = a.w * wv;
        }
        #pragma unroll
        for (int h = 0; h < 2; ++h) {
            int f = tid + h * 256;
            int kk = f >> 5, d4 = (f & 31) << 2;
            float4 b = *(const float4*)(E + (size_t)(kglob + kk) * DM + tn0 + d4);
            *(float4*)(&Bs[kk][d4]) = b;
        }
        __syncthreads();
        #pragma unroll
        for (int kk = 0; kk < 16; ++kk) {
            float4 a0 = *(const float4*)(&As[kk][ty * 8]);
            float4 a1 = *(const float4*)(&As[kk][ty * 8 + 4]);
            float4 b0 = *(const float4*)(&Bs[kk][tx * 8]);
            float4 b1 = *(const float4*)(&Bs[kk][tx * 8 + 4]);
            float av[8] = {a0.x, a0.y, a0.z, a0.w, a1.x, a1.y, a1.z, a1.w};
            float bw[8] = {b0.x, b0.y, b0.z, b0.w, b1.x, b1.y, b1.z, b1.w};
            #pragma unroll
            for (int i = 0; i < 8; ++i)
                #pragma unroll
                for (int j = 0; j < 8; ++j)
                    acc[i][j] = fmaf(av[i], bw[j], acc[i][j]);
        }
    }
    #pragma unroll
    for (int i = 0; i < 8; ++i) {
        int t = tm0 + ty * 8 + i;
        float* yrow = y + (size_t)t * DM + tn0 + tx * 8;
        *(float4*)yrow       = make_float4(acc[i][0], acc[i][1], acc[i][2], acc[i][3]);
        *(float4*)(yrow + 4) = make_float4(acc[i][4], acc[i][5], acc[i][6], acc[i][7]);
    }
}

__global__ __launch_bounds__(256) void k3_full(
    const float* __restrict__ Wd, const float* __restrict__ reflect_d,
    float* __restrict__ y, float* __restrict__ out_id)
{
    __shared__ float ys[4][DM];
    __shared__ float wds[64][17];
    const int tid = threadIdx.x;
    const int w = tid >> 6, lane = tid & 63;
    const int t = blockIdx.x * 4 + w;

    float4 yv[4];
    #pragma unroll
    for (int c = 0; c < 4; ++c) {
        yv[c] = *(const float4*)(y + (size_t)t * DM + lane * 16 + c * 4);
        *(float4*)(&ys[w][lane * 16 + c * 4]) = yv[c];
    }
    double s = 0.0;
    for (int kb = 0; kb < DM / 16; ++kb) {
        __syncthreads();
        {
            int row = tid >> 2, c4 = (tid & 3) << 2;
            float4 wv = *(const float4*)(Wd + (size_t)row * DM + kb * 16 + c4);
            wds[row][c4 + 0] = wv.x; wds[row][c4 + 1] = wv.y;
            wds[row][c4 + 2] = wv.z; wds[row][c4 + 3] = wv.w;
        }
        __syncthreads();
        #pragma unroll
        for (int i = 0; i < 16; ++i)
            s += (double)ys[w][kb * 16 + i] * (double)wds[lane][i];
    }
    int i0, i1;
    top2_64(s, lane, i0, i1);
    #pragma unroll
    for (int rr = 0; rr < 2; ++rr) {
        int idx = rr ? i1 : i0;
        const float* vrow = reflect_d + (size_t)idx * DM + lane * 16;
        float sv = 0.f, vn = 0.f;
        float4 vv[4];
        #pragma unroll
        for (int c = 0; c < 4; ++c) {
            vv[c] = *(const float4*)(vrow + c * 4);
            sv += vv[c].x * yv[c].x + vv[c].y * yv[c].y
                + vv[c].z * yv[c].z + vv[c].w * yv[c].w;
            vn += vv[c].x * vv[c].x + vv[c].y * vv[c].y
                + vv[c].z * vv[c].z + vv[c].w * vv[c].w;
        }
        #pragma unroll
        for (int m = 1; m < 64; m <<= 1) {
            sv += __shfl_xor(sv, m, 64);
            vn += __shfl_xor(vn, m, 64);
        }
        float coef = 2.0f * sv / (vn + 1e-8f);
        #pragma unroll
        for (int c = 0; c < 4; ++c) {
            yv[c].x -= coef * vv[c].x; yv[c].y -= coef * vv[c].y;
            yv[c].z -= coef * vv[c].z; yv[c].w -= coef * vv[c].w;
        }
    }
    #pragma unroll
    for (int c = 0; c < 4; ++c)
        *(float4*)(y + (size_t)t * DM + lane * 16 + c * 4) = yv[c];
    if (lane == 0) {
        out_id[(size_t)t * 2 + 0] = (float)i0;
        out_id[(size_t)t * 2 + 1] = (float)i1;
    }
}

extern "C" void kernel_launch(void* const* d_in, const int* in_sizes, int n_in,
                              void* d_out, int out_size, void* d_ws, size_t ws_size,
                              hipStream_t stream) {
    const float* x  = (const float*)d_in[0];
    const float* Wr = (const float*)d_in[1];
    const float* We = (const float*)d_in[2];
    const float* Wd = (const float*)d_in[3];
    const float* E  = (const float*)d_in[4];
    const float* rr = (const float*)d_in[5];
    const float* rd = (const float*)d_in[6];

    float* out    = (float*)d_out;
    float* y      = out + Y_OFF;
    float* out_ir = out + IR_OFF;
    float* out_w  = out + W_OFF;
    float* out_id = out + ID_OFF;

    if (ws_size >= WS_FULL) {
        char* p = (char*)d_ws;
        unsigned short* Ebt = (unsigned short*)p;  p += EBT_BYTES;
        float*          Xf  = (float*)p;           p += XF_BYTES;
        unsigned short* Xh  = (unsigned short*)p;  p += XH_BYTES;
        unsigned short* Xl  = (unsigned short*)p;  p += XH_BYTES;
        unsigned short* Gth = (unsigned short*)p;  p += GT_BYTES;
        unsigned short* Gtl = (unsigned short*)p;  p += GT_BYTES;
        float*          Sb  = (float*)p;           p += S_BYTES;
        double*         G64 = (double*)p;          p += G64_BYTES;
        double*         Srb = (double*)p;

        prep<<<3072, 256, 0, stream>>>(x, Wr, E, Wd, Srb, Ebt, G64, Gth, Gtl);
        k1s<<<TOK / 16, 256, 0, stream>>>(Srb, x, We, rr, Gth, Gtl, Xf,
                                          Xh, Xl, out_ir, out_w, Sb);
        k2_fused<<<dim3(DM / 128, TOK / 128), 256, 0, stream>>>(Xh, Ebt, out_w, y);
        refine_k3<<<TOK / 4, 256, 0, stream>>>(Sb, G64, Xf, out_w, rd, y, out_id);
    } else {
        float* xprime = (float*)d_ws;
        k1_tokens<<<TOK / 4, 256, 0, stream>>>(x, Wr, We, rr, xprime,
                                               out_ir, out_w);
        k2_gemm<<<dim3(DM / 128, TOK / 128), 256, 0, stream>>>(xprime, out_w, E, y);
        k3_full<<<TOK / 4, 256, 0, stream>>>(Wd, rd, y, out_id);
    }
}